// Round 3
// baseline (8403.766 us; speedup 1.0000x reference)
//
#include <hip/hip_runtime.h>
#include <hip/hip_fp16.h>

#define E_EDGES   400000
#define M_NODES   50000
#define N_INC     800000
#define PER_B     400000
#define VEC_N     800000
#define N4        200000
#define N4_PER_B  100000
#define CG_ITERS  20
#define EPSF      1e-12f

// scal layout: rs[it][b] = scal[2*it+b] (it=0..20), pAp slot t: scal[64+2*t+b] (t=0..20)

__device__ __forceinline__ float waveReduce(float v) {
#pragma unroll
    for (int off = 32; off > 0; off >>= 1)
        v += __shfl_down(v, off, 64);
    return v;
}

__global__ void k_zero_scal(float* __restrict__ s) {
    if (threadIdx.x < 128) s[threadIdx.x] = 0.0f;
}

__global__ void k_zero_cnt(int* __restrict__ cnt) {
    int i = blockIdx.x * blockDim.x + threadIdx.x;
    if (i < M_NODES) cnt[i] = 0;
}

__global__ void k_hist(const int* __restrict__ src, const int* __restrict__ dst,
                       int* __restrict__ cnt) {
    int e = blockIdx.x * blockDim.x + threadIdx.x;
    if (e < E_EDGES) {
        atomicAdd(&cnt[src[e]], 1);
        atomicAdd(&cnt[dst[e]], 1);
    }
}

#define SCAN_T 1024
__global__ void k_scan(const int* __restrict__ cnt, int* __restrict__ off,
                       int* __restrict__ cursor) {
    __shared__ int part[SCAN_T];
    int t = threadIdx.x;
    const int chunk = (M_NODES + SCAN_T - 1) / SCAN_T;
    int beg = t * chunk;
    int end = beg + chunk; if (end > M_NODES) end = M_NODES;
    if (beg > M_NODES) beg = M_NODES;
    int s = 0;
    for (int i = beg; i < end; ++i) s += cnt[i];
    part[t] = s;
    __syncthreads();
    for (int st = 1; st < SCAN_T; st <<= 1) {
        int v = (t >= st) ? part[t - st] : 0;
        __syncthreads();
        part[t] += v;
        __syncthreads();
    }
    int run = (t == 0) ? 0 : part[t - 1];
    for (int i = beg; i < end; ++i) {
        off[i] = run; cursor[i] = run;
        run += cnt[i];
    }
    if (t == SCAN_T - 1) off[M_NODES] = run;
}

// incidence arrays: wk = e + side*E  (side0: at src, W=C, GH=G; side1: at dst, W=Ct, GH=H)
//                   nb = other endpoint
__global__ void k_scatter(const int* __restrict__ src, const int* __restrict__ dst,
                          int* __restrict__ cursor, int* __restrict__ wk,
                          int* __restrict__ nb) {
    int e = blockIdx.x * blockDim.x + threadIdx.x;
    if (e < E_EDGES) {
        int s = src[e], t = dst[e];
        int p0 = atomicAdd(&cursor[s], 1);
        wk[p0] = e;          nb[p0] = t;
        int p1 = atomicAdd(&cursor[t], 1);
        wk[p1] = e + E_EDGES; nb[p1] = s;
    }
}

// 8 lanes per edge; lane a computes row a of C=Rs^T Rd, Ct=C^T, G=Rs^T Rs, H=Rd^T Rd (fp16)
__global__ __launch_bounds__(256) void k_buildC(const float* __restrict__ Rs,
                                                const float* __restrict__ Rd,
                                                __half* __restrict__ Call,
                                                __half* __restrict__ GH, int haveGH) {
    int gt = blockIdx.x * blockDim.x + threadIdx.x;
    int e = gt >> 3, a = gt & 7;
    if (e >= E_EDGES) return;
    const float* rs = Rs + ((size_t)e << 6);
    const float* rd = Rd + ((size_t)e << 6);
    float C[8], Ct[8], G[8], H[8];
#pragma unroll
    for (int j = 0; j < 8; ++j) { C[j] = 0; Ct[j] = 0; G[j] = 0; H[j] = 0; }
#pragma unroll
    for (int c = 0; c < 8; ++c) {
        float xs = rs[c * 8 + a];
        float xd = rd[c * 8 + a];
        float4 s0 = *(const float4*)(rs + c * 8);
        float4 s1 = *(const float4*)(rs + c * 8 + 4);
        float4 d0 = *(const float4*)(rd + c * 8);
        float4 d1 = *(const float4*)(rd + c * 8 + 4);
        C[0] += xs * d0.x; C[1] += xs * d0.y; C[2] += xs * d0.z; C[3] += xs * d0.w;
        C[4] += xs * d1.x; C[5] += xs * d1.y; C[6] += xs * d1.z; C[7] += xs * d1.w;
        Ct[0] += xd * s0.x; Ct[1] += xd * s0.y; Ct[2] += xd * s0.z; Ct[3] += xd * s0.w;
        Ct[4] += xd * s1.x; Ct[5] += xd * s1.y; Ct[6] += xd * s1.z; Ct[7] += xd * s1.w;
        G[0] += xs * s0.x; G[1] += xs * s0.y; G[2] += xs * s0.z; G[3] += xs * s0.w;
        G[4] += xs * s1.x; G[5] += xs * s1.y; G[6] += xs * s1.z; G[7] += xs * s1.w;
        H[0] += xd * d0.x; H[1] += xd * d0.y; H[2] += xd * d0.z; H[3] += xd * d0.w;
        H[4] += xd * d1.x; H[5] += xd * d1.y; H[6] += xd * d1.z; H[7] += xd * d1.w;
    }
    union { float4 f; __half2 h[4]; } u;
#pragma unroll
    for (int k = 0; k < 4; ++k) u.h[k] = __floats2half2_rn(C[2 * k], C[2 * k + 1]);
    *(float4*)(Call + ((size_t)e << 6) + (a << 3)) = u.f;
#pragma unroll
    for (int k = 0; k < 4; ++k) u.h[k] = __floats2half2_rn(Ct[2 * k], Ct[2 * k + 1]);
    *(float4*)(Call + (((size_t)(e + E_EDGES)) << 6) + (a << 3)) = u.f;
    if (haveGH) {
#pragma unroll
        for (int k = 0; k < 4; ++k) u.h[k] = __floats2half2_rn(G[2 * k], G[2 * k + 1]);
        *(float4*)(GH + ((size_t)e << 6) + (a << 3)) = u.f;
#pragma unroll
        for (int k = 0; k < 4; ++k) u.h[k] = __floats2half2_rn(H[2 * k], H[2 * k + 1]);
        *(float4*)(GH + (((size_t)(e + E_EDGES)) << 6) + (a << 3)) = u.f;
    }
}

// diag from fp16 G/H blocks (gathered via wk)
__global__ void k_diagGH(const int* __restrict__ off, const int* __restrict__ wk,
                         const __half* __restrict__ GH, float* __restrict__ diag) {
    int gt = blockIdx.x * blockDim.x + threadIdx.x;
    int m = gt >> 3, a = gt & 7;
    if (m >= M_NODES) return;
    float D[8];
#pragma unroll
    for (int j = 0; j < 8; ++j) D[j] = 0.0f;
    int beg = off[m], end = off[m + 1];
    for (int i = beg; i < end; ++i) {
        int k = wk[i];
        union { float4 f; __half2 h[4]; } u;
        u.f = *(const float4*)(GH + ((size_t)k << 6) + (a << 3));
        float2 w0 = __half22float2(u.h[0]);
        float2 w1 = __half22float2(u.h[1]);
        float2 w2 = __half22float2(u.h[2]);
        float2 w3 = __half22float2(u.h[3]);
        D[0] += w0.x; D[1] += w0.y; D[2] += w1.x; D[3] += w1.y;
        D[4] += w2.x; D[5] += w2.y; D[6] += w3.x; D[7] += w3.y;
    }
    D[a] += 1.0f;
    float* dout = diag + ((size_t)m << 6) + (a << 3);
    *(float4*)dout = make_float4(D[0], D[1], D[2], D[3]);
    *(float4*)(dout + 4) = make_float4(D[4], D[5], D[6], D[7]);
}

// fallback diag straight from R (if ws too small for GH)
__global__ void k_diagR(const int* __restrict__ off, const int* __restrict__ wk,
                        const float* __restrict__ Rs, const float* __restrict__ Rd,
                        float* __restrict__ diag) {
    int gt = blockIdx.x * blockDim.x + threadIdx.x;
    int m = gt >> 3, a = gt & 7;
    if (m >= M_NODES) return;
    float D[8];
#pragma unroll
    for (int j = 0; j < 8; ++j) D[j] = 0.0f;
    int beg = off[m], end = off[m + 1];
    for (int i = beg; i < end; ++i) {
        int k = wk[i];
        int side = (k >= E_EDGES);
        int e = k - (side ? E_EDGES : 0);
        const float* R = (side ? Rd : Rs) + ((size_t)e << 6);
#pragma unroll
        for (int c = 0; c < 8; ++c) {
            float xa = R[c * 8 + a];
            float4 y0 = *(const float4*)(R + c * 8);
            float4 y1 = *(const float4*)(R + c * 8 + 4);
            D[0] += xa * y0.x; D[1] += xa * y0.y; D[2] += xa * y0.z; D[3] += xa * y0.w;
            D[4] += xa * y1.x; D[5] += xa * y1.y; D[6] += xa * y1.z; D[7] += xa * y1.w;
        }
    }
    D[a] += 1.0f;
    float* dout = diag + ((size_t)m << 6) + (a << 3);
    *(float4*)dout = make_float4(D[0], D[1], D[2], D[3]);
    *(float4*)(dout + 4) = make_float4(D[4], D[5], D[6], D[7]);
}

// matvec: 16 lanes per node (lane = (m, batch b, row a)); 3-stage pipelined gather.
// Ap_m = diag_m p_m - sum_i W_i p_nb(i); pAp dot accumulated into pap[0/1].
__global__ __launch_bounds__(256) void k_matvec(const float* __restrict__ pv,
                                                float* __restrict__ Ap,
                                                const int* __restrict__ off,
                                                const int* __restrict__ nbA,
                                                const int* __restrict__ wkA,
                                                const __half* __restrict__ Wall,
                                                const float* __restrict__ diag,
                                                float* __restrict__ pap) {
    int gt = blockIdx.x * blockDim.x + threadIdx.x;
    int m = gt >> 4;
    int b = (gt >> 3) & 1;
    int a = gt & 7;
    float d0 = 0.0f, d1 = 0.0f;
    if (m < M_NODES) {
        const float* p_b = pv + b * PER_B;
        const float* dg = diag + ((size_t)m << 6) + (a << 3);
        float4 g0 = *(const float4*)dg;
        float4 g1 = *(const float4*)(dg + 4);
        const float* pm = p_b + (m << 3);
        float4 q0 = *(const float4*)pm;
        float4 q1 = *(const float4*)(pm + 4);
        float acc = g0.x * q0.x + g0.y * q0.y + g0.z * q0.z + g0.w * q0.w
                  + g1.x * q1.x + g1.y * q1.y + g1.z * q1.z + g1.w * q1.w;
        int beg = off[m], end = off[m + 1];
        if (beg < end) {
            // stage: current data (i), next idx (i+1)
            int kC = wkA[beg], nC = nbA[beg];
            float4 wC = *(const float4*)(Wall + ((size_t)kC << 6) + (a << 3));
            const float* pn = p_b + (nC << 3);
            float4 u0 = *(const float4*)pn;
            float4 u1 = *(const float4*)(pn + 4);
            int i1 = (beg + 1 < end) ? beg + 1 : beg;
            int kN = wkA[i1], nN = nbA[i1];
            for (int i = beg; i < end; ++i) {
                // issue data loads for i+1 (idx already in regs)
                float4 wN = *(const float4*)(Wall + ((size_t)kN << 6) + (a << 3));
                const float* pn2 = p_b + (nN << 3);
                float4 v0 = *(const float4*)pn2;
                float4 v1 = *(const float4*)(pn2 + 4);
                // prefetch idx for i+2
                int i2 = (i + 2 < end) ? i + 2 : end - 1;
                int kT = wkA[i2], nT = nbA[i2];
                // compute with current
                union { float4 f; __half2 h[4]; } u; u.f = wC;
                float2 w0 = __half22float2(u.h[0]);
                float2 w1 = __half22float2(u.h[1]);
                float2 w2 = __half22float2(u.h[2]);
                float2 w3 = __half22float2(u.h[3]);
                acc -= w0.x * u0.x + w0.y * u0.y + w1.x * u0.z + w1.y * u0.w
                     + w2.x * u1.x + w2.y * u1.y + w3.x * u1.z + w3.y * u1.w;
                wC = wN; u0 = v0; u1 = v1; kN = kT; nN = nT;
            }
        }
        Ap[b * PER_B + (m << 3) + a] = acc;
        float pa = p_b[(m << 3) + a];
        float d = pa * acc;
        if (b == 0) d0 = d; else d1 = d;
    }
    d0 = waveReduce(d0);
    d1 = waveReduce(d1);
    if ((threadIdx.x & 63) == 0) {
        if (d0 != 0.0f) atomicAdd(&pap[0], d0);
        if (d1 != 0.0f) atomicAdd(&pap[1], d1);
    }
}

// x = c0 ; r = p = c0 - Ap ; rs0 += r.r
__global__ void k_init_r(const float4* __restrict__ c0, const float4* __restrict__ Ap,
                         float4* __restrict__ x, float4* __restrict__ r,
                         float4* __restrict__ p, float* __restrict__ rs0) {
    int i = blockIdx.x * blockDim.x + threadIdx.x;
    float s0 = 0.0f, s1 = 0.0f;
    if (i < N4) {
        float4 c = c0[i];
        float4 a = Ap[i];
        float4 rv = make_float4(c.x - a.x, c.y - a.y, c.z - a.z, c.w - a.w);
        x[i] = c; r[i] = rv; p[i] = rv;
        float d = rv.x * rv.x + rv.y * rv.y + rv.z * rv.z + rv.w * rv.w;
        if (i < N4_PER_B) s0 = d; else s1 = d;
    }
    s0 = waveReduce(s0);
    s1 = waveReduce(s1);
    if ((threadIdx.x & 63) == 0) {
        if (s0 != 0.0f) atomicAdd(&rs0[0], s0);
        if (s1 != 0.0f) atomicAdd(&rs0[1], s1);
    }
}

// alpha = rsold/(pAp+eps) computed per-thread; x += a p ; r -= a Ap ; rsnew += r.r
__global__ void k_update(float4* __restrict__ x, const float4* __restrict__ p,
                         const float4* __restrict__ Ap, float4* __restrict__ r,
                         const float* __restrict__ rsold, const float* __restrict__ pap,
                         float* __restrict__ rsnew) {
    int i = blockIdx.x * blockDim.x + threadIdx.x;
    float s0 = 0.0f, s1 = 0.0f;
    if (i < N4) {
        int b = (i < N4_PER_B) ? 0 : 1;
        float al = rsold[b] / (pap[b] + EPSF);
        float4 xv = x[i], pv = p[i], av = Ap[i], rv = r[i];
        xv.x += al * pv.x; xv.y += al * pv.y; xv.z += al * pv.z; xv.w += al * pv.w;
        rv.x -= al * av.x; rv.y -= al * av.y; rv.z -= al * av.z; rv.w -= al * av.w;
        x[i] = xv; r[i] = rv;
        float d = rv.x * rv.x + rv.y * rv.y + rv.z * rv.z + rv.w * rv.w;
        if (b == 0) s0 = d; else s1 = d;
    }
    s0 = waveReduce(s0);
    s1 = waveReduce(s1);
    if ((threadIdx.x & 63) == 0) {
        if (s0 != 0.0f) atomicAdd(&rsnew[0], s0);
        if (s1 != 0.0f) atomicAdd(&rsnew[1], s1);
    }
}

// beta = rsnew/(rsold+eps) per-thread; p = r + beta p
__global__ void k_pupdate(float4* __restrict__ p, const float4* __restrict__ r,
                          const float* __restrict__ rsold, const float* __restrict__ rsnew) {
    int i = blockIdx.x * blockDim.x + threadIdx.x;
    if (i < N4) {
        int b = (i < N4_PER_B) ? 0 : 1;
        float be = rsnew[b] / (rsold[b] + EPSF);
        float4 rv = r[i], pv = p[i];
        p[i] = make_float4(rv.x + be * pv.x, rv.y + be * pv.y,
                           rv.z + be * pv.z, rv.w + be * pv.w);
    }
}

extern "C" void kernel_launch(void* const* d_in, const int* in_sizes, int n_in,
                              void* d_out, int out_size, void* d_ws, size_t ws_size,
                              hipStream_t stream) {
    const float* c0 = (const float*)d_in[0];
    const int* src  = (const int*)d_in[1];
    const int* dst  = (const int*)d_in[2];
    const float* Rs = (const float*)d_in[3];
    const float* Rd = (const float*)d_in[4];

    float* x = (float*)d_out;
    char* w = (char*)d_ws;
    size_t o = 0;
    auto alloc = [&](size_t bytes) { char* c = w + o; o = (o + bytes + 255) & ~(size_t)255; return c; };
    float* r      = (float*)alloc(VEC_N * 4);
    float* p      = (float*)alloc(VEC_N * 4);
    float* Ap     = (float*)alloc(VEC_N * 4);
    float* scal   = (float*)alloc(512);
    int*   cnt    = (int*)alloc(M_NODES * 4);
    int*   offa   = (int*)alloc((M_NODES + 1) * 4);
    int*   cursor = (int*)alloc(M_NODES * 4);
    int*   wk     = (int*)alloc(N_INC * 4);
    int*   nb     = (int*)alloc(N_INC * 4);
    float* diag   = (float*)alloc((size_t)M_NODES * 64 * 4);
    __half* Call  = (__half*)alloc((size_t)N_INC * 64 * 2);   // C | Ct
    size_t ghBytes = (size_t)N_INC * 64 * 2;
    int haveGH = (o + ghBytes) <= ws_size;
    __half* GH = haveGH ? (__half*)alloc(ghBytes) : (__half*)Call;

    const int BLK = 256;
    const int grid_v   = (N4 + BLK - 1) / BLK;
    const int grid_e   = (E_EDGES + BLK - 1) / BLK;
    const int grid_m   = (M_NODES + BLK - 1) / BLK;
    const int grid_e8  = (E_EDGES * 8 + BLK - 1) / BLK;
    const int grid_m8  = (M_NODES * 8 + BLK - 1) / BLK;
    const int grid_m16 = (M_NODES * 16 + BLK - 1) / BLK;

    // ---- precompute (rebuilt every call) ----
    k_zero_scal<<<1, 128, 0, stream>>>(scal);
    k_zero_cnt<<<grid_m, BLK, 0, stream>>>(cnt);
    k_hist<<<grid_e, BLK, 0, stream>>>(src, dst, cnt);
    k_scan<<<1, SCAN_T, 0, stream>>>(cnt, offa, cursor);
    k_scatter<<<grid_e, BLK, 0, stream>>>(src, dst, cursor, wk, nb);
    k_buildC<<<grid_e8, BLK, 0, stream>>>(Rs, Rd, Call, GH, haveGH);
    if (haveGH)
        k_diagGH<<<grid_m8, BLK, 0, stream>>>(offa, wk, GH, diag);
    else
        k_diagR<<<grid_m8, BLK, 0, stream>>>(offa, wk, Rs, Rd, diag);

    // ---- CG ----
    k_matvec<<<grid_m16, BLK, 0, stream>>>(c0, Ap, offa, nb, wk, Call, diag,
                                           scal + 64 + 2 * 20);
    k_init_r<<<grid_v, BLK, 0, stream>>>((const float4*)c0, (const float4*)Ap,
                                         (float4*)x, (float4*)r, (float4*)p, scal);

    for (int t = 0; t < CG_ITERS; ++t) {
        float* rs_old = scal + 2 * t;
        float* rs_new = scal + 2 * (t + 1);
        float* pap    = scal + 64 + 2 * t;
        k_matvec<<<grid_m16, BLK, 0, stream>>>(p, Ap, offa, nb, wk, Call, diag, pap);
        k_update<<<grid_v, BLK, 0, stream>>>((float4*)x, (const float4*)p,
                                             (const float4*)Ap, (float4*)r,
                                             rs_old, pap, rs_new);
        if (t < CG_ITERS - 1)
            k_pupdate<<<grid_v, BLK, 0, stream>>>((float4*)p, (const float4*)r,
                                                  rs_old, rs_new);
    }
}

// Round 4
// 8179.527 us; speedup vs baseline: 1.0274x; 1.0274x over previous
//
#include <hip/hip_runtime.h>
#include <hip/hip_fp16.h>

#define E_EDGES   400000
#define M_NODES   50000
#define N_INC     800000
#define PER_B     400000
#define VEC_N     800000
#define N4        200000
#define N4_PER_B  100000
#define CG_ITERS  20
#define EPSF      1e-12f

// scal layout: rs[it][b] = scal[2*it+b] (it=0..20), pAp slot t: scal[64+2*t+b]

__device__ __forceinline__ float waveReduce(float v) {
#pragma unroll
    for (int off = 32; off > 0; off >>= 1)
        v += __shfl_down(v, off, 64);
    return v;
}

__global__ void k_zero_scal(float* __restrict__ s) {
    if (threadIdx.x < 128) s[threadIdx.x] = 0.0f;
}

__global__ void k_zero_cnt(int* __restrict__ cnt) {
    int i = blockIdx.x * blockDim.x + threadIdx.x;
    if (i < M_NODES) cnt[i] = 0;
}

__global__ void k_hist(const int* __restrict__ src, const int* __restrict__ dst,
                       int* __restrict__ cnt) {
    int e = blockIdx.x * blockDim.x + threadIdx.x;
    if (e < E_EDGES) {
        atomicAdd(&cnt[src[e]], 1);
        atomicAdd(&cnt[dst[e]], 1);
    }
}

#define SCAN_T 1024
__global__ void k_scan(const int* __restrict__ cnt, int* __restrict__ off,
                       int* __restrict__ cursor) {
    __shared__ int part[SCAN_T];
    int t = threadIdx.x;
    const int chunk = (M_NODES + SCAN_T - 1) / SCAN_T;
    int beg = t * chunk;
    int end = beg + chunk; if (end > M_NODES) end = M_NODES;
    if (beg > M_NODES) beg = M_NODES;
    int s = 0;
    for (int i = beg; i < end; ++i) s += cnt[i];
    part[t] = s;
    __syncthreads();
    for (int st = 1; st < SCAN_T; st <<= 1) {
        int v = (t >= st) ? part[t - st] : 0;
        __syncthreads();
        part[t] += v;
        __syncthreads();
    }
    int run = (t == 0) ? 0 : part[t - 1];
    for (int i = beg; i < end; ++i) {
        off[i] = run; cursor[i] = run;
        run += cnt[i];
    }
    if (t == SCAN_T - 1) off[M_NODES] = run;
}

// CSR slots: pos0[e] = slot at src (W=C, GH=G), pos1[e] = slot at dst (W=Ct, GH=H)
// nb[slot] = other endpoint; wk[slot] = e + side*E (only for diag fallback)
__global__ void k_scatter(const int* __restrict__ src, const int* __restrict__ dst,
                          int* __restrict__ cursor, int* __restrict__ pos0,
                          int* __restrict__ pos1, int* __restrict__ nb,
                          int* __restrict__ wk) {
    int e = blockIdx.x * blockDim.x + threadIdx.x;
    if (e < E_EDGES) {
        int s = src[e], t = dst[e];
        int p0 = atomicAdd(&cursor[s], 1);
        pos0[e] = p0; nb[p0] = t; wk[p0] = e;
        int p1 = atomicAdd(&cursor[t], 1);
        pos1[e] = p1; nb[p1] = s; wk[p1] = e + E_EDGES;
    }
}

// 8 lanes/edge, coalesced sequential R reads; scatter-write 128B blocks to CSR slots.
__global__ __launch_bounds__(256) void k_buildC(const float* __restrict__ Rs,
                                                const float* __restrict__ Rd,
                                                const int* __restrict__ pos0,
                                                const int* __restrict__ pos1,
                                                __half* __restrict__ Wc,
                                                __half* __restrict__ GHc, int haveGH) {
    int gt = blockIdx.x * blockDim.x + threadIdx.x;
    int e = gt >> 3, a = gt & 7;
    if (e >= E_EDGES) return;
    const float* rs = Rs + ((size_t)e << 6);
    const float* rd = Rd + ((size_t)e << 6);
    float C[8], Ct[8], G[8], H[8];
#pragma unroll
    for (int j = 0; j < 8; ++j) { C[j] = 0; Ct[j] = 0; G[j] = 0; H[j] = 0; }
#pragma unroll
    for (int c = 0; c < 8; ++c) {
        float xs = rs[c * 8 + a];
        float xd = rd[c * 8 + a];
        float4 s0 = *(const float4*)(rs + c * 8);
        float4 s1 = *(const float4*)(rs + c * 8 + 4);
        float4 d0 = *(const float4*)(rd + c * 8);
        float4 d1 = *(const float4*)(rd + c * 8 + 4);
        C[0] += xs * d0.x; C[1] += xs * d0.y; C[2] += xs * d0.z; C[3] += xs * d0.w;
        C[4] += xs * d1.x; C[5] += xs * d1.y; C[6] += xs * d1.z; C[7] += xs * d1.w;
        Ct[0] += xd * s0.x; Ct[1] += xd * s0.y; Ct[2] += xd * s0.z; Ct[3] += xd * s0.w;
        Ct[4] += xd * s1.x; Ct[5] += xd * s1.y; Ct[6] += xd * s1.z; Ct[7] += xd * s1.w;
        G[0] += xs * s0.x; G[1] += xs * s0.y; G[2] += xs * s0.z; G[3] += xs * s0.w;
        G[4] += xs * s1.x; G[5] += xs * s1.y; G[6] += xs * s1.z; G[7] += xs * s1.w;
        H[0] += xd * d0.x; H[1] += xd * d0.y; H[2] += xd * d0.z; H[3] += xd * d0.w;
        H[4] += xd * d1.x; H[5] += xd * d1.y; H[6] += xd * d1.z; H[7] += xd * d1.w;
    }
    size_t s0o = (size_t)pos0[e] << 6;
    size_t s1o = (size_t)pos1[e] << 6;
    union { float4 f; __half2 h[4]; } u;
#pragma unroll
    for (int k = 0; k < 4; ++k) u.h[k] = __floats2half2_rn(C[2 * k], C[2 * k + 1]);
    *(float4*)(Wc + s0o + (a << 3)) = u.f;
#pragma unroll
    for (int k = 0; k < 4; ++k) u.h[k] = __floats2half2_rn(Ct[2 * k], Ct[2 * k + 1]);
    *(float4*)(Wc + s1o + (a << 3)) = u.f;
    if (haveGH) {
#pragma unroll
        for (int k = 0; k < 4; ++k) u.h[k] = __floats2half2_rn(G[2 * k], G[2 * k + 1]);
        *(float4*)(GHc + s0o + (a << 3)) = u.f;
#pragma unroll
        for (int k = 0; k < 4; ++k) u.h[k] = __floats2half2_rn(H[2 * k], H[2 * k + 1]);
        *(float4*)(GHc + s1o + (a << 3)) = u.f;
    }
}

// diag from CSR-streamed GH: wave per node, lane (g,a) accumulates rows from subset g.
__global__ __launch_bounds__(256) void k_diagS(const int* __restrict__ off,
                                               const __half* __restrict__ GHc,
                                               float* __restrict__ diag) {
    int wave = (blockIdx.x * blockDim.x + threadIdx.x) >> 6;
    int lane = threadIdx.x & 63;
    int g = lane >> 3, a = lane & 7;
    int m = wave;
    if (m >= M_NODES) return;
    float D[8];
#pragma unroll
    for (int j = 0; j < 8; ++j) D[j] = 0.0f;
    int beg = off[m], end = off[m + 1];
    for (int i = beg + g; i < end; i += 8) {
        union { float4 f; __half2 h[4]; } u;
        u.f = *(const float4*)(GHc + ((size_t)i << 6) + (a << 3));
        float2 w0 = __half22float2(u.h[0]);
        float2 w1 = __half22float2(u.h[1]);
        float2 w2 = __half22float2(u.h[2]);
        float2 w3 = __half22float2(u.h[3]);
        D[0] += w0.x; D[1] += w0.y; D[2] += w1.x; D[3] += w1.y;
        D[4] += w2.x; D[5] += w2.y; D[6] += w3.x; D[7] += w3.y;
    }
#pragma unroll
    for (int j = 0; j < 8; ++j) {
        D[j] += __shfl_xor(D[j], 8, 64);
        D[j] += __shfl_xor(D[j], 16, 64);
        D[j] += __shfl_xor(D[j], 32, 64);
    }
    if (g == 0) {
        D[a] += 1.0f;
        float* dout = diag + ((size_t)m << 6) + (a << 3);
        *(float4*)dout = make_float4(D[0], D[1], D[2], D[3]);
        *(float4*)(dout + 4) = make_float4(D[4], D[5], D[6], D[7]);
    }
}

// fallback diag straight from R (random gathers, runs once)
__global__ void k_diagR(const int* __restrict__ off, const int* __restrict__ wk,
                        const float* __restrict__ Rs, const float* __restrict__ Rd,
                        float* __restrict__ diag) {
    int gt = blockIdx.x * blockDim.x + threadIdx.x;
    int m = gt >> 3, a = gt & 7;
    if (m >= M_NODES) return;
    float D[8];
#pragma unroll
    for (int j = 0; j < 8; ++j) D[j] = 0.0f;
    int beg = off[m], end = off[m + 1];
    for (int i = beg; i < end; ++i) {
        int k = wk[i];
        int side = (k >= E_EDGES);
        int e = k - (side ? E_EDGES : 0);
        const float* R = (side ? Rd : Rs) + ((size_t)e << 6);
#pragma unroll
        for (int c = 0; c < 8; ++c) {
            float xa = R[c * 8 + a];
            float4 y0 = *(const float4*)(R + c * 8);
            float4 y1 = *(const float4*)(R + c * 8 + 4);
            D[0] += xa * y0.x; D[1] += xa * y0.y; D[2] += xa * y0.z; D[3] += xa * y0.w;
            D[4] += xa * y1.x; D[5] += xa * y1.y; D[6] += xa * y1.z; D[7] += xa * y1.w;
        }
    }
    D[a] += 1.0f;
    float* dout = diag + ((size_t)m << 6) + (a << 3);
    *(float4*)dout = make_float4(D[0], D[1], D[2], D[3]);
    *(float4*)(dout + 4) = make_float4(D[4], D[5], D[6], D[7]);
}

// matvec: one WAVE per node. Lane (g,a): g=incidence subgroup, a=output row.
// W streamed in CSR order (1KB contiguous per wave-iter), 8 incidences in flight.
// Ap_m = diag_m p_m - sum_i W_i p_nb(i); pAp accumulated (block-reduced) into pap[0/1].
__global__ __launch_bounds__(256) void k_matvec(const float* __restrict__ pv,
                                                float* __restrict__ Ap,
                                                const int* __restrict__ off,
                                                const int* __restrict__ nbA,
                                                const __half* __restrict__ Wc,
                                                const float* __restrict__ diag,
                                                float* __restrict__ pap) {
    __shared__ float red[8];
    int wave = (blockIdx.x * blockDim.x + threadIdx.x) >> 6;
    int lane = threadIdx.x & 63;
    int g = lane >> 3, a = lane & 7;
    int m = wave;
    float d0 = 0.0f, d1 = 0.0f;
    if (m < M_NODES) {
        int beg = off[m], end = off[m + 1];
        float acc0 = 0.0f, acc1 = 0.0f;
        for (int i = beg + g; i < end; i += 8) {
            int n = nbA[i];
            union { float4 f; __half2 h[4]; } u;
            u.f = *(const float4*)(Wc + ((size_t)i << 6) + (a << 3));
            const float* pn0 = pv + (n << 3);
            const float* pn1 = pv + PER_B + (n << 3);
            float4 x0 = *(const float4*)pn0, x1 = *(const float4*)(pn0 + 4);
            float4 y0 = *(const float4*)pn1, y1 = *(const float4*)(pn1 + 4);
            float2 w0 = __half22float2(u.h[0]);
            float2 w1 = __half22float2(u.h[1]);
            float2 w2 = __half22float2(u.h[2]);
            float2 w3 = __half22float2(u.h[3]);
            acc0 += w0.x * x0.x + w0.y * x0.y + w1.x * x0.z + w1.y * x0.w
                  + w2.x * x1.x + w2.y * x1.y + w3.x * x1.z + w3.y * x1.w;
            acc1 += w0.x * y0.x + w0.y * y0.y + w1.x * y0.z + w1.y * y0.w
                  + w2.x * y1.x + w2.y * y1.y + w3.x * y1.z + w3.y * y1.w;
        }
        // reduce edge sums across the 8 subgroups (lanes differing in bits 3..5)
        acc0 += __shfl_xor(acc0, 8, 64);  acc1 += __shfl_xor(acc1, 8, 64);
        acc0 += __shfl_xor(acc0, 16, 64); acc1 += __shfl_xor(acc1, 16, 64);
        acc0 += __shfl_xor(acc0, 32, 64); acc1 += __shfl_xor(acc1, 32, 64);
        // diag part
        const float* dg = diag + ((size_t)m << 6) + (a << 3);
        float4 g0 = *(const float4*)dg;
        float4 g1 = *(const float4*)(dg + 4);
        const float* pm0 = pv + (m << 3);
        const float* pm1 = pv + PER_B + (m << 3);
        float4 q0 = *(const float4*)pm0, q1 = *(const float4*)(pm0 + 4);
        float4 s0 = *(const float4*)pm1, s1 = *(const float4*)(pm1 + 4);
        float di0 = g0.x * q0.x + g0.y * q0.y + g0.z * q0.z + g0.w * q0.w
                  + g1.x * q1.x + g1.y * q1.y + g1.z * q1.z + g1.w * q1.w;
        float di1 = g0.x * s0.x + g0.y * s0.y + g0.z * s0.z + g0.w * s0.w
                  + g1.x * s1.x + g1.y * s1.y + g1.z * s1.z + g1.w * s1.w;
        if (g == 0) {
            float ap0 = di0 - acc0;
            Ap[(m << 3) + a] = ap0;
            d0 = pv[(m << 3) + a] * ap0;
        }
        if (g == 1) {
            float ap1 = di1 - acc1;
            Ap[PER_B + (m << 3) + a] = ap1;
            d1 = pv[PER_B + (m << 3) + a] * ap1;
        }
    }
    d0 = waveReduce(d0);
    d1 = waveReduce(d1);
    int w = threadIdx.x >> 6;
    if (lane == 0) { red[2 * w] = d0; red[2 * w + 1] = d1; }
    __syncthreads();
    if (threadIdx.x == 0) {
        float t0 = red[0] + red[2] + red[4] + red[6];
        float t1 = red[1] + red[3] + red[5] + red[7];
        if (t0 != 0.0f) atomicAdd(&pap[0], t0);
        if (t1 != 0.0f) atomicAdd(&pap[1], t1);
    }
}

// x = c0 ; r = p = c0 - Ap ; rs0 += r.r
__global__ void k_init_r(const float4* __restrict__ c0, const float4* __restrict__ Ap,
                         float4* __restrict__ x, float4* __restrict__ r,
                         float4* __restrict__ p, float* __restrict__ rs0) {
    int i = blockIdx.x * blockDim.x + threadIdx.x;
    float s0 = 0.0f, s1 = 0.0f;
    if (i < N4) {
        float4 c = c0[i];
        float4 a = Ap[i];
        float4 rv = make_float4(c.x - a.x, c.y - a.y, c.z - a.z, c.w - a.w);
        x[i] = c; r[i] = rv; p[i] = rv;
        float d = rv.x * rv.x + rv.y * rv.y + rv.z * rv.z + rv.w * rv.w;
        if (i < N4_PER_B) s0 = d; else s1 = d;
    }
    s0 = waveReduce(s0);
    s1 = waveReduce(s1);
    if ((threadIdx.x & 63) == 0) {
        if (s0 != 0.0f) atomicAdd(&rs0[0], s0);
        if (s1 != 0.0f) atomicAdd(&rs0[1], s1);
    }
}

// alpha per-thread; x += a p ; r -= a Ap ; rsnew += r.r
__global__ void k_update(float4* __restrict__ x, const float4* __restrict__ p,
                         const float4* __restrict__ Ap, float4* __restrict__ r,
                         const float* __restrict__ rsold, const float* __restrict__ pap,
                         float* __restrict__ rsnew) {
    int i = blockIdx.x * blockDim.x + threadIdx.x;
    float s0 = 0.0f, s1 = 0.0f;
    if (i < N4) {
        int b = (i < N4_PER_B) ? 0 : 1;
        float al = rsold[b] / (pap[b] + EPSF);
        float4 xv = x[i], pv = p[i], av = Ap[i], rv = r[i];
        xv.x += al * pv.x; xv.y += al * pv.y; xv.z += al * pv.z; xv.w += al * pv.w;
        rv.x -= al * av.x; rv.y -= al * av.y; rv.z -= al * av.z; rv.w -= al * av.w;
        x[i] = xv; r[i] = rv;
        float d = rv.x * rv.x + rv.y * rv.y + rv.z * rv.z + rv.w * rv.w;
        if (b == 0) s0 = d; else s1 = d;
    }
    s0 = waveReduce(s0);
    s1 = waveReduce(s1);
    if ((threadIdx.x & 63) == 0) {
        if (s0 != 0.0f) atomicAdd(&rsnew[0], s0);
        if (s1 != 0.0f) atomicAdd(&rsnew[1], s1);
    }
}

// beta per-thread; p = r + beta p
__global__ void k_pupdate(float4* __restrict__ p, const float4* __restrict__ r,
                          const float* __restrict__ rsold, const float* __restrict__ rsnew) {
    int i = blockIdx.x * blockDim.x + threadIdx.x;
    if (i < N4) {
        int b = (i < N4_PER_B) ? 0 : 1;
        float be = rsnew[b] / (rsold[b] + EPSF);
        float4 rv = r[i], pv = p[i];
        p[i] = make_float4(rv.x + be * pv.x, rv.y + be * pv.y,
                           rv.z + be * pv.z, rv.w + be * pv.w);
    }
}

extern "C" void kernel_launch(void* const* d_in, const int* in_sizes, int n_in,
                              void* d_out, int out_size, void* d_ws, size_t ws_size,
                              hipStream_t stream) {
    const float* c0 = (const float*)d_in[0];
    const int* src  = (const int*)d_in[1];
    const int* dst  = (const int*)d_in[2];
    const float* Rs = (const float*)d_in[3];
    const float* Rd = (const float*)d_in[4];

    float* x = (float*)d_out;
    char* w = (char*)d_ws;
    size_t o = 0;
    auto alloc = [&](size_t bytes) { char* c = w + o; o = (o + bytes + 255) & ~(size_t)255; return c; };
    float* r      = (float*)alloc(VEC_N * 4);
    float* p      = (float*)alloc(VEC_N * 4);
    float* Ap     = (float*)alloc(VEC_N * 4);
    float* scal   = (float*)alloc(512);
    int*   cnt    = (int*)alloc(M_NODES * 4);
    int*   offa   = (int*)alloc((M_NODES + 1) * 4);
    int*   cursor = (int*)alloc(M_NODES * 4);
    int*   pos0   = (int*)alloc(E_EDGES * 4);
    int*   pos1   = (int*)alloc(E_EDGES * 4);
    int*   wk     = (int*)alloc(N_INC * 4);
    int*   nb     = (int*)alloc(N_INC * 4);
    float* diag   = (float*)alloc((size_t)M_NODES * 64 * 4);
    __half* Wc    = (__half*)alloc((size_t)N_INC * 64 * 2);   // CSR-ordered C/Ct
    size_t ghBytes = (size_t)N_INC * 64 * 2;
    int haveGH = (o + ghBytes) <= ws_size;
    __half* GHc = haveGH ? (__half*)alloc(ghBytes) : (__half*)Wc;

    const int BLK = 256;
    const int grid_v  = (N4 + BLK - 1) / BLK;
    const int grid_e  = (E_EDGES + BLK - 1) / BLK;
    const int grid_m  = (M_NODES + BLK - 1) / BLK;
    const int grid_e8 = (E_EDGES * 8 + BLK - 1) / BLK;
    const int grid_m8 = (M_NODES * 8 + BLK - 1) / BLK;
    const int grid_mw = (M_NODES * 64 + BLK - 1) / BLK;   // wave per node

    // ---- precompute (rebuilt every call) ----
    k_zero_scal<<<1, 128, 0, stream>>>(scal);
    k_zero_cnt<<<grid_m, BLK, 0, stream>>>(cnt);
    k_hist<<<grid_e, BLK, 0, stream>>>(src, dst, cnt);
    k_scan<<<1, SCAN_T, 0, stream>>>(cnt, offa, cursor);
    k_scatter<<<grid_e, BLK, 0, stream>>>(src, dst, cursor, pos0, pos1, nb, wk);
    k_buildC<<<grid_e8, BLK, 0, stream>>>(Rs, Rd, pos0, pos1, Wc, GHc, haveGH);
    if (haveGH)
        k_diagS<<<grid_mw, BLK, 0, stream>>>(offa, GHc, diag);
    else
        k_diagR<<<grid_m8, BLK, 0, stream>>>(offa, wk, Rs, Rd, diag);

    // ---- CG ----
    k_matvec<<<grid_mw, BLK, 0, stream>>>(c0, Ap, offa, nb, Wc, diag,
                                          scal + 64 + 2 * 20);
    k_init_r<<<grid_v, BLK, 0, stream>>>((const float4*)c0, (const float4*)Ap,
                                         (float4*)x, (float4*)r, (float4*)p, scal);

    for (int t = 0; t < CG_ITERS; ++t) {
        float* rs_old = scal + 2 * t;
        float* rs_new = scal + 2 * (t + 1);
        float* pap    = scal + 64 + 2 * t;
        k_matvec<<<grid_mw, BLK, 0, stream>>>(p, Ap, offa, nb, Wc, diag, pap);
        k_update<<<grid_v, BLK, 0, stream>>>((float4*)x, (const float4*)p,
                                             (const float4*)Ap, (float4*)r,
                                             rs_old, pap, rs_new);
        if (t < CG_ITERS - 1)
            k_pupdate<<<grid_v, BLK, 0, stream>>>((float4*)p, (const float4*)r,
                                                  rs_old, rs_new);
    }
}

// Round 5
// 5684.832 us; speedup vs baseline: 1.4783x; 1.4388x over previous
//
#include <hip/hip_runtime.h>
#include <hip/hip_fp16.h>

#define E_EDGES   400000
#define M_NODES   50000
#define N_INC     800000
#define PER_B     400000
#define VEC_N     800000
#define N4        200000
#define N4_PER_B  100000
#define CG_ITERS  20
#define EPSF      1e-12f

// scal layout: rs[it][b] = scal[2*it+b] (it=0..20), pAp slot t: scal[64+2*t+b]

__device__ __forceinline__ float waveReduce(float v) {
#pragma unroll
    for (int off = 32; off > 0; off >>= 1)
        v += __shfl_down(v, off, 64);
    return v;
}

__global__ void k_zero_scal(float* __restrict__ s) {
    if (threadIdx.x < 128) s[threadIdx.x] = 0.0f;
}

__global__ void k_zero_cnt(int* __restrict__ cnt) {
    int i = blockIdx.x * blockDim.x + threadIdx.x;
    if (i < M_NODES) cnt[i] = 0;
}

__global__ void k_hist(const int* __restrict__ src, const int* __restrict__ dst,
                       int* __restrict__ cnt) {
    int e = blockIdx.x * blockDim.x + threadIdx.x;
    if (e < E_EDGES) {
        atomicAdd(&cnt[src[e]], 1);
        atomicAdd(&cnt[dst[e]], 1);
    }
}

#define SCAN_T 1024
__global__ void k_scan(const int* __restrict__ cnt, int* __restrict__ off,
                       int* __restrict__ cursor) {
    __shared__ int part[SCAN_T];
    int t = threadIdx.x;
    const int chunk = (M_NODES + SCAN_T - 1) / SCAN_T;
    int beg = t * chunk;
    int end = beg + chunk; if (end > M_NODES) end = M_NODES;
    if (beg > M_NODES) beg = M_NODES;
    int s = 0;
    for (int i = beg; i < end; ++i) s += cnt[i];
    part[t] = s;
    __syncthreads();
    for (int st = 1; st < SCAN_T; st <<= 1) {
        int v = (t >= st) ? part[t - st] : 0;
        __syncthreads();
        part[t] += v;
        __syncthreads();
    }
    int run = (t == 0) ? 0 : part[t - 1];
    for (int i = beg; i < end; ++i) {
        off[i] = run; cursor[i] = run;
        run += cnt[i];
    }
    if (t == SCAN_T - 1) off[M_NODES] = run;
}

// CSR slots: pos0[e] = slot at src (W=C, GH=G), pos1[e] = slot at dst (W=Ct, GH=H)
__global__ void k_scatter(const int* __restrict__ src, const int* __restrict__ dst,
                          int* __restrict__ cursor, int* __restrict__ pos0,
                          int* __restrict__ pos1, int* __restrict__ nb,
                          int* __restrict__ wk) {
    int e = blockIdx.x * blockDim.x + threadIdx.x;
    if (e < E_EDGES) {
        int s = src[e], t = dst[e];
        int p0 = atomicAdd(&cursor[s], 1);
        pos0[e] = p0; nb[p0] = t; wk[p0] = e;
        int p1 = atomicAdd(&cursor[t], 1);
        pos1[e] = p1; nb[p1] = s; wk[p1] = e + E_EDGES;
    }
}

// 8 lanes/edge, coalesced sequential R reads; scatter-write 128B blocks to CSR slots.
__global__ __launch_bounds__(256) void k_buildC(const float* __restrict__ Rs,
                                                const float* __restrict__ Rd,
                                                const int* __restrict__ pos0,
                                                const int* __restrict__ pos1,
                                                __half* __restrict__ Wc,
                                                __half* __restrict__ GHc, int haveGH) {
    int gt = blockIdx.x * blockDim.x + threadIdx.x;
    int e = gt >> 3, a = gt & 7;
    if (e >= E_EDGES) return;
    const float* rs = Rs + ((size_t)e << 6);
    const float* rd = Rd + ((size_t)e << 6);
    float C[8], Ct[8], G[8], H[8];
#pragma unroll
    for (int j = 0; j < 8; ++j) { C[j] = 0; Ct[j] = 0; G[j] = 0; H[j] = 0; }
#pragma unroll
    for (int c = 0; c < 8; ++c) {
        float xs = rs[c * 8 + a];
        float xd = rd[c * 8 + a];
        float4 s0 = *(const float4*)(rs + c * 8);
        float4 s1 = *(const float4*)(rs + c * 8 + 4);
        float4 d0 = *(const float4*)(rd + c * 8);
        float4 d1 = *(const float4*)(rd + c * 8 + 4);
        C[0] += xs * d0.x; C[1] += xs * d0.y; C[2] += xs * d0.z; C[3] += xs * d0.w;
        C[4] += xs * d1.x; C[5] += xs * d1.y; C[6] += xs * d1.z; C[7] += xs * d1.w;
        Ct[0] += xd * s0.x; Ct[1] += xd * s0.y; Ct[2] += xd * s0.z; Ct[3] += xd * s0.w;
        Ct[4] += xd * s1.x; Ct[5] += xd * s1.y; Ct[6] += xd * s1.z; Ct[7] += xd * s1.w;
        G[0] += xs * s0.x; G[1] += xs * s0.y; G[2] += xs * s0.z; G[3] += xs * s0.w;
        G[4] += xs * s1.x; G[5] += xs * s1.y; G[6] += xs * s1.z; G[7] += xs * s1.w;
        H[0] += xd * d0.x; H[1] += xd * d0.y; H[2] += xd * d0.z; H[3] += xd * d0.w;
        H[4] += xd * d1.x; H[5] += xd * d1.y; H[6] += xd * d1.z; H[7] += xd * d1.w;
    }
    size_t s0o = (size_t)pos0[e] << 6;
    size_t s1o = (size_t)pos1[e] << 6;
    union { float4 f; __half2 h[4]; } u;
#pragma unroll
    for (int k = 0; k < 4; ++k) u.h[k] = __floats2half2_rn(C[2 * k], C[2 * k + 1]);
    *(float4*)(Wc + s0o + (a << 3)) = u.f;
#pragma unroll
    for (int k = 0; k < 4; ++k) u.h[k] = __floats2half2_rn(Ct[2 * k], Ct[2 * k + 1]);
    *(float4*)(Wc + s1o + (a << 3)) = u.f;
    if (haveGH) {
#pragma unroll
        for (int k = 0; k < 4; ++k) u.h[k] = __floats2half2_rn(G[2 * k], G[2 * k + 1]);
        *(float4*)(GHc + s0o + (a << 3)) = u.f;
#pragma unroll
        for (int k = 0; k < 4; ++k) u.h[k] = __floats2half2_rn(H[2 * k], H[2 * k + 1]);
        *(float4*)(GHc + s1o + (a << 3)) = u.f;
    }
}

// diag from CSR-streamed GH: wave per node, lane (g,a) accumulates rows from subset g.
__global__ __launch_bounds__(256) void k_diagS(const int* __restrict__ off,
                                               const __half* __restrict__ GHc,
                                               float* __restrict__ diag) {
    int wave = (blockIdx.x * blockDim.x + threadIdx.x) >> 6;
    int lane = threadIdx.x & 63;
    int g = lane >> 3, a = lane & 7;
    int m = wave;
    if (m >= M_NODES) return;
    float D[8];
#pragma unroll
    for (int j = 0; j < 8; ++j) D[j] = 0.0f;
    int beg = off[m], end = off[m + 1];
    for (int i = beg + g; i < end; i += 8) {
        union { float4 f; __half2 h[4]; } u;
        u.f = *(const float4*)(GHc + ((size_t)i << 6) + (a << 3));
        float2 w0 = __half22float2(u.h[0]);
        float2 w1 = __half22float2(u.h[1]);
        float2 w2 = __half22float2(u.h[2]);
        float2 w3 = __half22float2(u.h[3]);
        D[0] += w0.x; D[1] += w0.y; D[2] += w1.x; D[3] += w1.y;
        D[4] += w2.x; D[5] += w2.y; D[6] += w3.x; D[7] += w3.y;
    }
#pragma unroll
    for (int j = 0; j < 8; ++j) {
        D[j] += __shfl_xor(D[j], 8, 64);
        D[j] += __shfl_xor(D[j], 16, 64);
        D[j] += __shfl_xor(D[j], 32, 64);
    }
    if (g == 0) {
        D[a] += 1.0f;
        float* dout = diag + ((size_t)m << 6) + (a << 3);
        *(float4*)dout = make_float4(D[0], D[1], D[2], D[3]);
        *(float4*)(dout + 4) = make_float4(D[4], D[5], D[6], D[7]);
    }
}

// fallback diag straight from R (random gathers, runs once)
__global__ void k_diagR(const int* __restrict__ off, const int* __restrict__ wk,
                        const float* __restrict__ Rs, const float* __restrict__ Rd,
                        float* __restrict__ diag) {
    int gt = blockIdx.x * blockDim.x + threadIdx.x;
    int m = gt >> 3, a = gt & 7;
    if (m >= M_NODES) return;
    float D[8];
#pragma unroll
    for (int j = 0; j < 8; ++j) D[j] = 0.0f;
    int beg = off[m], end = off[m + 1];
    for (int i = beg; i < end; ++i) {
        int k = wk[i];
        int side = (k >= E_EDGES);
        int e = k - (side ? E_EDGES : 0);
        const float* R = (side ? Rd : Rs) + ((size_t)e << 6);
#pragma unroll
        for (int c = 0; c < 8; ++c) {
            float xa = R[c * 8 + a];
            float4 y0 = *(const float4*)(R + c * 8);
            float4 y1 = *(const float4*)(R + c * 8 + 4);
            D[0] += xa * y0.x; D[1] += xa * y0.y; D[2] += xa * y0.z; D[3] += xa * y0.w;
            D[4] += xa * y1.x; D[5] += xa * y1.y; D[6] += xa * y1.z; D[7] += xa * y1.w;
        }
    }
    D[a] += 1.0f;
    float* dout = diag + ((size_t)m << 6) + (a << 3);
    *(float4*)dout = make_float4(D[0], D[1], D[2], D[3]);
    *(float4*)(dout + 4) = make_float4(D[4], D[5], D[6], D[7]);
}

// ---- matvec phase A: thread per incidence. y_i = W_i * p[nb_i] (both batches).
// W streamed sequentially (incidence order == storage order). Straight-line,
// 13 loads all independent except the single nb->p hop. y stored as 8 x half2
// (x=batch0, y=batch1), 32B contiguous per incidence.
__global__ __launch_bounds__(256) void k_ymv(const float* __restrict__ pv,
                                             const int* __restrict__ nbA,
                                             const __half* __restrict__ Wc,
                                             __half2* __restrict__ y) {
    int i = blockIdx.x * blockDim.x + threadIdx.x;
    if (i >= N_INC) return;
    int n = nbA[i];
    const __half* wp = Wc + ((size_t)i << 6);
    float4 wf[8];
#pragma unroll
    for (int k = 0; k < 8; ++k) wf[k] = *(const float4*)(wp + (k << 3));
    const float* pn0 = pv + (n << 3);
    const float* pn1 = pv + PER_B + (n << 3);
    float4 x0 = *(const float4*)pn0, x1 = *(const float4*)(pn0 + 4);
    float4 y0 = *(const float4*)pn1, y1 = *(const float4*)(pn1 + 4);
    __half2 out[8];
#pragma unroll
    for (int a = 0; a < 8; ++a) {
        union { float4 f; __half2 h[4]; } u; u.f = wf[a];
        float2 w0 = __half22float2(u.h[0]);
        float2 w1 = __half22float2(u.h[1]);
        float2 w2 = __half22float2(u.h[2]);
        float2 w3 = __half22float2(u.h[3]);
        float a0 = w0.x * x0.x + w0.y * x0.y + w1.x * x0.z + w1.y * x0.w
                 + w2.x * x1.x + w2.y * x1.y + w3.x * x1.z + w3.y * x1.w;
        float a1 = w0.x * y0.x + w0.y * y0.y + w1.x * y0.z + w1.y * y0.w
                 + w2.x * y1.x + w2.y * y1.y + w3.x * y1.z + w3.y * y1.w;
        out[a] = __floats2half2_rn(a0, a1);
    }
    float4* yo = (float4*)(y + ((size_t)i << 3));
    yo[0] = *(float4*)&out[0];
    yo[1] = *(float4*)&out[4];
}

// ---- matvec phase B: thread per (node m, row a). Ap = diag*p - sum(y segment).
// y segment is CSR-contiguous; 4B half2 loads coalesced across a-lanes, no
// dependent chain (addresses from loop index). Fused pAp dot.
__global__ __launch_bounds__(256) void k_apmv(const float* __restrict__ pv,
                                              float* __restrict__ Ap,
                                              const int* __restrict__ off,
                                              const __half2* __restrict__ y,
                                              const float* __restrict__ diag,
                                              float* __restrict__ pap) {
    int gt = blockIdx.x * blockDim.x + threadIdx.x;
    int m = gt >> 3, a = gt & 7;
    float d0 = 0.0f, d1 = 0.0f;
    if (m < M_NODES) {
        int beg = off[m], end = off[m + 1];
        float acc0 = 0.0f, acc1 = 0.0f;
#pragma unroll 4
        for (int i = beg; i < end; ++i) {
            float2 f = __half22float2(y[((size_t)i << 3) + a]);
            acc0 += f.x; acc1 += f.y;
        }
        const float* dg = diag + ((size_t)m << 6) + (a << 3);
        float4 g0 = *(const float4*)dg;
        float4 g1 = *(const float4*)(dg + 4);
        const float* pm0 = pv + (m << 3);
        const float* pm1 = pv + PER_B + (m << 3);
        float4 q0 = *(const float4*)pm0, q1 = *(const float4*)(pm0 + 4);
        float4 s0 = *(const float4*)pm1, s1 = *(const float4*)(pm1 + 4);
        float ap0 = g0.x * q0.x + g0.y * q0.y + g0.z * q0.z + g0.w * q0.w
                  + g1.x * q1.x + g1.y * q1.y + g1.z * q1.z + g1.w * q1.w - acc0;
        float ap1 = g0.x * s0.x + g0.y * s0.y + g0.z * s0.z + g0.w * s0.w
                  + g1.x * s1.x + g1.y * s1.y + g1.z * s1.z + g1.w * s1.w - acc1;
        Ap[(m << 3) + a] = ap0;
        Ap[PER_B + (m << 3) + a] = ap1;
        d0 = pm0[a] * ap0;
        d1 = pm1[a] * ap1;
    }
    d0 = waveReduce(d0);
    d1 = waveReduce(d1);
    if ((threadIdx.x & 63) == 0) {
        if (d0 != 0.0f) atomicAdd(&pap[0], d0);
        if (d1 != 0.0f) atomicAdd(&pap[1], d1);
    }
}

// x = c0 ; r = p = c0 - Ap ; rs0 += r.r
__global__ void k_init_r(const float4* __restrict__ c0, const float4* __restrict__ Ap,
                         float4* __restrict__ x, float4* __restrict__ r,
                         float4* __restrict__ p, float* __restrict__ rs0) {
    int i = blockIdx.x * blockDim.x + threadIdx.x;
    float s0 = 0.0f, s1 = 0.0f;
    if (i < N4) {
        float4 c = c0[i];
        float4 a = Ap[i];
        float4 rv = make_float4(c.x - a.x, c.y - a.y, c.z - a.z, c.w - a.w);
        x[i] = c; r[i] = rv; p[i] = rv;
        float d = rv.x * rv.x + rv.y * rv.y + rv.z * rv.z + rv.w * rv.w;
        if (i < N4_PER_B) s0 = d; else s1 = d;
    }
    s0 = waveReduce(s0);
    s1 = waveReduce(s1);
    if ((threadIdx.x & 63) == 0) {
        if (s0 != 0.0f) atomicAdd(&rs0[0], s0);
        if (s1 != 0.0f) atomicAdd(&rs0[1], s1);
    }
}

// alpha per-thread; x += a p ; r -= a Ap ; rsnew += r.r
__global__ void k_update(float4* __restrict__ x, const float4* __restrict__ p,
                         const float4* __restrict__ Ap, float4* __restrict__ r,
                         const float* __restrict__ rsold, const float* __restrict__ pap,
                         float* __restrict__ rsnew) {
    int i = blockIdx.x * blockDim.x + threadIdx.x;
    float s0 = 0.0f, s1 = 0.0f;
    if (i < N4) {
        int b = (i < N4_PER_B) ? 0 : 1;
        float al = rsold[b] / (pap[b] + EPSF);
        float4 xv = x[i], pv = p[i], av = Ap[i], rv = r[i];
        xv.x += al * pv.x; xv.y += al * pv.y; xv.z += al * pv.z; xv.w += al * pv.w;
        rv.x -= al * av.x; rv.y -= al * av.y; rv.z -= al * av.z; rv.w -= al * av.w;
        x[i] = xv; r[i] = rv;
        float d = rv.x * rv.x + rv.y * rv.y + rv.z * rv.z + rv.w * rv.w;
        if (b == 0) s0 = d; else s1 = d;
    }
    s0 = waveReduce(s0);
    s1 = waveReduce(s1);
    if ((threadIdx.x & 63) == 0) {
        if (s0 != 0.0f) atomicAdd(&rsnew[0], s0);
        if (s1 != 0.0f) atomicAdd(&rsnew[1], s1);
    }
}

// beta per-thread; p = r + beta p
__global__ void k_pupdate(float4* __restrict__ p, const float4* __restrict__ r,
                          const float* __restrict__ rsold, const float* __restrict__ rsnew) {
    int i = blockIdx.x * blockDim.x + threadIdx.x;
    if (i < N4) {
        int b = (i < N4_PER_B) ? 0 : 1;
        float be = rsnew[b] / (rsold[b] + EPSF);
        float4 rv = r[i], pv = p[i];
        p[i] = make_float4(rv.x + be * pv.x, rv.y + be * pv.y,
                           rv.z + be * pv.z, rv.w + be * pv.w);
    }
}

extern "C" void kernel_launch(void* const* d_in, const int* in_sizes, int n_in,
                              void* d_out, int out_size, void* d_ws, size_t ws_size,
                              hipStream_t stream) {
    const float* c0 = (const float*)d_in[0];
    const int* src  = (const int*)d_in[1];
    const int* dst  = (const int*)d_in[2];
    const float* Rs = (const float*)d_in[3];
    const float* Rd = (const float*)d_in[4];

    float* x = (float*)d_out;
    char* w = (char*)d_ws;
    size_t o = 0;
    auto alloc = [&](size_t bytes) { char* c = w + o; o = (o + bytes + 255) & ~(size_t)255; return c; };
    float* r      = (float*)alloc(VEC_N * 4);
    float* p      = (float*)alloc(VEC_N * 4);
    float* Ap     = (float*)alloc(VEC_N * 4);
    float* scal   = (float*)alloc(512);
    int*   cnt    = (int*)alloc(M_NODES * 4);
    int*   offa   = (int*)alloc((M_NODES + 1) * 4);
    int*   cursor = (int*)alloc(M_NODES * 4);
    int*   pos0   = (int*)alloc(E_EDGES * 4);
    int*   pos1   = (int*)alloc(E_EDGES * 4);
    int*   wk     = (int*)alloc(N_INC * 4);
    int*   nb     = (int*)alloc(N_INC * 4);
    float* diag   = (float*)alloc((size_t)M_NODES * 64 * 4);
    __half2* y    = (__half2*)alloc((size_t)N_INC * 8 * 4);   // 25.6 MB
    __half* Wc    = (__half*)alloc((size_t)N_INC * 64 * 2);   // CSR-ordered C/Ct
    size_t ghBytes = (size_t)N_INC * 64 * 2;
    int haveGH = (o + ghBytes) <= ws_size;
    __half* GHc = haveGH ? (__half*)alloc(ghBytes) : (__half*)Wc;

    const int BLK = 256;
    const int grid_v  = (N4 + BLK - 1) / BLK;
    const int grid_e  = (E_EDGES + BLK - 1) / BLK;
    const int grid_m  = (M_NODES + BLK - 1) / BLK;
    const int grid_e8 = (E_EDGES * 8 + BLK - 1) / BLK;
    const int grid_m8 = (M_NODES * 8 + BLK - 1) / BLK;
    const int grid_i  = (N_INC + BLK - 1) / BLK;
    const int grid_mw = (M_NODES * 64 + BLK - 1) / BLK;

    // ---- precompute (rebuilt every call) ----
    k_zero_scal<<<1, 128, 0, stream>>>(scal);
    k_zero_cnt<<<grid_m, BLK, 0, stream>>>(cnt);
    k_hist<<<grid_e, BLK, 0, stream>>>(src, dst, cnt);
    k_scan<<<1, SCAN_T, 0, stream>>>(cnt, offa, cursor);
    k_scatter<<<grid_e, BLK, 0, stream>>>(src, dst, cursor, pos0, pos1, nb, wk);
    k_buildC<<<grid_e8, BLK, 0, stream>>>(Rs, Rd, pos0, pos1, Wc, GHc, haveGH);
    if (haveGH)
        k_diagS<<<grid_mw, BLK, 0, stream>>>(offa, GHc, diag);
    else
        k_diagR<<<grid_m8, BLK, 0, stream>>>(offa, wk, Rs, Rd, diag);

    // ---- CG ----
    k_ymv<<<grid_i, BLK, 0, stream>>>(c0, nb, Wc, y);
    k_apmv<<<grid_m8, BLK, 0, stream>>>(c0, Ap, offa, y, diag, scal + 64 + 2 * 20);
    k_init_r<<<grid_v, BLK, 0, stream>>>((const float4*)c0, (const float4*)Ap,
                                         (float4*)x, (float4*)r, (float4*)p, scal);

    for (int t = 0; t < CG_ITERS; ++t) {
        float* rs_old = scal + 2 * t;
        float* rs_new = scal + 2 * (t + 1);
        float* pap    = scal + 64 + 2 * t;
        k_ymv<<<grid_i, BLK, 0, stream>>>(p, nb, Wc, y);
        k_apmv<<<grid_m8, BLK, 0, stream>>>(p, Ap, offa, y, diag, pap);
        k_update<<<grid_v, BLK, 0, stream>>>((float4*)x, (const float4*)p,
                                             (const float4*)Ap, (float4*)r,
                                             rs_old, pap, rs_new);
        if (t < CG_ITERS - 1)
            k_pupdate<<<grid_v, BLK, 0, stream>>>((float4*)p, (const float4*)r,
                                                  rs_old, rs_new);
    }
}

// Round 6
// 2207.039 us; speedup vs baseline: 3.8077x; 2.5758x over previous
//
#include <hip/hip_runtime.h>
#include <hip/hip_fp16.h>

#define E_EDGES   400000
#define M_NODES   50000
#define N_INC     800000
#define PER_B     400000
#define VEC_N     800000
#define N4        200000
#define N4_PER_B  100000
#define CG_ITERS  20
#define EPSF      1e-12f

// scal layout (1024 floats):
//   rs slots:  RS(t)  = scal + 16*t        (8 pairs: [2k]=batch0, [2k+1]=batch1), t=0..20
//   pAp slots: PAP(t) = scal + 512 + 16*t  (8 pairs), t=0..20
// Each reducing block atomically adds into pair (blockIdx & 7); consumers sum all 8.

__device__ __forceinline__ float waveReduce(float v) {
#pragma unroll
    for (int off = 32; off > 0; off >>= 1)
        v += __shfl_down(v, off, 64);
    return v;
}

// block-reduce (d0,d1) and add into slot pair (blockIdx&7) of base
__device__ __forceinline__ void blockReduceAdd(float d0, float d1, float* __restrict__ base) {
    __shared__ float red[8];
    d0 = waveReduce(d0);
    d1 = waveReduce(d1);
    int w = threadIdx.x >> 6, lane = threadIdx.x & 63;
    if (lane == 0) { red[2 * w] = d0; red[2 * w + 1] = d1; }
    __syncthreads();
    if (threadIdx.x == 0) {
        float t0 = red[0] + red[2] + red[4] + red[6];
        float t1 = red[1] + red[3] + red[5] + red[7];
        int s = (blockIdx.x & 7) << 1;
        atomicAdd(&base[s], t0);
        atomicAdd(&base[s + 1], t1);
    }
}

__device__ __forceinline__ float2 sumSlots(const float* __restrict__ base) {
    float a = 0.0f, b = 0.0f;
#pragma unroll
    for (int k = 0; k < 8; ++k) { a += base[2 * k]; b += base[2 * k + 1]; }
    return make_float2(a, b);
}

__global__ void k_zero_scal(float* __restrict__ s) {
    s[threadIdx.x] = 0.0f;   // <<<1,1024>>>
}

__global__ void k_zero_cnt(int* __restrict__ cnt) {
    int i = blockIdx.x * blockDim.x + threadIdx.x;
    if (i < M_NODES) cnt[i] = 0;
}

__global__ void k_hist(const int* __restrict__ src, const int* __restrict__ dst,
                       int* __restrict__ cnt) {
    int e = blockIdx.x * blockDim.x + threadIdx.x;
    if (e < E_EDGES) {
        atomicAdd(&cnt[src[e]], 1);
        atomicAdd(&cnt[dst[e]], 1);
    }
}

#define SCAN_T 1024
__global__ void k_scan(const int* __restrict__ cnt, int* __restrict__ off,
                       int* __restrict__ cursor) {
    __shared__ int part[SCAN_T];
    int t = threadIdx.x;
    const int chunk = (M_NODES + SCAN_T - 1) / SCAN_T;
    int beg = t * chunk;
    int end = beg + chunk; if (end > M_NODES) end = M_NODES;
    if (beg > M_NODES) beg = M_NODES;
    int s = 0;
    for (int i = beg; i < end; ++i) s += cnt[i];
    part[t] = s;
    __syncthreads();
    for (int st = 1; st < SCAN_T; st <<= 1) {
        int v = (t >= st) ? part[t - st] : 0;
        __syncthreads();
        part[t] += v;
        __syncthreads();
    }
    int run = (t == 0) ? 0 : part[t - 1];
    for (int i = beg; i < end; ++i) {
        off[i] = run; cursor[i] = run;
        run += cnt[i];
    }
    if (t == SCAN_T - 1) off[M_NODES] = run;
}

__global__ void k_scatter(const int* __restrict__ src, const int* __restrict__ dst,
                          int* __restrict__ cursor, int* __restrict__ pos0,
                          int* __restrict__ pos1, int* __restrict__ nb,
                          int* __restrict__ wk) {
    int e = blockIdx.x * blockDim.x + threadIdx.x;
    if (e < E_EDGES) {
        int s = src[e], t = dst[e];
        int p0 = atomicAdd(&cursor[s], 1);
        pos0[e] = p0; nb[p0] = t; wk[p0] = e;
        int p1 = atomicAdd(&cursor[t], 1);
        pos1[e] = p1; nb[p1] = s; wk[p1] = e + E_EDGES;
    }
}

// 8 lanes/edge, coalesced sequential R reads; scatter-write 128B blocks to CSR slots.
__global__ __launch_bounds__(256) void k_buildC(const float* __restrict__ Rs,
                                                const float* __restrict__ Rd,
                                                const int* __restrict__ pos0,
                                                const int* __restrict__ pos1,
                                                __half* __restrict__ Wc,
                                                __half* __restrict__ GHc, int haveGH) {
    int gt = blockIdx.x * blockDim.x + threadIdx.x;
    int e = gt >> 3, a = gt & 7;
    if (e >= E_EDGES) return;
    const float* rs = Rs + ((size_t)e << 6);
    const float* rd = Rd + ((size_t)e << 6);
    float C[8], Ct[8], G[8], H[8];
#pragma unroll
    for (int j = 0; j < 8; ++j) { C[j] = 0; Ct[j] = 0; G[j] = 0; H[j] = 0; }
#pragma unroll
    for (int c = 0; c < 8; ++c) {
        float xs = rs[c * 8 + a];
        float xd = rd[c * 8 + a];
        float4 s0 = *(const float4*)(rs + c * 8);
        float4 s1 = *(const float4*)(rs + c * 8 + 4);
        float4 d0 = *(const float4*)(rd + c * 8);
        float4 d1 = *(const float4*)(rd + c * 8 + 4);
        C[0] += xs * d0.x; C[1] += xs * d0.y; C[2] += xs * d0.z; C[3] += xs * d0.w;
        C[4] += xs * d1.x; C[5] += xs * d1.y; C[6] += xs * d1.z; C[7] += xs * d1.w;
        Ct[0] += xd * s0.x; Ct[1] += xd * s0.y; Ct[2] += xd * s0.z; Ct[3] += xd * s0.w;
        Ct[4] += xd * s1.x; Ct[5] += xd * s1.y; Ct[6] += xd * s1.z; Ct[7] += xd * s1.w;
        G[0] += xs * s0.x; G[1] += xs * s0.y; G[2] += xs * s0.z; G[3] += xs * s0.w;
        G[4] += xs * s1.x; G[5] += xs * s1.y; G[6] += xs * s1.z; G[7] += xs * s1.w;
        H[0] += xd * d0.x; H[1] += xd * d0.y; H[2] += xd * d0.z; H[3] += xd * d0.w;
        H[4] += xd * d1.x; H[5] += xd * d1.y; H[6] += xd * d1.z; H[7] += xd * d1.w;
    }
    size_t s0o = (size_t)pos0[e] << 6;
    size_t s1o = (size_t)pos1[e] << 6;
    union { float4 f; __half2 h[4]; } u;
#pragma unroll
    for (int k = 0; k < 4; ++k) u.h[k] = __floats2half2_rn(C[2 * k], C[2 * k + 1]);
    *(float4*)(Wc + s0o + (a << 3)) = u.f;
#pragma unroll
    for (int k = 0; k < 4; ++k) u.h[k] = __floats2half2_rn(Ct[2 * k], Ct[2 * k + 1]);
    *(float4*)(Wc + s1o + (a << 3)) = u.f;
    if (haveGH) {
#pragma unroll
        for (int k = 0; k < 4; ++k) u.h[k] = __floats2half2_rn(G[2 * k], G[2 * k + 1]);
        *(float4*)(GHc + s0o + (a << 3)) = u.f;
#pragma unroll
        for (int k = 0; k < 4; ++k) u.h[k] = __floats2half2_rn(H[2 * k], H[2 * k + 1]);
        *(float4*)(GHc + s1o + (a << 3)) = u.f;
    }
}

// diag from CSR-streamed GH: wave per node.
__global__ __launch_bounds__(256) void k_diagS(const int* __restrict__ off,
                                               const __half* __restrict__ GHc,
                                               float* __restrict__ diag) {
    int wave = (blockIdx.x * blockDim.x + threadIdx.x) >> 6;
    int lane = threadIdx.x & 63;
    int g = lane >> 3, a = lane & 7;
    int m = wave;
    if (m >= M_NODES) return;
    float D[8];
#pragma unroll
    for (int j = 0; j < 8; ++j) D[j] = 0.0f;
    int beg = off[m], end = off[m + 1];
    for (int i = beg + g; i < end; i += 8) {
        union { float4 f; __half2 h[4]; } u;
        u.f = *(const float4*)(GHc + ((size_t)i << 6) + (a << 3));
        float2 w0 = __half22float2(u.h[0]);
        float2 w1 = __half22float2(u.h[1]);
        float2 w2 = __half22float2(u.h[2]);
        float2 w3 = __half22float2(u.h[3]);
        D[0] += w0.x; D[1] += w0.y; D[2] += w1.x; D[3] += w1.y;
        D[4] += w2.x; D[5] += w2.y; D[6] += w3.x; D[7] += w3.y;
    }
#pragma unroll
    for (int j = 0; j < 8; ++j) {
        D[j] += __shfl_xor(D[j], 8, 64);
        D[j] += __shfl_xor(D[j], 16, 64);
        D[j] += __shfl_xor(D[j], 32, 64);
    }
    if (g == 0) {
        D[a] += 1.0f;
        float* dout = diag + ((size_t)m << 6) + (a << 3);
        *(float4*)dout = make_float4(D[0], D[1], D[2], D[3]);
        *(float4*)(dout + 4) = make_float4(D[4], D[5], D[6], D[7]);
    }
}

// fallback diag straight from R (runs once)
__global__ void k_diagR(const int* __restrict__ off, const int* __restrict__ wk,
                        const float* __restrict__ Rs, const float* __restrict__ Rd,
                        float* __restrict__ diag) {
    int gt = blockIdx.x * blockDim.x + threadIdx.x;
    int m = gt >> 3, a = gt & 7;
    if (m >= M_NODES) return;
    float D[8];
#pragma unroll
    for (int j = 0; j < 8; ++j) D[j] = 0.0f;
    int beg = off[m], end = off[m + 1];
    for (int i = beg; i < end; ++i) {
        int k = wk[i];
        int side = (k >= E_EDGES);
        int e = k - (side ? E_EDGES : 0);
        const float* R = (side ? Rd : Rs) + ((size_t)e << 6);
#pragma unroll
        for (int c = 0; c < 8; ++c) {
            float xa = R[c * 8 + a];
            float4 y0 = *(const float4*)(R + c * 8);
            float4 y1 = *(const float4*)(R + c * 8 + 4);
            D[0] += xa * y0.x; D[1] += xa * y0.y; D[2] += xa * y0.z; D[3] += xa * y0.w;
            D[4] += xa * y1.x; D[5] += xa * y1.y; D[6] += xa * y1.z; D[7] += xa * y1.w;
        }
    }
    D[a] += 1.0f;
    float* dout = diag + ((size_t)m << 6) + (a << 3);
    *(float4*)dout = make_float4(D[0], D[1], D[2], D[3]);
    *(float4*)(dout + 4) = make_float4(D[4], D[5], D[6], D[7]);
}

// phase A: thread per incidence, y_i = W_i * p[nb_i] (both batches). No atomics.
__global__ __launch_bounds__(256) void k_ymv(const float* __restrict__ pv,
                                             const int* __restrict__ nbA,
                                             const __half* __restrict__ Wc,
                                             __half2* __restrict__ y) {
    int i = blockIdx.x * blockDim.x + threadIdx.x;
    if (i >= N_INC) return;
    int n = nbA[i];
    const __half* wp = Wc + ((size_t)i << 6);
    float4 wf[8];
#pragma unroll
    for (int k = 0; k < 8; ++k) wf[k] = *(const float4*)(wp + (k << 3));
    const float* pn0 = pv + (n << 3);
    const float* pn1 = pv + PER_B + (n << 3);
    float4 x0 = *(const float4*)pn0, x1 = *(const float4*)(pn0 + 4);
    float4 y0 = *(const float4*)pn1, y1 = *(const float4*)(pn1 + 4);
    __half2 out[8];
#pragma unroll
    for (int a = 0; a < 8; ++a) {
        union { float4 f; __half2 h[4]; } u; u.f = wf[a];
        float2 w0 = __half22float2(u.h[0]);
        float2 w1 = __half22float2(u.h[1]);
        float2 w2 = __half22float2(u.h[2]);
        float2 w3 = __half22float2(u.h[3]);
        float a0 = w0.x * x0.x + w0.y * x0.y + w1.x * x0.z + w1.y * x0.w
                 + w2.x * x1.x + w2.y * x1.y + w3.x * x1.z + w3.y * x1.w;
        float a1 = w0.x * y0.x + w0.y * y0.y + w1.x * y0.z + w1.y * y0.w
                 + w2.x * y1.x + w2.y * y1.y + w3.x * y1.z + w3.y * y1.w;
        out[a] = __floats2half2_rn(a0, a1);
    }
    float4* yo = (float4*)(y + ((size_t)i << 3));
    yo[0] = *(float4*)&out[0];
    yo[1] = *(float4*)&out[4];
}

// phase B: grid-stride over (node m, row a). Ap = diag*p - sum(y segment).
// Fused pAp dot -> block reduce -> 1 atomic pair/block into 8-way slots.
__global__ __launch_bounds__(256) void k_apmv(const float* __restrict__ pv,
                                              float* __restrict__ Ap,
                                              const int* __restrict__ off,
                                              const __half2* __restrict__ y,
                                              const float* __restrict__ diag,
                                              float* __restrict__ pap) {
    float d0 = 0.0f, d1 = 0.0f;
    for (int gt = blockIdx.x * blockDim.x + threadIdx.x; gt < M_NODES * 8;
         gt += gridDim.x * blockDim.x) {
        int m = gt >> 3, a = gt & 7;
        int beg = off[m], end = off[m + 1];
        float acc0 = 0.0f, acc1 = 0.0f;
#pragma unroll 4
        for (int i = beg; i < end; ++i) {
            float2 f = __half22float2(y[((size_t)i << 3) + a]);
            acc0 += f.x; acc1 += f.y;
        }
        const float* dg = diag + ((size_t)m << 6) + (a << 3);
        float4 g0 = *(const float4*)dg;
        float4 g1 = *(const float4*)(dg + 4);
        const float* pm0 = pv + (m << 3);
        const float* pm1 = pv + PER_B + (m << 3);
        float4 q0 = *(const float4*)pm0, q1 = *(const float4*)(pm0 + 4);
        float4 s0 = *(const float4*)pm1, s1 = *(const float4*)(pm1 + 4);
        float ap0 = g0.x * q0.x + g0.y * q0.y + g0.z * q0.z + g0.w * q0.w
                  + g1.x * q1.x + g1.y * q1.y + g1.z * q1.z + g1.w * q1.w - acc0;
        float ap1 = g0.x * s0.x + g0.y * s0.y + g0.z * s0.z + g0.w * s0.w
                  + g1.x * s1.x + g1.y * s1.y + g1.z * s1.z + g1.w * s1.w - acc1;
        Ap[(m << 3) + a] = ap0;
        Ap[PER_B + (m << 3) + a] = ap1;
        d0 += pm0[a] * ap0;
        d1 += pm1[a] * ap1;
    }
    blockReduceAdd(d0, d1, pap);
}

// x = c0 ; r = p = c0 - Ap ; rs0 += r.r   (grid-stride, block-reduced)
__global__ __launch_bounds__(256) void k_init_r(const float4* __restrict__ c0,
                                                const float4* __restrict__ Ap,
                                                float4* __restrict__ x,
                                                float4* __restrict__ r,
                                                float4* __restrict__ p,
                                                float* __restrict__ rs0) {
    float s0 = 0.0f, s1 = 0.0f;
    for (int i = blockIdx.x * blockDim.x + threadIdx.x; i < N4;
         i += gridDim.x * blockDim.x) {
        float4 c = c0[i];
        float4 a = Ap[i];
        float4 rv = make_float4(c.x - a.x, c.y - a.y, c.z - a.z, c.w - a.w);
        x[i] = c; r[i] = rv; p[i] = rv;
        float d = rv.x * rv.x + rv.y * rv.y + rv.z * rv.z + rv.w * rv.w;
        if (i < N4_PER_B) s0 += d; else s1 += d;
    }
    blockReduceAdd(s0, s1, rs0);
}

// alpha per-thread from 8-slot sums; x += a p ; r -= a Ap ; rsnew += r.r
__global__ __launch_bounds__(256) void k_update(float4* __restrict__ x,
                                                const float4* __restrict__ p,
                                                const float4* __restrict__ Ap,
                                                float4* __restrict__ r,
                                                const float* __restrict__ rsold,
                                                const float* __restrict__ pap,
                                                float* __restrict__ rsnew) {
    float2 rs = sumSlots(rsold);
    float2 pa = sumSlots(pap);
    float al0 = rs.x / (pa.x + EPSF);
    float al1 = rs.y / (pa.y + EPSF);
    float s0 = 0.0f, s1 = 0.0f;
    for (int i = blockIdx.x * blockDim.x + threadIdx.x; i < N4;
         i += gridDim.x * blockDim.x) {
        float al = (i < N4_PER_B) ? al0 : al1;
        float4 xv = x[i], pv = p[i], av = Ap[i], rv = r[i];
        xv.x += al * pv.x; xv.y += al * pv.y; xv.z += al * pv.z; xv.w += al * pv.w;
        rv.x -= al * av.x; rv.y -= al * av.y; rv.z -= al * av.z; rv.w -= al * av.w;
        x[i] = xv; r[i] = rv;
        float d = rv.x * rv.x + rv.y * rv.y + rv.z * rv.z + rv.w * rv.w;
        if (i < N4_PER_B) s0 += d; else s1 += d;
    }
    blockReduceAdd(s0, s1, rsnew);
}

// beta per-thread from 8-slot sums; p = r + beta p
__global__ __launch_bounds__(256) void k_pupdate(float4* __restrict__ p,
                                                 const float4* __restrict__ r,
                                                 const float* __restrict__ rsold,
                                                 const float* __restrict__ rsnew) {
    float2 ro = sumSlots(rsold);
    float2 rn = sumSlots(rsnew);
    float be0 = rn.x / (ro.x + EPSF);
    float be1 = rn.y / (ro.y + EPSF);
    int i = blockIdx.x * blockDim.x + threadIdx.x;
    if (i < N4) {
        float be = (i < N4_PER_B) ? be0 : be1;
        float4 rv = r[i], pv = p[i];
        p[i] = make_float4(rv.x + be * pv.x, rv.y + be * pv.y,
                           rv.z + be * pv.z, rv.w + be * pv.w);
    }
}

extern "C" void kernel_launch(void* const* d_in, const int* in_sizes, int n_in,
                              void* d_out, int out_size, void* d_ws, size_t ws_size,
                              hipStream_t stream) {
    const float* c0 = (const float*)d_in[0];
    const int* src  = (const int*)d_in[1];
    const int* dst  = (const int*)d_in[2];
    const float* Rs = (const float*)d_in[3];
    const float* Rd = (const float*)d_in[4];

    float* x = (float*)d_out;
    char* w = (char*)d_ws;
    size_t o = 0;
    auto alloc = [&](size_t bytes) { char* c = w + o; o = (o + bytes + 255) & ~(size_t)255; return c; };
    float* r      = (float*)alloc(VEC_N * 4);
    float* p      = (float*)alloc(VEC_N * 4);
    float* Ap     = (float*)alloc(VEC_N * 4);
    float* scal   = (float*)alloc(1024 * 4);
    int*   cnt    = (int*)alloc(M_NODES * 4);
    int*   offa   = (int*)alloc((M_NODES + 1) * 4);
    int*   cursor = (int*)alloc(M_NODES * 4);
    int*   pos0   = (int*)alloc(E_EDGES * 4);
    int*   pos1   = (int*)alloc(E_EDGES * 4);
    int*   wk     = (int*)alloc(N_INC * 4);
    int*   nb     = (int*)alloc(N_INC * 4);
    float* diag   = (float*)alloc((size_t)M_NODES * 64 * 4);
    __half2* y    = (__half2*)alloc((size_t)N_INC * 8 * 4);   // 25.6 MB
    __half* Wc    = (__half*)alloc((size_t)N_INC * 64 * 2);   // CSR-ordered C/Ct
    size_t ghBytes = (size_t)N_INC * 64 * 2;
    int haveGH = (o + ghBytes) <= ws_size;
    __half* GHc = haveGH ? (__half*)alloc(ghBytes) : (__half*)Wc;

    const int BLK = 256;
    const int grid_v  = (N4 + BLK - 1) / BLK;
    const int grid_e  = (E_EDGES + BLK - 1) / BLK;
    const int grid_m  = (M_NODES + BLK - 1) / BLK;
    const int grid_e8 = (E_EDGES * 8 + BLK - 1) / BLK;
    const int grid_m8 = (M_NODES * 8 + BLK - 1) / BLK;
    const int grid_i  = (N_INC + BLK - 1) / BLK;
    const int grid_mw = (M_NODES * 64 + BLK - 1) / BLK;
    const int GRED    = 512;   // grid for reducing kernels (atomics = 2*GRED, 8-way spread)

    float* RS  = scal;         // RS(t)  = scal + 16*t
    float* PAP = scal + 512;   // PAP(t) = scal + 512 + 16*t

    // ---- precompute (rebuilt every call) ----
    k_zero_scal<<<1, 1024, 0, stream>>>(scal);
    k_zero_cnt<<<grid_m, BLK, 0, stream>>>(cnt);
    k_hist<<<grid_e, BLK, 0, stream>>>(src, dst, cnt);
    k_scan<<<1, SCAN_T, 0, stream>>>(cnt, offa, cursor);
    k_scatter<<<grid_e, BLK, 0, stream>>>(src, dst, cursor, pos0, pos1, nb, wk);
    k_buildC<<<grid_e8, BLK, 0, stream>>>(Rs, Rd, pos0, pos1, Wc, GHc, haveGH);
    if (haveGH)
        k_diagS<<<grid_mw, BLK, 0, stream>>>(offa, GHc, diag);
    else
        k_diagR<<<grid_m8, BLK, 0, stream>>>(offa, wk, Rs, Rd, diag);

    // ---- CG ----
    k_ymv<<<grid_i, BLK, 0, stream>>>(c0, nb, Wc, y);
    k_apmv<<<GRED, BLK, 0, stream>>>(c0, Ap, offa, y, diag, PAP + 16 * 20); // scratch slot
    k_init_r<<<GRED, BLK, 0, stream>>>((const float4*)c0, (const float4*)Ap,
                                       (float4*)x, (float4*)r, (float4*)p, RS);

    for (int t = 0; t < CG_ITERS; ++t) {
        float* rs_old = RS + 16 * t;
        float* rs_new = RS + 16 * (t + 1);
        float* pap_t  = PAP + 16 * t;
        k_ymv<<<grid_i, BLK, 0, stream>>>(p, nb, Wc, y);
        k_apmv<<<GRED, BLK, 0, stream>>>(p, Ap, offa, y, diag, pap_t);
        k_update<<<GRED, BLK, 0, stream>>>((float4*)x, (const float4*)p,
                                           (const float4*)Ap, (float4*)r,
                                           rs_old, pap_t, rs_new);
        if (t < CG_ITERS - 1)
            k_pupdate<<<grid_v, BLK, 0, stream>>>((float4*)p, (const float4*)r,
                                                  rs_old, rs_new);
    }
}

// Round 7
// 1783.095 us; speedup vs baseline: 4.7130x; 1.2378x over previous
//
#include <hip/hip_runtime.h>
#include <hip/hip_fp16.h>

#define E_EDGES   400000
#define M_NODES   50000
#define N_INC     800000
#define PER_B     400000
#define VEC_N     800000
#define N4        200000
#define N4_PER_B  100000
#define CG_ITERS  17
#define EPSF      1e-12f

// scal layout (2048 floats): 16 slot-pairs (32 floats) per quantity.
//   RS(t)  = scal + 32*t          t=0..21
//   PAP(t) = scal + 768 + 32*t    t=0..20
//   ZSLOT  = scal + 1984          (always zero)
// Reducing blocks atomicAdd into pair (blockIdx & 15); consumers sum all 16.

__device__ __forceinline__ float waveReduce(float v) {
#pragma unroll
    for (int off = 32; off > 0; off >>= 1)
        v += __shfl_down(v, off, 64);
    return v;
}

__device__ __forceinline__ void blockReduceAdd(float d0, float d1, float* __restrict__ base) {
    __shared__ float red[8];
    d0 = waveReduce(d0);
    d1 = waveReduce(d1);
    int w = threadIdx.x >> 6, lane = threadIdx.x & 63;
    if (lane == 0) { red[2 * w] = d0; red[2 * w + 1] = d1; }
    __syncthreads();
    if (threadIdx.x == 0) {
        float t0 = red[0] + red[2] + red[4] + red[6];
        float t1 = red[1] + red[3] + red[5] + red[7];
        int s = (blockIdx.x & 15) << 1;
        atomicAdd(&base[s], t0);
        atomicAdd(&base[s + 1], t1);
    }
}

__device__ __forceinline__ float2 sumSlots(const float* __restrict__ base) {
    float a = 0.0f, b = 0.0f;
#pragma unroll
    for (int k = 0; k < 16; ++k) { a += base[2 * k]; b += base[2 * k + 1]; }
    return make_float2(a, b);
}

__global__ void k_zero_scal(float* __restrict__ s) {
    int i = blockIdx.x * blockDim.x + threadIdx.x;
    if (i < 2048) s[i] = 0.0f;
}

__global__ void k_zero_cnt(int* __restrict__ cnt) {
    int i = blockIdx.x * blockDim.x + threadIdx.x;
    if (i < M_NODES) cnt[i] = 0;
}

__global__ void k_hist(const int* __restrict__ src, const int* __restrict__ dst,
                       int* __restrict__ cnt) {
    int e = blockIdx.x * blockDim.x + threadIdx.x;
    if (e < E_EDGES) {
        atomicAdd(&cnt[src[e]], 1);
        atomicAdd(&cnt[dst[e]], 1);
    }
}

#define SCAN_T 1024
__global__ void k_scan(const int* __restrict__ cnt, int* __restrict__ off,
                       int* __restrict__ cursor) {
    __shared__ int part[SCAN_T];
    int t = threadIdx.x;
    const int chunk = (M_NODES + SCAN_T - 1) / SCAN_T;
    int beg = t * chunk;
    int end = beg + chunk; if (end > M_NODES) end = M_NODES;
    if (beg > M_NODES) beg = M_NODES;
    int s = 0;
    for (int i = beg; i < end; ++i) s += cnt[i];
    part[t] = s;
    __syncthreads();
    for (int st = 1; st < SCAN_T; st <<= 1) {
        int v = (t >= st) ? part[t - st] : 0;
        __syncthreads();
        part[t] += v;
        __syncthreads();
    }
    int run = (t == 0) ? 0 : part[t - 1];
    for (int i = beg; i < end; ++i) {
        off[i] = run; cursor[i] = run;
        run += cnt[i];
    }
    if (t == SCAN_T - 1) off[M_NODES] = run;
}

__global__ void k_scatter(const int* __restrict__ src, const int* __restrict__ dst,
                          int* __restrict__ cursor, int* __restrict__ pos0,
                          int* __restrict__ pos1, int* __restrict__ nb,
                          int* __restrict__ wk) {
    int e = blockIdx.x * blockDim.x + threadIdx.x;
    if (e < E_EDGES) {
        int s = src[e], t = dst[e];
        int p0 = atomicAdd(&cursor[s], 1);
        pos0[e] = p0; nb[p0] = t; wk[p0] = e;
        int p1 = atomicAdd(&cursor[t], 1);
        pos1[e] = p1; nb[p1] = s; wk[p1] = e + E_EDGES;
    }
}

// 8 lanes/edge, coalesced sequential R reads; scatter-write 128B blocks to CSR slots.
__global__ __launch_bounds__(256) void k_buildC(const float* __restrict__ Rs,
                                                const float* __restrict__ Rd,
                                                const int* __restrict__ pos0,
                                                const int* __restrict__ pos1,
                                                __half* __restrict__ Wc,
                                                __half* __restrict__ GHc, int haveGH) {
    int gt = blockIdx.x * blockDim.x + threadIdx.x;
    int e = gt >> 3, a = gt & 7;
    if (e >= E_EDGES) return;
    const float* rs = Rs + ((size_t)e << 6);
    const float* rd = Rd + ((size_t)e << 6);
    float C[8], Ct[8], G[8], H[8];
#pragma unroll
    for (int j = 0; j < 8; ++j) { C[j] = 0; Ct[j] = 0; G[j] = 0; H[j] = 0; }
#pragma unroll
    for (int c = 0; c < 8; ++c) {
        float xs = rs[c * 8 + a];
        float xd = rd[c * 8 + a];
        float4 s0 = *(const float4*)(rs + c * 8);
        float4 s1 = *(const float4*)(rs + c * 8 + 4);
        float4 d0 = *(const float4*)(rd + c * 8);
        float4 d1 = *(const float4*)(rd + c * 8 + 4);
        C[0] += xs * d0.x; C[1] += xs * d0.y; C[2] += xs * d0.z; C[3] += xs * d0.w;
        C[4] += xs * d1.x; C[5] += xs * d1.y; C[6] += xs * d1.z; C[7] += xs * d1.w;
        Ct[0] += xd * s0.x; Ct[1] += xd * s0.y; Ct[2] += xd * s0.z; Ct[3] += xd * s0.w;
        Ct[4] += xd * s1.x; Ct[5] += xd * s1.y; Ct[6] += xd * s1.z; Ct[7] += xd * s1.w;
        G[0] += xs * s0.x; G[1] += xs * s0.y; G[2] += xs * s0.z; G[3] += xs * s0.w;
        G[4] += xs * s1.x; G[5] += xs * s1.y; G[6] += xs * s1.z; G[7] += xs * s1.w;
        H[0] += xd * d0.x; H[1] += xd * d0.y; H[2] += xd * d0.z; H[3] += xd * d0.w;
        H[4] += xd * d1.x; H[5] += xd * d1.y; H[6] += xd * d1.z; H[7] += xd * d1.w;
    }
    size_t s0o = (size_t)pos0[e] << 6;
    size_t s1o = (size_t)pos1[e] << 6;
    union { float4 f; __half2 h[4]; } u;
#pragma unroll
    for (int k = 0; k < 4; ++k) u.h[k] = __floats2half2_rn(C[2 * k], C[2 * k + 1]);
    *(float4*)(Wc + s0o + (a << 3)) = u.f;
#pragma unroll
    for (int k = 0; k < 4; ++k) u.h[k] = __floats2half2_rn(Ct[2 * k], Ct[2 * k + 1]);
    *(float4*)(Wc + s1o + (a << 3)) = u.f;
    if (haveGH) {
#pragma unroll
        for (int k = 0; k < 4; ++k) u.h[k] = __floats2half2_rn(G[2 * k], G[2 * k + 1]);
        *(float4*)(GHc + s0o + (a << 3)) = u.f;
#pragma unroll
        for (int k = 0; k < 4; ++k) u.h[k] = __floats2half2_rn(H[2 * k], H[2 * k + 1]);
        *(float4*)(GHc + s1o + (a << 3)) = u.f;
    }
}

// diag from CSR-streamed GH: wave per node.
__global__ __launch_bounds__(256) void k_diagS(const int* __restrict__ off,
                                               const __half* __restrict__ GHc,
                                               float* __restrict__ diag) {
    int wave = (blockIdx.x * blockDim.x + threadIdx.x) >> 6;
    int lane = threadIdx.x & 63;
    int g = lane >> 3, a = lane & 7;
    int m = wave;
    if (m >= M_NODES) return;
    float D[8];
#pragma unroll
    for (int j = 0; j < 8; ++j) D[j] = 0.0f;
    int beg = off[m], end = off[m + 1];
    for (int i = beg + g; i < end; i += 8) {
        union { float4 f; __half2 h[4]; } u;
        u.f = *(const float4*)(GHc + ((size_t)i << 6) + (a << 3));
        float2 w0 = __half22float2(u.h[0]);
        float2 w1 = __half22float2(u.h[1]);
        float2 w2 = __half22float2(u.h[2]);
        float2 w3 = __half22float2(u.h[3]);
        D[0] += w0.x; D[1] += w0.y; D[2] += w1.x; D[3] += w1.y;
        D[4] += w2.x; D[5] += w2.y; D[6] += w3.x; D[7] += w3.y;
    }
#pragma unroll
    for (int j = 0; j < 8; ++j) {
        D[j] += __shfl_xor(D[j], 8, 64);
        D[j] += __shfl_xor(D[j], 16, 64);
        D[j] += __shfl_xor(D[j], 32, 64);
    }
    if (g == 0) {
        D[a] += 1.0f;
        float* dout = diag + ((size_t)m << 6) + (a << 3);
        *(float4*)dout = make_float4(D[0], D[1], D[2], D[3]);
        *(float4*)(dout + 4) = make_float4(D[4], D[5], D[6], D[7]);
    }
}

// fallback diag straight from R (runs once)
__global__ void k_diagR(const int* __restrict__ off, const int* __restrict__ wk,
                        const float* __restrict__ Rs, const float* __restrict__ Rd,
                        float* __restrict__ diag) {
    int gt = blockIdx.x * blockDim.x + threadIdx.x;
    int m = gt >> 3, a = gt & 7;
    if (m >= M_NODES) return;
    float D[8];
#pragma unroll
    for (int j = 0; j < 8; ++j) D[j] = 0.0f;
    int beg = off[m], end = off[m + 1];
    for (int i = beg; i < end; ++i) {
        int k = wk[i];
        int side = (k >= E_EDGES);
        int e = k - (side ? E_EDGES : 0);
        const float* R = (side ? Rd : Rs) + ((size_t)e << 6);
#pragma unroll
        for (int c = 0; c < 8; ++c) {
            float xa = R[c * 8 + a];
            float4 y0 = *(const float4*)(R + c * 8);
            float4 y1 = *(const float4*)(R + c * 8 + 4);
            D[0] += xa * y0.x; D[1] += xa * y0.y; D[2] += xa * y0.z; D[3] += xa * y0.w;
            D[4] += xa * y1.x; D[5] += xa * y1.y; D[6] += xa * y1.z; D[7] += xa * y1.w;
        }
    }
    D[a] += 1.0f;
    float* dout = diag + ((size_t)m << 6) + (a << 3);
    *(float4*)dout = make_float4(D[0], D[1], D[2], D[3]);
    *(float4*)(dout + 4) = make_float4(D[4], D[5], D[6], D[7]);
}

// Fused single-pass: p_t = r + beta*p_old (inline, own-node written out),
// Ap = diag*p_t - sum_i W_i p_t[nb_i], pAp dot -> block-reduced slots.
// Wave per node, grid-strided. Lane (g,a): g = incidence subgroup, a = row.
__global__ __launch_bounds__(256) void k_mv(const float* __restrict__ rv,
                                            const float* __restrict__ p_old,
                                            float* __restrict__ p_out,
                                            float* __restrict__ Ap,
                                            const int* __restrict__ off,
                                            const int* __restrict__ nbA,
                                            const __half* __restrict__ Wc,
                                            const float* __restrict__ diag,
                                            const float* __restrict__ bnum,
                                            const float* __restrict__ bden,
                                            float* __restrict__ pap) {
    float2 bn = sumSlots(bnum);
    float2 bd = sumSlots(bden);
    float be0 = bn.x / (bd.x + EPSF);
    float be1 = bn.y / (bd.y + EPSF);
    int lane = threadIdx.x & 63;
    int g = lane >> 3, a = lane & 7;
    int waveId = (blockIdx.x * blockDim.x + threadIdx.x) >> 6;
    int nWaves = (gridDim.x * blockDim.x) >> 6;
    float d0 = 0.0f, d1 = 0.0f;
    for (int m = waveId; m < M_NODES; m += nWaves) {
        int beg = off[m], end = off[m + 1];
        float acc0 = 0.0f, acc1 = 0.0f;
        for (int i = beg + g; i < end; i += 8) {
            int n = nbA[i];
            union { float4 f; __half2 h[4]; } u;
            u.f = *(const float4*)(Wc + ((size_t)i << 6) + (a << 3));
            const float* rn0 = rv + (n << 3);
            const float* rn1 = rv + PER_B + (n << 3);
            const float* qn0 = p_old + (n << 3);
            const float* qn1 = p_old + PER_B + (n << 3);
            float4 rA = *(const float4*)rn0, rB = *(const float4*)(rn0 + 4);
            float4 rC = *(const float4*)rn1, rD = *(const float4*)(rn1 + 4);
            float4 qA = *(const float4*)qn0, qB = *(const float4*)(qn0 + 4);
            float4 qC = *(const float4*)qn1, qD = *(const float4*)(qn1 + 4);
            float p00 = rA.x + be0 * qA.x, p01 = rA.y + be0 * qA.y;
            float p02 = rA.z + be0 * qA.z, p03 = rA.w + be0 * qA.w;
            float p04 = rB.x + be0 * qB.x, p05 = rB.y + be0 * qB.y;
            float p06 = rB.z + be0 * qB.z, p07 = rB.w + be0 * qB.w;
            float p10 = rC.x + be1 * qC.x, p11 = rC.y + be1 * qC.y;
            float p12 = rC.z + be1 * qC.z, p13 = rC.w + be1 * qC.w;
            float p14 = rD.x + be1 * qD.x, p15 = rD.y + be1 * qD.y;
            float p16 = rD.z + be1 * qD.z, p17 = rD.w + be1 * qD.w;
            float2 w0 = __half22float2(u.h[0]);
            float2 w1 = __half22float2(u.h[1]);
            float2 w2 = __half22float2(u.h[2]);
            float2 w3 = __half22float2(u.h[3]);
            acc0 += w0.x * p00 + w0.y * p01 + w1.x * p02 + w1.y * p03
                  + w2.x * p04 + w2.y * p05 + w3.x * p06 + w3.y * p07;
            acc1 += w0.x * p10 + w0.y * p11 + w1.x * p12 + w1.y * p13
                  + w2.x * p14 + w2.y * p15 + w3.x * p16 + w3.y * p17;
        }
        acc0 += __shfl_xor(acc0, 8, 64);  acc1 += __shfl_xor(acc1, 8, 64);
        acc0 += __shfl_xor(acc0, 16, 64); acc1 += __shfl_xor(acc1, 16, 64);
        acc0 += __shfl_xor(acc0, 32, 64); acc1 += __shfl_xor(acc1, 32, 64);
        if (g < 2) {
            int base = g * PER_B;
            float be = g ? be1 : be0;
            float acc = g ? acc1 : acc0;
            const float* rm = rv + base + (m << 3);
            const float* qm = p_old + base + (m << 3);
            float4 rA = *(const float4*)rm, rB = *(const float4*)(rm + 4);
            float4 qA = *(const float4*)qm, qB = *(const float4*)(qm + 4);
            float pm[8];
            pm[0] = rA.x + be * qA.x; pm[1] = rA.y + be * qA.y;
            pm[2] = rA.z + be * qA.z; pm[3] = rA.w + be * qA.w;
            pm[4] = rB.x + be * qB.x; pm[5] = rB.y + be * qB.y;
            pm[6] = rB.z + be * qB.z; pm[7] = rB.w + be * qB.w;
            const float* dg = diag + ((size_t)m << 6) + (a << 3);
            float4 g0 = *(const float4*)dg;
            float4 g1 = *(const float4*)(dg + 4);
            float ap = g0.x * pm[0] + g0.y * pm[1] + g0.z * pm[2] + g0.w * pm[3]
                     + g1.x * pm[4] + g1.y * pm[5] + g1.z * pm[6] + g1.w * pm[7] - acc;
            Ap[base + (m << 3) + a] = ap;
            p_out[base + (m << 3) + a] = pm[a];
            float dd = pm[a] * ap;
            if (g == 0) d0 += dd; else d1 += dd;
        }
    }
    blockReduceAdd(d0, d1, pap);
}

// x = c0 ; r = c0 - Ap ; rs0 += r.r   (grid-stride, block-reduced)
__global__ __launch_bounds__(256) void k_init_r(const float4* __restrict__ c0,
                                                const float4* __restrict__ Ap,
                                                float4* __restrict__ x,
                                                float4* __restrict__ r,
                                                float* __restrict__ rs0) {
    float s0 = 0.0f, s1 = 0.0f;
    for (int i = blockIdx.x * blockDim.x + threadIdx.x; i < N4;
         i += gridDim.x * blockDim.x) {
        float4 c = c0[i];
        float4 a = Ap[i];
        float4 rv = make_float4(c.x - a.x, c.y - a.y, c.z - a.z, c.w - a.w);
        x[i] = c; r[i] = rv;
        float d = rv.x * rv.x + rv.y * rv.y + rv.z * rv.z + rv.w * rv.w;
        if (i < N4_PER_B) s0 += d; else s1 += d;
    }
    blockReduceAdd(s0, s1, rs0);
}

// alpha per-thread from slot sums; x += a p ; r -= a Ap ; rsnew += r.r
__global__ __launch_bounds__(256) void k_update(float4* __restrict__ x,
                                                const float4* __restrict__ p,
                                                const float4* __restrict__ Ap,
                                                float4* __restrict__ r,
                                                const float* __restrict__ rsold,
                                                const float* __restrict__ pap,
                                                float* __restrict__ rsnew) {
    float2 rs = sumSlots(rsold);
    float2 pa = sumSlots(pap);
    float al0 = rs.x / (pa.x + EPSF);
    float al1 = rs.y / (pa.y + EPSF);
    float s0 = 0.0f, s1 = 0.0f;
    for (int i = blockIdx.x * blockDim.x + threadIdx.x; i < N4;
         i += gridDim.x * blockDim.x) {
        float al = (i < N4_PER_B) ? al0 : al1;
        float4 xv = x[i], pv = p[i], av = Ap[i], rv = r[i];
        xv.x += al * pv.x; xv.y += al * pv.y; xv.z += al * pv.z; xv.w += al * pv.w;
        rv.x -= al * av.x; rv.y -= al * av.y; rv.z -= al * av.z; rv.w -= al * av.w;
        x[i] = xv; r[i] = rv;
        float d = rv.x * rv.x + rv.y * rv.y + rv.z * rv.z + rv.w * rv.w;
        if (i < N4_PER_B) s0 += d; else s1 += d;
    }
    blockReduceAdd(s0, s1, rsnew);
}

extern "C" void kernel_launch(void* const* d_in, const int* in_sizes, int n_in,
                              void* d_out, int out_size, void* d_ws, size_t ws_size,
                              hipStream_t stream) {
    const float* c0 = (const float*)d_in[0];
    const int* src  = (const int*)d_in[1];
    const int* dst  = (const int*)d_in[2];
    const float* Rs = (const float*)d_in[3];
    const float* Rd = (const float*)d_in[4];

    float* x = (float*)d_out;
    char* w = (char*)d_ws;
    size_t o = 0;
    auto alloc = [&](size_t bytes) { char* c = w + o; o = (o + bytes + 255) & ~(size_t)255; return c; };
    float* r      = (float*)alloc(VEC_N * 4);
    float* pA     = (float*)alloc(VEC_N * 4);
    float* pB     = (float*)alloc(VEC_N * 4);
    float* Ap     = (float*)alloc(VEC_N * 4);
    float* scal   = (float*)alloc(2048 * 4);
    int*   cnt    = (int*)alloc(M_NODES * 4);
    int*   offa   = (int*)alloc((M_NODES + 1) * 4);
    int*   cursor = (int*)alloc(M_NODES * 4);
    int*   pos0   = (int*)alloc(E_EDGES * 4);
    int*   pos1   = (int*)alloc(E_EDGES * 4);
    int*   wk     = (int*)alloc(N_INC * 4);
    int*   nb     = (int*)alloc(N_INC * 4);
    float* diag   = (float*)alloc((size_t)M_NODES * 64 * 4);
    __half* Wc    = (__half*)alloc((size_t)N_INC * 64 * 2);   // CSR-ordered C/Ct
    size_t ghBytes = (size_t)N_INC * 64 * 2;
    int haveGH = (o + ghBytes) <= ws_size;
    __half* GHc = haveGH ? (__half*)alloc(ghBytes) : (__half*)Wc;

    const int BLK = 256;
    const int grid_e  = (E_EDGES + BLK - 1) / BLK;
    const int grid_m  = (M_NODES + BLK - 1) / BLK;
    const int grid_e8 = (E_EDGES * 8 + BLK - 1) / BLK;
    const int grid_m8 = (M_NODES * 8 + BLK - 1) / BLK;
    const int grid_mw = (M_NODES * 64 + BLK - 1) / BLK;
    const int MVB     = 2048;  // k_mv blocks (8192 waves, grid-strided over nodes)
    const int GRED    = 512;   // vector reduce kernels

    float* RS    = scal;                       // RS(t)  = scal + 32*t
    float* PAP   = scal + 768;                 // PAP(t) = scal + 768 + 32*t
    float* ZSLOT = scal + 1984;                // stays zero

    // ---- precompute (rebuilt every call) ----
    k_zero_scal<<<8, 256, 0, stream>>>(scal);
    k_zero_cnt<<<grid_m, BLK, 0, stream>>>(cnt);
    k_hist<<<grid_e, BLK, 0, stream>>>(src, dst, cnt);
    k_scan<<<1, SCAN_T, 0, stream>>>(cnt, offa, cursor);
    k_scatter<<<grid_e, BLK, 0, stream>>>(src, dst, cursor, pos0, pos1, nb, wk);
    k_buildC<<<grid_e8, BLK, 0, stream>>>(Rs, Rd, pos0, pos1, Wc, GHc, haveGH);
    if (haveGH)
        k_diagS<<<grid_mw, BLK, 0, stream>>>(offa, GHc, diag);
    else
        k_diagR<<<grid_m8, BLK, 0, stream>>>(offa, wk, Rs, Rd, diag);

    // ---- init: Ap = A c0 (beta=0 path), r = c0 - Ap, x = c0 ----
    k_mv<<<MVB, BLK, 0, stream>>>(c0, c0, pB, Ap, offa, nb, Wc, diag,
                                  ZSLOT, ZSLOT, PAP + 32 * 20);  // scratch slot
    k_init_r<<<GRED, BLK, 0, stream>>>((const float4*)c0, (const float4*)Ap,
                                       (float4*)x, (float4*)r, RS);

    // ---- CG loop: 2 kernels/iter ----
    for (int t = 0; t < CG_ITERS; ++t) {
        float* pcur  = (t & 1) ? pB : pA;
        const float* pprev = (t == 0) ? r : ((t & 1) ? pA : pB);
        const float* bnum = (t == 0) ? ZSLOT : RS + 32 * t;
        const float* bden = (t == 0) ? ZSLOT : RS + 32 * (t - 1);
        k_mv<<<MVB, BLK, 0, stream>>>(r, pprev, pcur, Ap, offa, nb, Wc, diag,
                                      bnum, bden, PAP + 32 * t);
        k_update<<<GRED, BLK, 0, stream>>>((float4*)x, (const float4*)pcur,
                                           (const float4*)Ap, (float4*)r,
                                           RS + 32 * t, PAP + 32 * t,
                                           RS + 32 * (t + 1));
    }
}

// Round 8
// 1440.414 us; speedup vs baseline: 5.8343x; 1.2379x over previous
//
#include <hip/hip_runtime.h>
#include <hip/hip_fp16.h>

#define E_EDGES   400000
#define M_NODES   50000
#define N_INC     800000
#define PER_B     400000
#define VEC_N     800000
#define N4        200000
#define CG_ITERS  17
#define EPSF      1e-12f

// scal (2048 floats):
//   RHO(t) = scal + 32*t          (16 slot-pairs) t=0..17  (t=17 = init-mv scratch)
//   MU(t)  = scal + 1024 + 32*t   t=0..17
//   fin    = scal + 1792 : fin[4t+0/1]=alpha_t(b0/b1), fin[4t+2/3]=rho_t(b0/b1)

__device__ __forceinline__ float waveReduce(float v) {
#pragma unroll
    for (int off = 32; off > 0; off >>= 1)
        v += __shfl_down(v, off, 64);
    return v;
}

__device__ __forceinline__ void blockReduceAdd4(float a0, float a1, float b0, float b1,
                                                float* __restrict__ baseA,
                                                float* __restrict__ baseB) {
    __shared__ float red[16];
    a0 = waveReduce(a0); a1 = waveReduce(a1);
    b0 = waveReduce(b0); b1 = waveReduce(b1);
    int w = threadIdx.x >> 6, lane = threadIdx.x & 63;
    if (lane == 0) { red[4*w] = a0; red[4*w+1] = a1; red[4*w+2] = b0; red[4*w+3] = b1; }
    __syncthreads();
    if (threadIdx.x == 0) {
        float t0 = red[0] + red[4] + red[8]  + red[12];
        float t1 = red[1] + red[5] + red[9]  + red[13];
        float t2 = red[2] + red[6] + red[10] + red[14];
        float t3 = red[3] + red[7] + red[11] + red[15];
        int s = (blockIdx.x & 15) << 1;
        atomicAdd(&baseA[s], t0); atomicAdd(&baseA[s+1], t1);
        atomicAdd(&baseB[s], t2); atomicAdd(&baseB[s+1], t3);
    }
}

__device__ __forceinline__ float2 sumSlots(const float* __restrict__ base) {
    float a = 0.0f, b = 0.0f;
#pragma unroll
    for (int k = 0; k < 16; ++k) { a += base[2*k]; b += base[2*k+1]; }
    return make_float2(a, b);
}

__global__ void k_zero_scal(float* __restrict__ s) {
    int i = blockIdx.x * blockDim.x + threadIdx.x;
    if (i < 2048) s[i] = 0.0f;
}

__global__ void k_zero_cnt(int* __restrict__ cnt) {
    int i = blockIdx.x * blockDim.x + threadIdx.x;
    if (i < M_NODES) cnt[i] = 0;
}

__global__ void k_hist(const int* __restrict__ src, const int* __restrict__ dst,
                       int* __restrict__ cnt) {
    int e = blockIdx.x * blockDim.x + threadIdx.x;
    if (e < E_EDGES) {
        atomicAdd(&cnt[src[e]], 1);
        atomicAdd(&cnt[dst[e]], 1);
    }
}

#define SCAN_T 1024
__global__ void k_scan(const int* __restrict__ cnt, int* __restrict__ off,
                       int* __restrict__ cursor) {
    __shared__ int part[SCAN_T];
    int t = threadIdx.x;
    const int chunk = (M_NODES + SCAN_T - 1) / SCAN_T;
    int beg = t * chunk;
    int end = beg + chunk; if (end > M_NODES) end = M_NODES;
    if (beg > M_NODES) beg = M_NODES;
    int s = 0;
    for (int i = beg; i < end; ++i) s += cnt[i];
    part[t] = s;
    __syncthreads();
    for (int st = 1; st < SCAN_T; st <<= 1) {
        int v = (t >= st) ? part[t - st] : 0;
        __syncthreads();
        part[t] += v;
        __syncthreads();
    }
    int run = (t == 0) ? 0 : part[t - 1];
    for (int i = beg; i < end; ++i) {
        off[i] = run; cursor[i] = run;
        run += cnt[i];
    }
    if (t == SCAN_T - 1) off[M_NODES] = run;
}

__global__ void k_scatter(const int* __restrict__ src, const int* __restrict__ dst,
                          int* __restrict__ cursor, int* __restrict__ pos0,
                          int* __restrict__ pos1, int* __restrict__ nb,
                          int* __restrict__ wk) {
    int e = blockIdx.x * blockDim.x + threadIdx.x;
    if (e < E_EDGES) {
        int s = src[e], t = dst[e];
        int p0 = atomicAdd(&cursor[s], 1);
        pos0[e] = p0; nb[p0] = t; wk[p0] = e;
        int p1 = atomicAdd(&cursor[t], 1);
        pos1[e] = p1; nb[p1] = s; wk[p1] = e + E_EDGES;
    }
}

// 8 lanes/edge, coalesced sequential R reads; scatter-write 128B blocks to CSR slots.
__global__ __launch_bounds__(256) void k_buildC(const float* __restrict__ Rs,
                                                const float* __restrict__ Rd,
                                                const int* __restrict__ pos0,
                                                const int* __restrict__ pos1,
                                                __half* __restrict__ Wc,
                                                __half* __restrict__ GHc, int haveGH) {
    int gt = blockIdx.x * blockDim.x + threadIdx.x;
    int e = gt >> 3, a = gt & 7;
    if (e >= E_EDGES) return;
    const float* rs = Rs + ((size_t)e << 6);
    const float* rd = Rd + ((size_t)e << 6);
    float C[8], Ct[8], G[8], H[8];
#pragma unroll
    for (int j = 0; j < 8; ++j) { C[j] = 0; Ct[j] = 0; G[j] = 0; H[j] = 0; }
#pragma unroll
    for (int c = 0; c < 8; ++c) {
        float xs = rs[c * 8 + a];
        float xd = rd[c * 8 + a];
        float4 s0 = *(const float4*)(rs + c * 8);
        float4 s1 = *(const float4*)(rs + c * 8 + 4);
        float4 d0 = *(const float4*)(rd + c * 8);
        float4 d1 = *(const float4*)(rd + c * 8 + 4);
        C[0] += xs * d0.x; C[1] += xs * d0.y; C[2] += xs * d0.z; C[3] += xs * d0.w;
        C[4] += xs * d1.x; C[5] += xs * d1.y; C[6] += xs * d1.z; C[7] += xs * d1.w;
        Ct[0] += xd * s0.x; Ct[1] += xd * s0.y; Ct[2] += xd * s0.z; Ct[3] += xd * s0.w;
        Ct[4] += xd * s1.x; Ct[5] += xd * s1.y; Ct[6] += xd * s1.z; Ct[7] += xd * s1.w;
        G[0] += xs * s0.x; G[1] += xs * s0.y; G[2] += xs * s0.z; G[3] += xs * s0.w;
        G[4] += xs * s1.x; G[5] += xs * s1.y; G[6] += xs * s1.z; G[7] += xs * s1.w;
        H[0] += xd * d0.x; H[1] += xd * d0.y; H[2] += xd * d0.z; H[3] += xd * d0.w;
        H[4] += xd * d1.x; H[5] += xd * d1.y; H[6] += xd * d1.z; H[7] += xd * d1.w;
    }
    size_t s0o = (size_t)pos0[e] << 6;
    size_t s1o = (size_t)pos1[e] << 6;
    union { float4 f; __half2 h[4]; } u;
#pragma unroll
    for (int k = 0; k < 4; ++k) u.h[k] = __floats2half2_rn(C[2*k], C[2*k+1]);
    *(float4*)(Wc + s0o + (a << 3)) = u.f;
#pragma unroll
    for (int k = 0; k < 4; ++k) u.h[k] = __floats2half2_rn(Ct[2*k], Ct[2*k+1]);
    *(float4*)(Wc + s1o + (a << 3)) = u.f;
    if (haveGH) {
#pragma unroll
        for (int k = 0; k < 4; ++k) u.h[k] = __floats2half2_rn(G[2*k], G[2*k+1]);
        *(float4*)(GHc + s0o + (a << 3)) = u.f;
#pragma unroll
        for (int k = 0; k < 4; ++k) u.h[k] = __floats2half2_rn(H[2*k], H[2*k+1]);
        *(float4*)(GHc + s1o + (a << 3)) = u.f;
    }
}

// diag from CSR-streamed GH: wave per node.
__global__ __launch_bounds__(256) void k_diagS(const int* __restrict__ off,
                                               const __half* __restrict__ GHc,
                                               float* __restrict__ diag) {
    int wave = (blockIdx.x * blockDim.x + threadIdx.x) >> 6;
    int lane = threadIdx.x & 63;
    int g = lane >> 3, a = lane & 7;
    int m = wave;
    if (m >= M_NODES) return;
    float D[8];
#pragma unroll
    for (int j = 0; j < 8; ++j) D[j] = 0.0f;
    int beg = off[m], end = off[m + 1];
    for (int i = beg + g; i < end; i += 8) {
        union { float4 f; __half2 h[4]; } u;
        u.f = *(const float4*)(GHc + ((size_t)i << 6) + (a << 3));
        float2 w0 = __half22float2(u.h[0]);
        float2 w1 = __half22float2(u.h[1]);
        float2 w2 = __half22float2(u.h[2]);
        float2 w3 = __half22float2(u.h[3]);
        D[0] += w0.x; D[1] += w0.y; D[2] += w1.x; D[3] += w1.y;
        D[4] += w2.x; D[5] += w2.y; D[6] += w3.x; D[7] += w3.y;
    }
#pragma unroll
    for (int j = 0; j < 8; ++j) {
        D[j] += __shfl_xor(D[j], 8, 64);
        D[j] += __shfl_xor(D[j], 16, 64);
        D[j] += __shfl_xor(D[j], 32, 64);
    }
    if (g == 0) {
        D[a] += 1.0f;
        float* dout = diag + ((size_t)m << 6) + (a << 3);
        *(float4*)dout = make_float4(D[0], D[1], D[2], D[3]);
        *(float4*)(dout + 4) = make_float4(D[4], D[5], D[6], D[7]);
    }
}

// fallback diag straight from R (runs once)
__global__ void k_diagR(const int* __restrict__ off, const int* __restrict__ wk,
                        const float* __restrict__ Rs, const float* __restrict__ Rd,
                        float* __restrict__ diag) {
    int gt = blockIdx.x * blockDim.x + threadIdx.x;
    int m = gt >> 3, a = gt & 7;
    if (m >= M_NODES) return;
    float D[8];
#pragma unroll
    for (int j = 0; j < 8; ++j) D[j] = 0.0f;
    int beg = off[m], end = off[m + 1];
    for (int i = beg; i < end; ++i) {
        int k = wk[i];
        int side = (k >= E_EDGES);
        int e = k - (side ? E_EDGES : 0);
        const float* R = (side ? Rd : Rs) + ((size_t)e << 6);
#pragma unroll
        for (int c = 0; c < 8; ++c) {
            float xa = R[c * 8 + a];
            float4 y0 = *(const float4*)(R + c * 8);
            float4 y1 = *(const float4*)(R + c * 8 + 4);
            D[0] += xa * y0.x; D[1] += xa * y0.y; D[2] += xa * y0.z; D[3] += xa * y0.w;
            D[4] += xa * y1.x; D[5] += xa * y1.y; D[6] += xa * y1.z; D[7] += xa * y1.w;
        }
    }
    D[a] += 1.0f;
    float* dout = diag + ((size_t)m << 6) + (a << 3);
    *(float4*)dout = make_float4(D[0], D[1], D[2], D[3]);
    *(float4*)(dout + 4) = make_float4(D[4], D[5], D[6], D[7]);
}

// layout convert: orig [b][m][8] -> interleaved [m][16]
__global__ void k_cvt(const float4* __restrict__ src, float4* __restrict__ il) {
    int i = blockIdx.x * blockDim.x + threadIdx.x;
    if (i >= N4) return;
    int b = i / (PER_B / 4);
    int rem = i - b * (PER_B / 4);
    int m = rem >> 1, half = rem & 1;
    il[(m << 2) + (b << 1) + half] = src[i];
}

// interleaved [m][16] -> orig [b][m][8]
__global__ void k_emit(const float4* __restrict__ il, float4* __restrict__ dst) {
    int i = blockIdx.x * blockDim.x + threadIdx.x;
    if (i >= N4) return;
    int b = i / (PER_B / 4);
    int rem = i - b * (PER_B / 4);
    int m = rem >> 1, half = rem & 1;
    dst[i] = il[(m << 2) + (b << 1) + half];
}

// w = A r  (interleaved layout). Wave per node, grid-strided.
// Fused dots: rho = r.r, mu = w.r (per batch) -> slots.
__global__ __launch_bounds__(256) void k_mv(const float* __restrict__ rv,
                                            float* __restrict__ wv,
                                            const int* __restrict__ off,
                                            const int* __restrict__ nbA,
                                            const __half* __restrict__ Wc,
                                            const float* __restrict__ diag,
                                            float* __restrict__ rho,
                                            float* __restrict__ mu) {
    int lane = threadIdx.x & 63;
    int g = lane >> 3, a = lane & 7;
    int waveId = (blockIdx.x * blockDim.x + threadIdx.x) >> 6;
    int nWaves = (gridDim.x * blockDim.x) >> 6;
    float rho0 = 0.f, rho1 = 0.f, mu0 = 0.f, mu1 = 0.f;
    for (int m = waveId; m < M_NODES; m += nWaves) {
        int beg = off[m], end = off[m + 1];
        float acc0 = 0.f, acc1 = 0.f;
        for (int i = beg + g; i < end; i += 8) {
            int n = nbA[i];
            union { float4 f; __half2 h[4]; } u;
            u.f = *(const float4*)(Wc + ((size_t)i << 6) + (a << 3));
            const float* rn = rv + (n << 4);          // one 64B line
            float4 r0 = *(const float4*)rn;
            float4 r1 = *(const float4*)(rn + 4);
            float4 r2 = *(const float4*)(rn + 8);
            float4 r3 = *(const float4*)(rn + 12);
            float2 w0 = __half22float2(u.h[0]);
            float2 w1 = __half22float2(u.h[1]);
            float2 w2 = __half22float2(u.h[2]);
            float2 w3 = __half22float2(u.h[3]);
            acc0 += w0.x*r0.x + w0.y*r0.y + w1.x*r0.z + w1.y*r0.w
                  + w2.x*r1.x + w2.y*r1.y + w3.x*r1.z + w3.y*r1.w;
            acc1 += w0.x*r2.x + w0.y*r2.y + w1.x*r2.z + w1.y*r2.w
                  + w2.x*r3.x + w2.y*r3.y + w3.x*r3.z + w3.y*r3.w;
        }
        acc0 += __shfl_xor(acc0, 8, 64);  acc1 += __shfl_xor(acc1, 8, 64);
        acc0 += __shfl_xor(acc0, 16, 64); acc1 += __shfl_xor(acc1, 16, 64);
        acc0 += __shfl_xor(acc0, 32, 64); acc1 += __shfl_xor(acc1, 32, 64);
        if (g < 2) {
            const float* rm = rv + (m << 4) + (g << 3);
            float4 rA = *(const float4*)rm, rB = *(const float4*)(rm + 4);
            const float* dg = diag + ((size_t)m << 6) + (a << 3);
            float4 g0 = *(const float4*)dg, g1 = *(const float4*)(dg + 4);
            float acc = g ? acc1 : acc0;
            float w = g0.x*rA.x + g0.y*rA.y + g0.z*rA.z + g0.w*rA.w
                    + g1.x*rB.x + g1.y*rB.y + g1.z*rB.z + g1.w*rB.w - acc;
            wv[(m << 4) + (g << 3) + a] = w;
            float ra = rm[a];                          // L1-hot scalar (avoid dyn reg idx)
            if (g == 0) { rho0 += ra * ra; mu0 += ra * w; }
            else        { rho1 += ra * ra; mu1 += ra * w; }
        }
    }
    blockReduceAdd4(rho0, rho1, mu0, mu1, rho, mu);
}

// r = b - w ; x = b   (elementwise on interleaved vectors)
__global__ void k_init0(const float4* __restrict__ b_il, const float4* __restrict__ w,
                        float4* __restrict__ r, float4* __restrict__ x) {
    int i = blockIdx.x * blockDim.x + threadIdx.x;
    if (i >= N4) return;
    float4 bv = b_il[i], wv = w[i];
    float4 rv = make_float4(bv.x - wv.x, bv.y - wv.y, bv.z - wv.z, bv.w - wv.w);
    r[i] = rv; x[i] = bv;
}

// C-G CG update: beta/alpha from slots (+fin history), then
// p = r + beta p; q = w + beta q; x += alpha p; r -= alpha q.
__global__ __launch_bounds__(256) void k_axpy(float4* __restrict__ x,
                                              float4* __restrict__ r,
                                              float4* __restrict__ p,
                                              float4* __restrict__ q,
                                              const float4* __restrict__ w,
                                              const float* __restrict__ rho_s,
                                              const float* __restrict__ mu_s,
                                              float* __restrict__ fin, int j) {
    float2 rho = sumSlots(rho_s);
    float2 mu  = sumSlots(mu_s);
    float b0, b1, al0, al1;
    if (j == 0) {
        b0 = b1 = 0.0f;
        al0 = rho.x / (mu.x + EPSF);
        al1 = rho.y / (mu.y + EPSF);
    } else {
        float ap0 = fin[4*(j-1)+0], ap1 = fin[4*(j-1)+1];
        float rp0 = fin[4*(j-1)+2], rp1 = fin[4*(j-1)+3];
        b0 = rho.x / (rp0 + EPSF);
        b1 = rho.y / (rp1 + EPSF);
        al0 = rho.x / (mu.x - b0 * rho.x / (ap0 + EPSF) + EPSF);
        al1 = rho.y / (mu.y - b1 * rho.y / (ap1 + EPSF) + EPSF);
    }
    int i = blockIdx.x * blockDim.x + threadIdx.x;
    if (i == 0) { fin[4*j] = al0; fin[4*j+1] = al1; fin[4*j+2] = rho.x; fin[4*j+3] = rho.y; }
    if (i >= N4) return;
    int batch = (i >> 1) & 1;   // float4 slot within 16-float group
    float be = batch ? b1 : b0;
    float al = batch ? al1 : al0;
    float4 rv = r[i], wv = w[i], xv = x[i];
    float4 pn, qn;
    if (j == 0) { pn = rv; qn = wv; }
    else {
        float4 pv = p[i], qv = q[i];
        pn = make_float4(rv.x + be*pv.x, rv.y + be*pv.y, rv.z + be*pv.z, rv.w + be*pv.w);
        qn = make_float4(wv.x + be*qv.x, wv.y + be*qv.y, wv.z + be*qv.z, wv.w + be*qv.w);
    }
    x[i] = make_float4(xv.x + al*pn.x, xv.y + al*pn.y, xv.z + al*pn.z, xv.w + al*pn.w);
    r[i] = make_float4(rv.x - al*qn.x, rv.y - al*qn.y, rv.z - al*qn.z, rv.w - al*qn.w);
    p[i] = pn; q[i] = qn;
}

extern "C" void kernel_launch(void* const* d_in, const int* in_sizes, int n_in,
                              void* d_out, int out_size, void* d_ws, size_t ws_size,
                              hipStream_t stream) {
    const float* c0 = (const float*)d_in[0];
    const int* src  = (const int*)d_in[1];
    const int* dst  = (const int*)d_in[2];
    const float* Rs = (const float*)d_in[3];
    const float* Rd = (const float*)d_in[4];

    char* wsp = (char*)d_ws;
    size_t o = 0;
    auto alloc = [&](size_t bytes) { char* c = wsp + o; o = (o + bytes + 255) & ~(size_t)255; return c; };
    float* b_il   = (float*)alloc(VEC_N * 4);
    float* r      = (float*)alloc(VEC_N * 4);
    float* wv     = (float*)alloc(VEC_N * 4);
    float* p      = (float*)alloc(VEC_N * 4);
    float* q      = (float*)alloc(VEC_N * 4);
    float* x      = (float*)alloc(VEC_N * 4);
    float* scal   = (float*)alloc(2048 * 4);
    int*   cnt    = (int*)alloc(M_NODES * 4);
    int*   offa   = (int*)alloc((M_NODES + 1) * 4);
    int*   cursor = (int*)alloc(M_NODES * 4);
    int*   pos0   = (int*)alloc(E_EDGES * 4);
    int*   pos1   = (int*)alloc(E_EDGES * 4);
    int*   wk     = (int*)alloc(N_INC * 4);
    int*   nb     = (int*)alloc(N_INC * 4);
    float* diag   = (float*)alloc((size_t)M_NODES * 64 * 4);
    __half* Wc    = (__half*)alloc((size_t)N_INC * 64 * 2);
    size_t ghBytes = (size_t)N_INC * 64 * 2;
    int haveGH = (o + ghBytes) <= ws_size;
    __half* GHc = haveGH ? (__half*)alloc(ghBytes) : (__half*)Wc;

    const int BLK = 256;
    const int grid_v  = (N4 + BLK - 1) / BLK;
    const int grid_e  = (E_EDGES + BLK - 1) / BLK;
    const int grid_m  = (M_NODES + BLK - 1) / BLK;
    const int grid_e8 = (E_EDGES * 8 + BLK - 1) / BLK;
    const int grid_m8 = (M_NODES * 8 + BLK - 1) / BLK;
    const int grid_mw = (M_NODES * 64 + BLK - 1) / BLK;
    const int MVB     = 2048;

    float* RHO = scal;             // RHO(t) = scal + 32*t
    float* MU  = scal + 1024;      // MU(t)  = scal + 1024 + 32*t
    float* FIN = scal + 1792;

    // ---- precompute (rebuilt every call) ----
    k_zero_scal<<<8, 256, 0, stream>>>(scal);
    k_zero_cnt<<<grid_m, BLK, 0, stream>>>(cnt);
    k_hist<<<grid_e, BLK, 0, stream>>>(src, dst, cnt);
    k_scan<<<1, SCAN_T, 0, stream>>>(cnt, offa, cursor);
    k_scatter<<<grid_e, BLK, 0, stream>>>(src, dst, cursor, pos0, pos1, nb, wk);
    k_buildC<<<grid_e8, BLK, 0, stream>>>(Rs, Rd, pos0, pos1, Wc, GHc, haveGH);
    if (haveGH)
        k_diagS<<<grid_mw, BLK, 0, stream>>>(offa, GHc, diag);
    else
        k_diagR<<<grid_m8, BLK, 0, stream>>>(offa, wk, Rs, Rd, diag);

    // ---- init: b_il = interleave(c0); w = A b; r = b - w; x = b ----
    k_cvt<<<grid_v, BLK, 0, stream>>>((const float4*)c0, (float4*)b_il);
    k_mv<<<MVB, BLK, 0, stream>>>(b_il, wv, offa, nb, Wc, diag,
                                  RHO + 32 * 17, MU + 32 * 17);   // scratch slots
    k_init0<<<grid_v, BLK, 0, stream>>>((const float4*)b_il, (const float4*)wv,
                                        (float4*)r, (float4*)x);

    // ---- C-G CG: 2 kernels/iter, matvec on r ----
    for (int t = 0; t < CG_ITERS; ++t) {
        k_mv<<<MVB, BLK, 0, stream>>>(r, wv, offa, nb, Wc, diag,
                                      RHO + 32 * t, MU + 32 * t);
        k_axpy<<<grid_v, BLK, 0, stream>>>((float4*)x, (float4*)r, (float4*)p,
                                           (float4*)q, (const float4*)wv,
                                           RHO + 32 * t, MU + 32 * t, FIN, t);
    }

    k_emit<<<grid_v, BLK, 0, stream>>>((const float4*)x, (float4*)d_out);
}

// Round 9
// 1359.747 us; speedup vs baseline: 6.1804x; 1.0593x over previous
//
#include <hip/hip_runtime.h>
#include <hip/hip_fp16.h>

#define E_EDGES   400000
#define M_NODES   50000
#define N_INC     800000
#define PER_B     400000
#define VEC_N     800000
#define N4        200000
#define CG_ITERS  13
#define EPSF      1e-12f

// scal (4096 floats): 32 slot-pairs (64 floats) per instance.
//   RHO(t) = scal + 64*t           t=0..13  (t=13 = init-mv scratch)
//   MU(t)  = scal + 1024 + 64*t    t=0..13
//   fin    = scal + 3968 : fin[4t+0/1]=alpha_t(b0/b1), fin[4t+2/3]=rho_t(b0/b1)

__device__ __forceinline__ float waveReduce(float v) {
#pragma unroll
    for (int off = 32; off > 0; off >>= 1)
        v += __shfl_down(v, off, 64);
    return v;
}

__device__ __forceinline__ void blockReduceAdd4(float a0, float a1, float b0, float b1,
                                                float* __restrict__ baseA,
                                                float* __restrict__ baseB) {
    __shared__ float red[16];
    a0 = waveReduce(a0); a1 = waveReduce(a1);
    b0 = waveReduce(b0); b1 = waveReduce(b1);
    int w = threadIdx.x >> 6, lane = threadIdx.x & 63;
    if (lane == 0) { red[4*w] = a0; red[4*w+1] = a1; red[4*w+2] = b0; red[4*w+3] = b1; }
    __syncthreads();
    if (threadIdx.x == 0) {
        float t0 = red[0] + red[4] + red[8]  + red[12];
        float t1 = red[1] + red[5] + red[9]  + red[13];
        float t2 = red[2] + red[6] + red[10] + red[14];
        float t3 = red[3] + red[7] + red[11] + red[15];
        int s = (blockIdx.x & 31) << 1;
        atomicAdd(&baseA[s], t0); atomicAdd(&baseA[s+1], t1);
        atomicAdd(&baseB[s], t2); atomicAdd(&baseB[s+1], t3);
    }
}

__device__ __forceinline__ float2 sumSlots(const float* __restrict__ base) {
    float a = 0.0f, b = 0.0f;
#pragma unroll
    for (int k = 0; k < 32; ++k) { a += base[2*k]; b += base[2*k+1]; }
    return make_float2(a, b);
}

__global__ void k_zero_scal(float* __restrict__ s) {
    int i = blockIdx.x * blockDim.x + threadIdx.x;
    if (i < 4096) s[i] = 0.0f;
}

__global__ void k_zero_cnt(int* __restrict__ cnt) {
    int i = blockIdx.x * blockDim.x + threadIdx.x;
    if (i < M_NODES) cnt[i] = 0;
}

__global__ void k_hist(const int* __restrict__ src, const int* __restrict__ dst,
                       int* __restrict__ cnt) {
    int e = blockIdx.x * blockDim.x + threadIdx.x;
    if (e < E_EDGES) {
        atomicAdd(&cnt[src[e]], 1);
        atomicAdd(&cnt[dst[e]], 1);
    }
}

#define SCAN_T 1024
__global__ void k_scan(const int* __restrict__ cnt, int* __restrict__ off,
                       int* __restrict__ cursor) {
    __shared__ int part[SCAN_T];
    int t = threadIdx.x;
    const int chunk = (M_NODES + SCAN_T - 1) / SCAN_T;
    int beg = t * chunk;
    int end = beg + chunk; if (end > M_NODES) end = M_NODES;
    if (beg > M_NODES) beg = M_NODES;
    int s = 0;
    for (int i = beg; i < end; ++i) s += cnt[i];
    part[t] = s;
    __syncthreads();
    for (int st = 1; st < SCAN_T; st <<= 1) {
        int v = (t >= st) ? part[t - st] : 0;
        __syncthreads();
        part[t] += v;
        __syncthreads();
    }
    int run = (t == 0) ? 0 : part[t - 1];
    for (int i = beg; i < end; ++i) {
        off[i] = run; cursor[i] = run;
        run += cnt[i];
    }
    if (t == SCAN_T - 1) off[M_NODES] = run;
}

__global__ void k_scatter(const int* __restrict__ src, const int* __restrict__ dst,
                          int* __restrict__ cursor, int* __restrict__ pos0,
                          int* __restrict__ pos1, int* __restrict__ nb,
                          int* __restrict__ wk) {
    int e = blockIdx.x * blockDim.x + threadIdx.x;
    if (e < E_EDGES) {
        int s = src[e], t = dst[e];
        int p0 = atomicAdd(&cursor[s], 1);
        pos0[e] = p0; nb[p0] = t; wk[p0] = e;
        int p1 = atomicAdd(&cursor[t], 1);
        pos1[e] = p1; nb[p1] = s; wk[p1] = e + E_EDGES;
    }
}

// 8 lanes/edge, coalesced sequential R reads; scatter-write 128B blocks to CSR slots.
__global__ __launch_bounds__(256) void k_buildC(const float* __restrict__ Rs,
                                                const float* __restrict__ Rd,
                                                const int* __restrict__ pos0,
                                                const int* __restrict__ pos1,
                                                __half* __restrict__ Wc,
                                                __half* __restrict__ GHc, int haveGH) {
    int gt = blockIdx.x * blockDim.x + threadIdx.x;
    int e = gt >> 3, a = gt & 7;
    if (e >= E_EDGES) return;
    const float* rs = Rs + ((size_t)e << 6);
    const float* rd = Rd + ((size_t)e << 6);
    float C[8], Ct[8], G[8], H[8];
#pragma unroll
    for (int j = 0; j < 8; ++j) { C[j] = 0; Ct[j] = 0; G[j] = 0; H[j] = 0; }
#pragma unroll
    for (int c = 0; c < 8; ++c) {
        float xs = rs[c * 8 + a];
        float xd = rd[c * 8 + a];
        float4 s0 = *(const float4*)(rs + c * 8);
        float4 s1 = *(const float4*)(rs + c * 8 + 4);
        float4 d0 = *(const float4*)(rd + c * 8);
        float4 d1 = *(const float4*)(rd + c * 8 + 4);
        C[0] += xs * d0.x; C[1] += xs * d0.y; C[2] += xs * d0.z; C[3] += xs * d0.w;
        C[4] += xs * d1.x; C[5] += xs * d1.y; C[6] += xs * d1.z; C[7] += xs * d1.w;
        Ct[0] += xd * s0.x; Ct[1] += xd * s0.y; Ct[2] += xd * s0.z; Ct[3] += xd * s0.w;
        Ct[4] += xd * s1.x; Ct[5] += xd * s1.y; Ct[6] += xd * s1.z; Ct[7] += xd * s1.w;
        G[0] += xs * s0.x; G[1] += xs * s0.y; G[2] += xs * s0.z; G[3] += xs * s0.w;
        G[4] += xs * s1.x; G[5] += xs * s1.y; G[6] += xs * s1.z; G[7] += xs * s1.w;
        H[0] += xd * d0.x; H[1] += xd * d0.y; H[2] += xd * d0.z; H[3] += xd * d0.w;
        H[4] += xd * d1.x; H[5] += xd * d1.y; H[6] += xd * d1.z; H[7] += xd * d1.w;
    }
    size_t s0o = (size_t)pos0[e] << 6;
    size_t s1o = (size_t)pos1[e] << 6;
    union { float4 f; __half2 h[4]; } u;
#pragma unroll
    for (int k = 0; k < 4; ++k) u.h[k] = __floats2half2_rn(C[2*k], C[2*k+1]);
    *(float4*)(Wc + s0o + (a << 3)) = u.f;
#pragma unroll
    for (int k = 0; k < 4; ++k) u.h[k] = __floats2half2_rn(Ct[2*k], Ct[2*k+1]);
    *(float4*)(Wc + s1o + (a << 3)) = u.f;
    if (haveGH) {
#pragma unroll
        for (int k = 0; k < 4; ++k) u.h[k] = __floats2half2_rn(G[2*k], G[2*k+1]);
        *(float4*)(GHc + s0o + (a << 3)) = u.f;
#pragma unroll
        for (int k = 0; k < 4; ++k) u.h[k] = __floats2half2_rn(H[2*k], H[2*k+1]);
        *(float4*)(GHc + s1o + (a << 3)) = u.f;
    }
}

// diag (fp16) from CSR-streamed GH: wave per node.
__global__ __launch_bounds__(256) void k_diagS(const int* __restrict__ off,
                                               const __half* __restrict__ GHc,
                                               __half* __restrict__ diag) {
    int wave = (blockIdx.x * blockDim.x + threadIdx.x) >> 6;
    int lane = threadIdx.x & 63;
    int g = lane >> 3, a = lane & 7;
    int m = wave;
    if (m >= M_NODES) return;
    float D[8];
#pragma unroll
    for (int j = 0; j < 8; ++j) D[j] = 0.0f;
    int beg = off[m], end = off[m + 1];
    for (int i = beg + g; i < end; i += 8) {
        union { float4 f; __half2 h[4]; } u;
        u.f = *(const float4*)(GHc + ((size_t)i << 6) + (a << 3));
        float2 w0 = __half22float2(u.h[0]);
        float2 w1 = __half22float2(u.h[1]);
        float2 w2 = __half22float2(u.h[2]);
        float2 w3 = __half22float2(u.h[3]);
        D[0] += w0.x; D[1] += w0.y; D[2] += w1.x; D[3] += w1.y;
        D[4] += w2.x; D[5] += w2.y; D[6] += w3.x; D[7] += w3.y;
    }
#pragma unroll
    for (int j = 0; j < 8; ++j) {
        D[j] += __shfl_xor(D[j], 8, 64);
        D[j] += __shfl_xor(D[j], 16, 64);
        D[j] += __shfl_xor(D[j], 32, 64);
    }
    if (g == 0) {
        D[a] += 1.0f;
        union { float4 f; __half2 h[4]; } u;
#pragma unroll
        for (int k = 0; k < 4; ++k) u.h[k] = __floats2half2_rn(D[2*k], D[2*k+1]);
        *(float4*)(diag + ((size_t)m << 6) + (a << 3)) = u.f;
    }
}

// fallback diag straight from R (runs once)
__global__ void k_diagR(const int* __restrict__ off, const int* __restrict__ wk,
                        const float* __restrict__ Rs, const float* __restrict__ Rd,
                        __half* __restrict__ diag) {
    int gt = blockIdx.x * blockDim.x + threadIdx.x;
    int m = gt >> 3, a = gt & 7;
    if (m >= M_NODES) return;
    float D[8];
#pragma unroll
    for (int j = 0; j < 8; ++j) D[j] = 0.0f;
    int beg = off[m], end = off[m + 1];
    for (int i = beg; i < end; ++i) {
        int k = wk[i];
        int side = (k >= E_EDGES);
        int e = k - (side ? E_EDGES : 0);
        const float* R = (side ? Rd : Rs) + ((size_t)e << 6);
#pragma unroll
        for (int c = 0; c < 8; ++c) {
            float xa = R[c * 8 + a];
            float4 y0 = *(const float4*)(R + c * 8);
            float4 y1 = *(const float4*)(R + c * 8 + 4);
            D[0] += xa * y0.x; D[1] += xa * y0.y; D[2] += xa * y0.z; D[3] += xa * y0.w;
            D[4] += xa * y1.x; D[5] += xa * y1.y; D[6] += xa * y1.z; D[7] += xa * y1.w;
        }
    }
    D[a] += 1.0f;
    union { float4 f; __half2 h[4]; } u;
#pragma unroll
    for (int k = 0; k < 4; ++k) u.h[k] = __floats2half2_rn(D[2*k], D[2*k+1]);
    *(float4*)(diag + ((size_t)m << 6) + (a << 3)) = u.f;
}

// layout convert: orig [b][m][8] -> interleaved [m][16]
__global__ void k_cvt(const float4* __restrict__ src, float4* __restrict__ il) {
    int i = blockIdx.x * blockDim.x + threadIdx.x;
    if (i >= N4) return;
    int b = i / (PER_B / 4);
    int rem = i - b * (PER_B / 4);
    int m = rem >> 1, half = rem & 1;
    il[(m << 2) + (b << 1) + half] = src[i];
}

// w = A r  (interleaved layout). Wave per node, grid-strided.
// Fused dots: rho = r.r, mu = w.r (per batch) -> slots.
__global__ __launch_bounds__(256) void k_mv(const float* __restrict__ rv,
                                            float* __restrict__ wv,
                                            const int* __restrict__ off,
                                            const int* __restrict__ nbA,
                                            const __half* __restrict__ Wc,
                                            const __half* __restrict__ diag,
                                            float* __restrict__ rho,
                                            float* __restrict__ mu) {
    int lane = threadIdx.x & 63;
    int g = lane >> 3, a = lane & 7;
    int waveId = (blockIdx.x * blockDim.x + threadIdx.x) >> 6;
    int nWaves = (gridDim.x * blockDim.x) >> 6;
    float rho0 = 0.f, rho1 = 0.f, mu0 = 0.f, mu1 = 0.f;
    for (int m = waveId; m < M_NODES; m += nWaves) {
        int beg = off[m], end = off[m + 1];
        float acc0 = 0.f, acc1 = 0.f;
        for (int i = beg + g; i < end; i += 8) {
            int n = nbA[i];
            union { float4 f; __half2 h[4]; } u;
            u.f = *(const float4*)(Wc + ((size_t)i << 6) + (a << 3));
            const float* rn = rv + (n << 4);          // one 64B line
            float4 r0 = *(const float4*)rn;
            float4 r1 = *(const float4*)(rn + 4);
            float4 r2 = *(const float4*)(rn + 8);
            float4 r3 = *(const float4*)(rn + 12);
            float2 w0 = __half22float2(u.h[0]);
            float2 w1 = __half22float2(u.h[1]);
            float2 w2 = __half22float2(u.h[2]);
            float2 w3 = __half22float2(u.h[3]);
            acc0 += w0.x*r0.x + w0.y*r0.y + w1.x*r0.z + w1.y*r0.w
                  + w2.x*r1.x + w2.y*r1.y + w3.x*r1.z + w3.y*r1.w;
            acc1 += w0.x*r2.x + w0.y*r2.y + w1.x*r2.z + w1.y*r2.w
                  + w2.x*r3.x + w2.y*r3.y + w3.x*r3.z + w3.y*r3.w;
        }
        acc0 += __shfl_xor(acc0, 8, 64);  acc1 += __shfl_xor(acc1, 8, 64);
        acc0 += __shfl_xor(acc0, 16, 64); acc1 += __shfl_xor(acc1, 16, 64);
        acc0 += __shfl_xor(acc0, 32, 64); acc1 += __shfl_xor(acc1, 32, 64);
        if (g < 2) {
            const float* rm = rv + (m << 4) + (g << 3);
            float4 rA = *(const float4*)rm, rB = *(const float4*)(rm + 4);
            union { float4 f; __half2 h[4]; } ud;
            ud.f = *(const float4*)(diag + ((size_t)m << 6) + (a << 3));
            float2 g0 = __half22float2(ud.h[0]);
            float2 g1 = __half22float2(ud.h[1]);
            float2 g2 = __half22float2(ud.h[2]);
            float2 g3 = __half22float2(ud.h[3]);
            float acc = g ? acc1 : acc0;
            float w = g0.x*rA.x + g0.y*rA.y + g1.x*rA.z + g1.y*rA.w
                    + g2.x*rB.x + g2.y*rB.y + g3.x*rB.z + g3.y*rB.w - acc;
            wv[(m << 4) + (g << 3) + a] = w;
            float ra = rm[a];
            if (g == 0) { rho0 += ra * ra; mu0 += ra * w; }
            else        { rho1 += ra * ra; mu1 += ra * w; }
        }
    }
    blockReduceAdd4(rho0, rho1, mu0, mu1, rho, mu);
}

// r = b - w ; x = b   (elementwise on interleaved vectors)
__global__ void k_init0(const float4* __restrict__ b_il, const float4* __restrict__ w,
                        float4* __restrict__ r, float4* __restrict__ x) {
    int i = blockIdx.x * blockDim.x + threadIdx.x;
    if (i >= N4) return;
    float4 bv = b_il[i], wv = w[i];
    float4 rv = make_float4(bv.x - wv.x, bv.y - wv.y, bv.z - wv.z, bv.w - wv.w);
    r[i] = rv; x[i] = bv;
}

// C-G CG update: beta/alpha from slots (+fin history), then
// p = r + beta p; q = w + beta q; x += alpha p; r -= alpha q.
// On the last iteration, write x directly to d_out (de-interleaved) and skip r/p/q.
__global__ __launch_bounds__(256) void k_axpy(float4* __restrict__ x,
                                              float4* __restrict__ r,
                                              float4* __restrict__ p,
                                              float4* __restrict__ q,
                                              const float4* __restrict__ w,
                                              const float* __restrict__ rho_s,
                                              const float* __restrict__ mu_s,
                                              float* __restrict__ fin, int j, int last,
                                              float4* __restrict__ out) {
    float2 rho = sumSlots(rho_s);
    float2 mu  = sumSlots(mu_s);
    float b0, b1, al0, al1;
    if (j == 0) {
        b0 = b1 = 0.0f;
        al0 = rho.x / (mu.x + EPSF);
        al1 = rho.y / (mu.y + EPSF);
    } else {
        float ap0 = fin[4*(j-1)+0], ap1 = fin[4*(j-1)+1];
        float rp0 = fin[4*(j-1)+2], rp1 = fin[4*(j-1)+3];
        b0 = rho.x / (rp0 + EPSF);
        b1 = rho.y / (rp1 + EPSF);
        al0 = rho.x / (mu.x - b0 * rho.x / (ap0 + EPSF) + EPSF);
        al1 = rho.y / (mu.y - b1 * rho.y / (ap1 + EPSF) + EPSF);
    }
    int i = blockIdx.x * blockDim.x + threadIdx.x;
    if (i == 0 && !last) {
        fin[4*j] = al0; fin[4*j+1] = al1; fin[4*j+2] = rho.x; fin[4*j+3] = rho.y;
    }
    if (i >= N4) return;
    int batch = (i >> 1) & 1;   // float4 slot within 16-float group
    float be = batch ? b1 : b0;
    float al = batch ? al1 : al0;
    float4 rv = r[i], wv = w[i], xv = x[i];
    float4 pn, qn;
    if (j == 0) { pn = rv; qn = wv; }
    else {
        float4 pv = p[i], qv = q[i];
        pn = make_float4(rv.x + be*pv.x, rv.y + be*pv.y, rv.z + be*pv.z, rv.w + be*pv.w);
        qn = make_float4(wv.x + be*qv.x, wv.y + be*qv.y, wv.z + be*qv.z, wv.w + be*qv.w);
    }
    float4 xn = make_float4(xv.x + al*pn.x, xv.y + al*pn.y, xv.z + al*pn.z, xv.w + al*pn.w);
    if (last) {
        int m = i >> 2, slot = i & 3;
        int b = slot >> 1, h = slot & 1;
        out[b * (PER_B / 4) + (m << 1) + h] = xn;
    } else {
        x[i] = xn;
        r[i] = make_float4(rv.x - al*qn.x, rv.y - al*qn.y, rv.z - al*qn.z, rv.w - al*qn.w);
        p[i] = pn; q[i] = qn;
    }
}

extern "C" void kernel_launch(void* const* d_in, const int* in_sizes, int n_in,
                              void* d_out, int out_size, void* d_ws, size_t ws_size,
                              hipStream_t stream) {
    const float* c0 = (const float*)d_in[0];
    const int* src  = (const int*)d_in[1];
    const int* dst  = (const int*)d_in[2];
    const float* Rs = (const float*)d_in[3];
    const float* Rd = (const float*)d_in[4];

    char* wsp = (char*)d_ws;
    size_t o = 0;
    auto alloc = [&](size_t bytes) { char* c = wsp + o; o = (o + bytes + 255) & ~(size_t)255; return c; };
    float* b_il   = (float*)alloc(VEC_N * 4);
    float* r      = (float*)alloc(VEC_N * 4);
    float* wv     = (float*)alloc(VEC_N * 4);
    float* p      = (float*)alloc(VEC_N * 4);
    float* q      = (float*)alloc(VEC_N * 4);
    float* x      = (float*)alloc(VEC_N * 4);
    float* scal   = (float*)alloc(4096 * 4);
    int*   cnt    = (int*)alloc(M_NODES * 4);
    int*   offa   = (int*)alloc((M_NODES + 1) * 4);
    int*   cursor = (int*)alloc(M_NODES * 4);
    int*   pos0   = (int*)alloc(E_EDGES * 4);
    int*   pos1   = (int*)alloc(E_EDGES * 4);
    int*   wk     = (int*)alloc(N_INC * 4);
    int*   nb     = (int*)alloc(N_INC * 4);
    __half* diag  = (__half*)alloc((size_t)M_NODES * 64 * 2);
    __half* Wc    = (__half*)alloc((size_t)N_INC * 64 * 2);
    size_t ghBytes = (size_t)N_INC * 64 * 2;
    int haveGH = (o + ghBytes) <= ws_size;
    __half* GHc = haveGH ? (__half*)alloc(ghBytes) : (__half*)Wc;

    const int BLK = 256;
    const int grid_v  = (N4 + BLK - 1) / BLK;
    const int grid_e  = (E_EDGES + BLK - 1) / BLK;
    const int grid_m  = (M_NODES + BLK - 1) / BLK;
    const int grid_e8 = (E_EDGES * 8 + BLK - 1) / BLK;
    const int grid_m8 = (M_NODES * 8 + BLK - 1) / BLK;
    const int grid_mw = (M_NODES * 64 + BLK - 1) / BLK;
    const int MVB     = 4096;

    float* RHO = scal;             // RHO(t) = scal + 64*t
    float* MU  = scal + 1024;      // MU(t)  = scal + 1024 + 64*t
    float* FIN = scal + 3968;

    // ---- precompute (rebuilt every call) ----
    k_zero_scal<<<16, 256, 0, stream>>>(scal);
    k_zero_cnt<<<grid_m, BLK, 0, stream>>>(cnt);
    k_hist<<<grid_e, BLK, 0, stream>>>(src, dst, cnt);
    k_scan<<<1, SCAN_T, 0, stream>>>(cnt, offa, cursor);
    k_scatter<<<grid_e, BLK, 0, stream>>>(src, dst, cursor, pos0, pos1, nb, wk);
    k_buildC<<<grid_e8, BLK, 0, stream>>>(Rs, Rd, pos0, pos1, Wc, GHc, haveGH);
    if (haveGH)
        k_diagS<<<grid_mw, BLK, 0, stream>>>(offa, GHc, diag);
    else
        k_diagR<<<grid_m8, BLK, 0, stream>>>(offa, wk, Rs, Rd, diag);

    // ---- init: b_il = interleave(c0); w = A b; r = b - w; x = b ----
    k_cvt<<<grid_v, BLK, 0, stream>>>((const float4*)c0, (float4*)b_il);
    k_mv<<<MVB, BLK, 0, stream>>>(b_il, wv, offa, nb, Wc, diag,
                                  RHO + 64 * 13, MU + 64 * 13);   // scratch slots
    k_init0<<<grid_v, BLK, 0, stream>>>((const float4*)b_il, (const float4*)wv,
                                        (float4*)r, (float4*)x);

    // ---- C-G CG: 2 kernels/iter, matvec on r ----
    for (int t = 0; t < CG_ITERS; ++t) {
        k_mv<<<MVB, BLK, 0, stream>>>(r, wv, offa, nb, Wc, diag,
                                      RHO + 64 * t, MU + 64 * t);
        k_axpy<<<grid_v, BLK, 0, stream>>>((float4*)x, (float4*)r, (float4*)p,
                                           (float4*)q, (const float4*)wv,
                                           RHO + 64 * t, MU + 64 * t, FIN, t,
                                           (t == CG_ITERS - 1) ? 1 : 0,
                                           (float4*)d_out);
    }
}

// Round 10
// 1204.444 us; speedup vs baseline: 6.9773x; 1.1289x over previous
//
#include <hip/hip_runtime.h>
#include <hip/hip_fp16.h>

#define E_EDGES   400000
#define M_NODES   50000
#define N_INC     800000
#define PER_B     400000
#define VEC_N     800000
#define N4        200000
#define CG_ITERS  12
#define EPSF      1e-12f

// scal (4096 floats): 32 slot-pairs (64 floats) per instance.
//   RHO(t) = scal + 64*t           t=0..13
//   MU(t)  = scal + 1024 + 64*t    t=0..13  (t=13 = init-mv scratch)
//   fin    = scal + 3968 : fin[4t+0/1]=alpha_t(b0/b1), fin[4t+2/3]=rho_t(b0/b1)

__device__ __forceinline__ float waveReduce(float v) {
#pragma unroll
    for (int off = 32; off > 0; off >>= 1)
        v += __shfl_down(v, off, 64);
    return v;
}

__device__ __forceinline__ void blockReduceAdd2(float d0, float d1, float* __restrict__ base) {
    __shared__ float red[8];
    d0 = waveReduce(d0);
    d1 = waveReduce(d1);
    int w = threadIdx.x >> 6, lane = threadIdx.x & 63;
    if (lane == 0) { red[2*w] = d0; red[2*w+1] = d1; }
    __syncthreads();
    if (threadIdx.x == 0) {
        float t0 = red[0] + red[2] + red[4] + red[6];
        float t1 = red[1] + red[3] + red[5] + red[7];
        int s = (blockIdx.x & 31) << 1;
        atomicAdd(&base[s], t0);
        atomicAdd(&base[s + 1], t1);
    }
}

__device__ __forceinline__ float2 sumSlots(const float* __restrict__ base) {
    float a = 0.0f, b = 0.0f;
#pragma unroll
    for (int k = 0; k < 32; ++k) { a += base[2*k]; b += base[2*k+1]; }
    return make_float2(a, b);
}

__global__ void k_zero_scal(float* __restrict__ s) {
    int i = blockIdx.x * blockDim.x + threadIdx.x;
    if (i < 4096) s[i] = 0.0f;
}

__global__ void k_zero_cnt(int* __restrict__ cnt) {
    int i = blockIdx.x * blockDim.x + threadIdx.x;
    if (i < M_NODES) cnt[i] = 0;
}

__global__ void k_hist(const int* __restrict__ src, const int* __restrict__ dst,
                       int* __restrict__ cnt) {
    int e = blockIdx.x * blockDim.x + threadIdx.x;
    if (e < E_EDGES) {
        atomicAdd(&cnt[src[e]], 1);
        atomicAdd(&cnt[dst[e]], 1);
    }
}

#define SCAN_T 1024
__global__ void k_scan(const int* __restrict__ cnt, int* __restrict__ off,
                       int* __restrict__ cursor) {
    __shared__ int part[SCAN_T];
    int t = threadIdx.x;
    const int chunk = (M_NODES + SCAN_T - 1) / SCAN_T;
    int beg = t * chunk;
    int end = beg + chunk; if (end > M_NODES) end = M_NODES;
    if (beg > M_NODES) beg = M_NODES;
    int s = 0;
    for (int i = beg; i < end; ++i) s += cnt[i];
    part[t] = s;
    __syncthreads();
    for (int st = 1; st < SCAN_T; st <<= 1) {
        int v = (t >= st) ? part[t - st] : 0;
        __syncthreads();
        part[t] += v;
        __syncthreads();
    }
    int run = (t == 0) ? 0 : part[t - 1];
    for (int i = beg; i < end; ++i) {
        off[i] = run; cursor[i] = run;
        run += cnt[i];
    }
    if (t == SCAN_T - 1) off[M_NODES] = run;
}

__global__ void k_scatter(const int* __restrict__ src, const int* __restrict__ dst,
                          int* __restrict__ cursor, int* __restrict__ pos0,
                          int* __restrict__ pos1, int* __restrict__ nb,
                          int* __restrict__ wk) {
    int e = blockIdx.x * blockDim.x + threadIdx.x;
    if (e < E_EDGES) {
        int s = src[e], t = dst[e];
        int p0 = atomicAdd(&cursor[s], 1);
        pos0[e] = p0; nb[p0] = t; wk[p0] = e;
        int p1 = atomicAdd(&cursor[t], 1);
        pos1[e] = p1; nb[p1] = s; wk[p1] = e + E_EDGES;
    }
}

// 8 lanes/edge, coalesced sequential R reads; scatter-write 128B blocks to CSR slots.
__global__ __launch_bounds__(256) void k_buildC(const float* __restrict__ Rs,
                                                const float* __restrict__ Rd,
                                                const int* __restrict__ pos0,
                                                const int* __restrict__ pos1,
                                                __half* __restrict__ Wc,
                                                __half* __restrict__ GHc, int haveGH) {
    int gt = blockIdx.x * blockDim.x + threadIdx.x;
    int e = gt >> 3, a = gt & 7;
    if (e >= E_EDGES) return;
    const float* rs = Rs + ((size_t)e << 6);
    const float* rd = Rd + ((size_t)e << 6);
    float C[8], Ct[8], G[8], H[8];
#pragma unroll
    for (int j = 0; j < 8; ++j) { C[j] = 0; Ct[j] = 0; G[j] = 0; H[j] = 0; }
#pragma unroll
    for (int c = 0; c < 8; ++c) {
        float xs = rs[c * 8 + a];
        float xd = rd[c * 8 + a];
        float4 s0 = *(const float4*)(rs + c * 8);
        float4 s1 = *(const float4*)(rs + c * 8 + 4);
        float4 d0 = *(const float4*)(rd + c * 8);
        float4 d1 = *(const float4*)(rd + c * 8 + 4);
        C[0] += xs * d0.x; C[1] += xs * d0.y; C[2] += xs * d0.z; C[3] += xs * d0.w;
        C[4] += xs * d1.x; C[5] += xs * d1.y; C[6] += xs * d1.z; C[7] += xs * d1.w;
        Ct[0] += xd * s0.x; Ct[1] += xd * s0.y; Ct[2] += xd * s0.z; Ct[3] += xd * s0.w;
        Ct[4] += xd * s1.x; Ct[5] += xd * s1.y; Ct[6] += xd * s1.z; Ct[7] += xd * s1.w;
        G[0] += xs * s0.x; G[1] += xs * s0.y; G[2] += xs * s0.z; G[3] += xs * s0.w;
        G[4] += xs * s1.x; G[5] += xs * s1.y; G[6] += xs * s1.z; G[7] += xs * s1.w;
        H[0] += xd * d0.x; H[1] += xd * d0.y; H[2] += xd * d0.z; H[3] += xd * d0.w;
        H[4] += xd * d1.x; H[5] += xd * d1.y; H[6] += xd * d1.z; H[7] += xd * d1.w;
    }
    size_t s0o = (size_t)pos0[e] << 6;
    size_t s1o = (size_t)pos1[e] << 6;
    union { float4 f; __half2 h[4]; } u;
#pragma unroll
    for (int k = 0; k < 4; ++k) u.h[k] = __floats2half2_rn(C[2*k], C[2*k+1]);
    *(float4*)(Wc + s0o + (a << 3)) = u.f;
#pragma unroll
    for (int k = 0; k < 4; ++k) u.h[k] = __floats2half2_rn(Ct[2*k], Ct[2*k+1]);
    *(float4*)(Wc + s1o + (a << 3)) = u.f;
    if (haveGH) {
#pragma unroll
        for (int k = 0; k < 4; ++k) u.h[k] = __floats2half2_rn(G[2*k], G[2*k+1]);
        *(float4*)(GHc + s0o + (a << 3)) = u.f;
#pragma unroll
        for (int k = 0; k < 4; ++k) u.h[k] = __floats2half2_rn(H[2*k], H[2*k+1]);
        *(float4*)(GHc + s1o + (a << 3)) = u.f;
    }
}

// diag (fp16) from CSR-streamed GH: wave per node.
__global__ __launch_bounds__(256) void k_diagS(const int* __restrict__ off,
                                               const __half* __restrict__ GHc,
                                               __half* __restrict__ diag) {
    int wave = (blockIdx.x * blockDim.x + threadIdx.x) >> 6;
    int lane = threadIdx.x & 63;
    int g = lane >> 3, a = lane & 7;
    int m = wave;
    if (m >= M_NODES) return;
    float D[8];
#pragma unroll
    for (int j = 0; j < 8; ++j) D[j] = 0.0f;
    int beg = off[m], end = off[m + 1];
    for (int i = beg + g; i < end; i += 8) {
        union { float4 f; __half2 h[4]; } u;
        u.f = *(const float4*)(GHc + ((size_t)i << 6) + (a << 3));
        float2 w0 = __half22float2(u.h[0]);
        float2 w1 = __half22float2(u.h[1]);
        float2 w2 = __half22float2(u.h[2]);
        float2 w3 = __half22float2(u.h[3]);
        D[0] += w0.x; D[1] += w0.y; D[2] += w1.x; D[3] += w1.y;
        D[4] += w2.x; D[5] += w2.y; D[6] += w3.x; D[7] += w3.y;
    }
#pragma unroll
    for (int j = 0; j < 8; ++j) {
        D[j] += __shfl_xor(D[j], 8, 64);
        D[j] += __shfl_xor(D[j], 16, 64);
        D[j] += __shfl_xor(D[j], 32, 64);
    }
    if (g == 0) {
        D[a] += 1.0f;
        union { float4 f; __half2 h[4]; } u;
#pragma unroll
        for (int k = 0; k < 4; ++k) u.h[k] = __floats2half2_rn(D[2*k], D[2*k+1]);
        *(float4*)(diag + ((size_t)m << 6) + (a << 3)) = u.f;
    }
}

// fallback diag straight from R (runs once)
__global__ void k_diagR(const int* __restrict__ off, const int* __restrict__ wk,
                        const float* __restrict__ Rs, const float* __restrict__ Rd,
                        __half* __restrict__ diag) {
    int gt = blockIdx.x * blockDim.x + threadIdx.x;
    int m = gt >> 3, a = gt & 7;
    if (m >= M_NODES) return;
    float D[8];
#pragma unroll
    for (int j = 0; j < 8; ++j) D[j] = 0.0f;
    int beg = off[m], end = off[m + 1];
    for (int i = beg; i < end; ++i) {
        int k = wk[i];
        int side = (k >= E_EDGES);
        int e = k - (side ? E_EDGES : 0);
        const float* R = (side ? Rd : Rs) + ((size_t)e << 6);
#pragma unroll
        for (int c = 0; c < 8; ++c) {
            float xa = R[c * 8 + a];
            float4 y0 = *(const float4*)(R + c * 8);
            float4 y1 = *(const float4*)(R + c * 8 + 4);
            D[0] += xa * y0.x; D[1] += xa * y0.y; D[2] += xa * y0.z; D[3] += xa * y0.w;
            D[4] += xa * y1.x; D[5] += xa * y1.y; D[6] += xa * y1.z; D[7] += xa * y1.w;
        }
    }
    D[a] += 1.0f;
    union { float4 f; __half2 h[4]; } u;
#pragma unroll
    for (int k = 0; k < 4; ++k) u.h[k] = __floats2half2_rn(D[2*k], D[2*k+1]);
    *(float4*)(diag + ((size_t)m << 6) + (a << 3)) = u.f;
}

// layout convert: orig [b][m][8] -> interleaved [m][16]
__global__ void k_cvt(const float4* __restrict__ src, float4* __restrict__ il) {
    int i = blockIdx.x * blockDim.x + threadIdx.x;
    if (i >= N4) return;
    int b = i / (PER_B / 4);
    int rem = i - b * (PER_B / 4);
    int m = rem >> 1, half = rem & 1;
    il[(m << 2) + (b << 1) + half] = src[i];
}

// w = A r  (interleaved). Wave/node grid-strided; incidence loop unrolled x2
// (each g-group handles i and i+8 per iter -> 2x in-flight loads).
// Fused dot: mu = w.r -> slots. (rho comes from k_axpy / k_init0.)
__global__ __launch_bounds__(256) void k_mv(const float* __restrict__ rv,
                                            float* __restrict__ wv,
                                            const int* __restrict__ off,
                                            const int* __restrict__ nbA,
                                            const __half* __restrict__ Wc,
                                            const __half* __restrict__ diag,
                                            float* __restrict__ mu) {
    int lane = threadIdx.x & 63;
    int g = lane >> 3, a = lane & 7;
    int waveId = (blockIdx.x * blockDim.x + threadIdx.x) >> 6;
    int nWaves = (gridDim.x * blockDim.x) >> 6;
    float mu0 = 0.f, mu1 = 0.f;
    for (int m = waveId; m < M_NODES; m += nWaves) {
        int beg = off[m], end = off[m + 1];
        float acc0 = 0.f, acc1 = 0.f;
        int i = beg + g;
        for (; i + 8 < end; i += 16) {
            int nA = nbA[i];
            int nB = nbA[i + 8];
            union { float4 f; __half2 h[4]; } uA, uB;
            uA.f = *(const float4*)(Wc + ((size_t)i << 6) + (a << 3));
            uB.f = *(const float4*)(Wc + ((size_t)(i + 8) << 6) + (a << 3));
            const float* rnA = rv + (nA << 4);
            const float* rnB = rv + (nB << 4);
            float4 a0 = *(const float4*)rnA;
            float4 a1 = *(const float4*)(rnA + 4);
            float4 a2 = *(const float4*)(rnA + 8);
            float4 a3 = *(const float4*)(rnA + 12);
            float4 b0 = *(const float4*)rnB;
            float4 b1 = *(const float4*)(rnB + 4);
            float4 b2 = *(const float4*)(rnB + 8);
            float4 b3 = *(const float4*)(rnB + 12);
            float2 wA0 = __half22float2(uA.h[0]);
            float2 wA1 = __half22float2(uA.h[1]);
            float2 wA2 = __half22float2(uA.h[2]);
            float2 wA3 = __half22float2(uA.h[3]);
            float2 wB0 = __half22float2(uB.h[0]);
            float2 wB1 = __half22float2(uB.h[1]);
            float2 wB2 = __half22float2(uB.h[2]);
            float2 wB3 = __half22float2(uB.h[3]);
            acc0 += wA0.x*a0.x + wA0.y*a0.y + wA1.x*a0.z + wA1.y*a0.w
                  + wA2.x*a1.x + wA2.y*a1.y + wA3.x*a1.z + wA3.y*a1.w;
            acc1 += wA0.x*a2.x + wA0.y*a2.y + wA1.x*a2.z + wA1.y*a2.w
                  + wA2.x*a3.x + wA2.y*a3.y + wA3.x*a3.z + wA3.y*a3.w;
            acc0 += wB0.x*b0.x + wB0.y*b0.y + wB1.x*b0.z + wB1.y*b0.w
                  + wB2.x*b1.x + wB2.y*b1.y + wB3.x*b1.z + wB3.y*b1.w;
            acc1 += wB0.x*b2.x + wB0.y*b2.y + wB1.x*b2.z + wB1.y*b2.w
                  + wB2.x*b3.x + wB2.y*b3.y + wB3.x*b3.z + wB3.y*b3.w;
        }
        if (i < end) {
            int n = nbA[i];
            union { float4 f; __half2 h[4]; } u;
            u.f = *(const float4*)(Wc + ((size_t)i << 6) + (a << 3));
            const float* rn = rv + (n << 4);
            float4 r0 = *(const float4*)rn;
            float4 r1 = *(const float4*)(rn + 4);
            float4 r2 = *(const float4*)(rn + 8);
            float4 r3 = *(const float4*)(rn + 12);
            float2 w0 = __half22float2(u.h[0]);
            float2 w1 = __half22float2(u.h[1]);
            float2 w2 = __half22float2(u.h[2]);
            float2 w3 = __half22float2(u.h[3]);
            acc0 += w0.x*r0.x + w0.y*r0.y + w1.x*r0.z + w1.y*r0.w
                  + w2.x*r1.x + w2.y*r1.y + w3.x*r1.z + w3.y*r1.w;
            acc1 += w0.x*r2.x + w0.y*r2.y + w1.x*r2.z + w1.y*r2.w
                  + w2.x*r3.x + w2.y*r3.y + w3.x*r3.z + w3.y*r3.w;
        }
        acc0 += __shfl_xor(acc0, 8, 64);  acc1 += __shfl_xor(acc1, 8, 64);
        acc0 += __shfl_xor(acc0, 16, 64); acc1 += __shfl_xor(acc1, 16, 64);
        acc0 += __shfl_xor(acc0, 32, 64); acc1 += __shfl_xor(acc1, 32, 64);
        if (g < 2) {
            const float* rm = rv + (m << 4) + (g << 3);
            float4 rA = *(const float4*)rm, rB = *(const float4*)(rm + 4);
            union { float4 f; __half2 h[4]; } ud;
            ud.f = *(const float4*)(diag + ((size_t)m << 6) + (a << 3));
            float2 g0 = __half22float2(ud.h[0]);
            float2 g1 = __half22float2(ud.h[1]);
            float2 g2 = __half22float2(ud.h[2]);
            float2 g3 = __half22float2(ud.h[3]);
            float acc = g ? acc1 : acc0;
            float w = g0.x*rA.x + g0.y*rA.y + g1.x*rA.z + g1.y*rA.w
                    + g2.x*rB.x + g2.y*rB.y + g3.x*rB.z + g3.y*rB.w - acc;
            wv[(m << 4) + (g << 3) + a] = w;
            float ra = rm[a];
            if (g == 0) mu0 += ra * w; else mu1 += ra * w;
        }
    }
    blockReduceAdd2(mu0, mu1, mu);
}

// r = b - w ; x = b ; rho0 = r.r
__global__ __launch_bounds__(256) void k_init0(const float4* __restrict__ b_il,
                                               const float4* __restrict__ w,
                                               float4* __restrict__ r,
                                               float4* __restrict__ x,
                                               float* __restrict__ rho0) {
    int i = blockIdx.x * blockDim.x + threadIdx.x;
    float s0 = 0.f, s1 = 0.f;
    if (i < N4) {
        float4 bv = b_il[i], wv = w[i];
        float4 rv = make_float4(bv.x - wv.x, bv.y - wv.y, bv.z - wv.z, bv.w - wv.w);
        r[i] = rv; x[i] = bv;
        float d = rv.x*rv.x + rv.y*rv.y + rv.z*rv.z + rv.w*rv.w;
        int batch = (i >> 1) & 1;
        if (batch == 0) s0 = d; else s1 = d;
    }
    blockReduceAdd2(s0, s1, rho0);
}

// C-G CG update. Scalars computed once/block (thread 0 -> LDS broadcast).
// p = r + beta p; q = w + beta q; x += alpha p; r -= alpha q; rho_next = r.r.
// Last iter: write x de-interleaved to out, skip r/p/q and rho.
__global__ __launch_bounds__(256) void k_axpy(float4* __restrict__ x,
                                              float4* __restrict__ r,
                                              float4* __restrict__ p,
                                              float4* __restrict__ q,
                                              const float4* __restrict__ w,
                                              const float* __restrict__ rho_s,
                                              const float* __restrict__ mu_s,
                                              float* __restrict__ fin,
                                              float* __restrict__ rho_next,
                                              int j, int last,
                                              float4* __restrict__ out) {
    __shared__ float sc[4];
    if (threadIdx.x == 0) {
        float2 rho = sumSlots(rho_s);
        float2 mu  = sumSlots(mu_s);
        float b0, b1, al0, al1;
        if (j == 0) {
            b0 = b1 = 0.0f;
            al0 = rho.x / (mu.x + EPSF);
            al1 = rho.y / (mu.y + EPSF);
        } else {
            float ap0 = fin[4*(j-1)+0], ap1 = fin[4*(j-1)+1];
            float rp0 = fin[4*(j-1)+2], rp1 = fin[4*(j-1)+3];
            b0 = rho.x / (rp0 + EPSF);
            b1 = rho.y / (rp1 + EPSF);
            al0 = rho.x / (mu.x - b0 * rho.x / (ap0 + EPSF) + EPSF);
            al1 = rho.y / (mu.y - b1 * rho.y / (ap1 + EPSF) + EPSF);
        }
        if (!last && blockIdx.x == 0) {
            fin[4*j] = al0; fin[4*j+1] = al1; fin[4*j+2] = rho.x; fin[4*j+3] = rho.y;
        }
        sc[0] = al0; sc[1] = al1; sc[2] = b0; sc[3] = b1;
    }
    __syncthreads();
    float al0 = sc[0], al1 = sc[1], b0 = sc[2], b1 = sc[3];
    int i = blockIdx.x * blockDim.x + threadIdx.x;
    float s0 = 0.f, s1 = 0.f;
    if (i < N4) {
        int batch = (i >> 1) & 1;
        float be = batch ? b1 : b0;
        float al = batch ? al1 : al0;
        float4 rv = r[i], wv = w[i], xv = x[i];
        float4 pn, qn;
        if (j == 0) { pn = rv; qn = wv; }
        else {
            float4 pv = p[i], qv = q[i];
            pn = make_float4(rv.x + be*pv.x, rv.y + be*pv.y, rv.z + be*pv.z, rv.w + be*pv.w);
            qn = make_float4(wv.x + be*qv.x, wv.y + be*qv.y, wv.z + be*qv.z, wv.w + be*qv.w);
        }
        float4 xn = make_float4(xv.x + al*pn.x, xv.y + al*pn.y, xv.z + al*pn.z, xv.w + al*pn.w);
        if (last) {
            int m = i >> 2, slot = i & 3;
            int b = slot >> 1, h = slot & 1;
            out[b * (PER_B / 4) + (m << 1) + h] = xn;
        } else {
            float4 rn = make_float4(rv.x - al*qn.x, rv.y - al*qn.y,
                                    rv.z - al*qn.z, rv.w - al*qn.w);
            x[i] = xn; r[i] = rn; p[i] = pn; q[i] = qn;
            float d = rn.x*rn.x + rn.y*rn.y + rn.z*rn.z + rn.w*rn.w;
            if (batch == 0) s0 = d; else s1 = d;
        }
    }
    if (!last) blockReduceAdd2(s0, s1, rho_next);
}

extern "C" void kernel_launch(void* const* d_in, const int* in_sizes, int n_in,
                              void* d_out, int out_size, void* d_ws, size_t ws_size,
                              hipStream_t stream) {
    const float* c0 = (const float*)d_in[0];
    const int* src  = (const int*)d_in[1];
    const int* dst  = (const int*)d_in[2];
    const float* Rs = (const float*)d_in[3];
    const float* Rd = (const float*)d_in[4];

    char* wsp = (char*)d_ws;
    size_t o = 0;
    auto alloc = [&](size_t bytes) { char* c = wsp + o; o = (o + bytes + 255) & ~(size_t)255; return c; };
    float* b_il   = (float*)alloc(VEC_N * 4);
    float* r      = (float*)alloc(VEC_N * 4);
    float* wv     = (float*)alloc(VEC_N * 4);
    float* p      = (float*)alloc(VEC_N * 4);
    float* q      = (float*)alloc(VEC_N * 4);
    float* x      = (float*)alloc(VEC_N * 4);
    float* scal   = (float*)alloc(4096 * 4);
    int*   cnt    = (int*)alloc(M_NODES * 4);
    int*   offa   = (int*)alloc((M_NODES + 1) * 4);
    int*   cursor = (int*)alloc(M_NODES * 4);
    int*   pos0   = (int*)alloc(E_EDGES * 4);
    int*   pos1   = (int*)alloc(E_EDGES * 4);
    int*   wk     = (int*)alloc(N_INC * 4);
    int*   nb     = (int*)alloc(N_INC * 4);
    __half* diag  = (__half*)alloc((size_t)M_NODES * 64 * 2);
    __half* Wc    = (__half*)alloc((size_t)N_INC * 64 * 2);
    size_t ghBytes = (size_t)N_INC * 64 * 2;
    int haveGH = (o + ghBytes) <= ws_size;
    __half* GHc = haveGH ? (__half*)alloc(ghBytes) : (__half*)Wc;

    const int BLK = 256;
    const int grid_v  = (N4 + BLK - 1) / BLK;
    const int grid_e  = (E_EDGES + BLK - 1) / BLK;
    const int grid_m  = (M_NODES + BLK - 1) / BLK;
    const int grid_e8 = (E_EDGES * 8 + BLK - 1) / BLK;
    const int grid_m8 = (M_NODES * 8 + BLK - 1) / BLK;
    const int grid_mw = (M_NODES * 64 + BLK - 1) / BLK;
    const int MVB     = 2048;

    float* RHO = scal;             // RHO(t) = scal + 64*t
    float* MU  = scal + 1024;      // MU(t)  = scal + 1024 + 64*t
    float* FIN = scal + 3968;

    // ---- precompute (rebuilt every call) ----
    k_zero_scal<<<16, 256, 0, stream>>>(scal);
    k_zero_cnt<<<grid_m, BLK, 0, stream>>>(cnt);
    k_hist<<<grid_e, BLK, 0, stream>>>(src, dst, cnt);
    k_scan<<<1, SCAN_T, 0, stream>>>(cnt, offa, cursor);
    k_scatter<<<grid_e, BLK, 0, stream>>>(src, dst, cursor, pos0, pos1, nb, wk);
    k_buildC<<<grid_e8, BLK, 0, stream>>>(Rs, Rd, pos0, pos1, Wc, GHc, haveGH);
    if (haveGH)
        k_diagS<<<grid_mw, BLK, 0, stream>>>(offa, GHc, diag);
    else
        k_diagR<<<grid_m8, BLK, 0, stream>>>(offa, wk, Rs, Rd, diag);

    // ---- init: b_il = interleave(c0); w = A b; r = b - w; x = b; rho0 ----
    k_cvt<<<grid_v, BLK, 0, stream>>>((const float4*)c0, (float4*)b_il);
    k_mv<<<MVB, BLK, 0, stream>>>(b_il, wv, offa, nb, Wc, diag, MU + 64 * 13);
    k_init0<<<grid_v, BLK, 0, stream>>>((const float4*)b_il, (const float4*)wv,
                                        (float4*)r, (float4*)x, RHO);

    // ---- C-G CG: 2 kernels/iter, matvec on r ----
    for (int t = 0; t < CG_ITERS; ++t) {
        k_mv<<<MVB, BLK, 0, stream>>>(r, wv, offa, nb, Wc, diag, MU + 64 * t);
        k_axpy<<<grid_v, BLK, 0, stream>>>((float4*)x, (float4*)r, (float4*)p,
                                           (float4*)q, (const float4*)wv,
                                           RHO + 64 * t, MU + 64 * t, FIN,
                                           RHO + 64 * (t + 1), t,
                                           (t == CG_ITERS - 1) ? 1 : 0,
                                           (float4*)d_out);
    }
}

// Round 11
// 1130.532 us; speedup vs baseline: 7.4335x; 1.0654x over previous
//
#include <hip/hip_runtime.h>
#include <hip/hip_fp16.h>

#define E_EDGES   400000
#define M_NODES   50000
#define N_INC     800000
#define PER_B     400000
#define VEC_N     800000
#define N4        200000
#define CG_ITERS  12
#define EPSF      1e-12f

// scal (4096 floats): 32 slot-pairs (64 floats) per instance.
//   RHO(t) = scal + 64*t           t=0..13
//   MU(t)  = scal + 1024 + 64*t    t=0..13  (t=13 = init-mv scratch)
//   fin    = scal + 3968 : fin[4t+0/1]=alpha_t(b0/b1), fin[4t+2/3]=rho_t(b0/b1)

__device__ __forceinline__ float waveReduce(float v) {
#pragma unroll
    for (int off = 32; off > 0; off >>= 1)
        v += __shfl_down(v, off, 64);
    return v;
}

__device__ __forceinline__ void blockReduceAdd2(float d0, float d1, float* __restrict__ base) {
    __shared__ float red[8];
    d0 = waveReduce(d0);
    d1 = waveReduce(d1);
    int w = threadIdx.x >> 6, lane = threadIdx.x & 63;
    if (lane == 0) { red[2*w] = d0; red[2*w+1] = d1; }
    __syncthreads();
    if (threadIdx.x == 0) {
        float t0 = red[0] + red[2] + red[4] + red[6];
        float t1 = red[1] + red[3] + red[5] + red[7];
        int s = (blockIdx.x & 31) << 1;
        atomicAdd(&base[s], t0);
        atomicAdd(&base[s + 1], t1);
    }
}

__device__ __forceinline__ float2 sumSlots(const float* __restrict__ base) {
    float a = 0.0f, b = 0.0f;
#pragma unroll
    for (int k = 0; k < 32; ++k) { a += base[2*k]; b += base[2*k+1]; }
    return make_float2(a, b);
}

// zero scal (4096 floats) + cnt (M_NODES ints) in one launch
__global__ void k_zero(float* __restrict__ s, int* __restrict__ cnt) {
    int i = blockIdx.x * blockDim.x + threadIdx.x;
    if (i < 4096) s[i] = 0.0f;
    if (i < M_NODES) cnt[i] = 0;
}

__global__ void k_hist(const int* __restrict__ src, const int* __restrict__ dst,
                       int* __restrict__ cnt) {
    int e = blockIdx.x * blockDim.x + threadIdx.x;
    if (e < E_EDGES) {
        atomicAdd(&cnt[src[e]], 1);
        atomicAdd(&cnt[dst[e]], 1);
    }
}

#define SCAN_T 1024
__global__ void k_scan(const int* __restrict__ cnt, int* __restrict__ off,
                       int* __restrict__ cursor) {
    __shared__ int part[SCAN_T];
    int t = threadIdx.x;
    const int chunk = (M_NODES + SCAN_T - 1) / SCAN_T;
    int beg = t * chunk;
    int end = beg + chunk; if (end > M_NODES) end = M_NODES;
    if (beg > M_NODES) beg = M_NODES;
    int s = 0;
    for (int i = beg; i < end; ++i) s += cnt[i];
    part[t] = s;
    __syncthreads();
    for (int st = 1; st < SCAN_T; st <<= 1) {
        int v = (t >= st) ? part[t - st] : 0;
        __syncthreads();
        part[t] += v;
        __syncthreads();
    }
    int run = (t == 0) ? 0 : part[t - 1];
    for (int i = beg; i < end; ++i) {
        off[i] = run; cursor[i] = run;
        run += cnt[i];
    }
    if (t == SCAN_T - 1) off[M_NODES] = run;
}

__global__ void k_scatter(const int* __restrict__ src, const int* __restrict__ dst,
                          int* __restrict__ cursor, int* __restrict__ pos0,
                          int* __restrict__ pos1, int* __restrict__ nb,
                          int* __restrict__ wk) {
    int e = blockIdx.x * blockDim.x + threadIdx.x;
    if (e < E_EDGES) {
        int s = src[e], t = dst[e];
        int p0 = atomicAdd(&cursor[s], 1);
        pos0[e] = p0; nb[p0] = t; wk[p0] = e;
        int p1 = atomicAdd(&cursor[t], 1);
        pos1[e] = p1; nb[p1] = s; wk[p1] = e + E_EDGES;
    }
}

// 8 lanes/edge, coalesced sequential R reads; scatter-write 128B blocks to CSR slots.
__global__ __launch_bounds__(256) void k_buildC(const float* __restrict__ Rs,
                                                const float* __restrict__ Rd,
                                                const int* __restrict__ pos0,
                                                const int* __restrict__ pos1,
                                                __half* __restrict__ Wc,
                                                __half* __restrict__ GHc, int haveGH) {
    int gt = blockIdx.x * blockDim.x + threadIdx.x;
    int e = gt >> 3, a = gt & 7;
    if (e >= E_EDGES) return;
    const float* rs = Rs + ((size_t)e << 6);
    const float* rd = Rd + ((size_t)e << 6);
    float C[8], Ct[8], G[8], H[8];
#pragma unroll
    for (int j = 0; j < 8; ++j) { C[j] = 0; Ct[j] = 0; G[j] = 0; H[j] = 0; }
#pragma unroll
    for (int c = 0; c < 8; ++c) {
        float xs = rs[c * 8 + a];
        float xd = rd[c * 8 + a];
        float4 s0 = *(const float4*)(rs + c * 8);
        float4 s1 = *(const float4*)(rs + c * 8 + 4);
        float4 d0 = *(const float4*)(rd + c * 8);
        float4 d1 = *(const float4*)(rd + c * 8 + 4);
        C[0] += xs * d0.x; C[1] += xs * d0.y; C[2] += xs * d0.z; C[3] += xs * d0.w;
        C[4] += xs * d1.x; C[5] += xs * d1.y; C[6] += xs * d1.z; C[7] += xs * d1.w;
        Ct[0] += xd * s0.x; Ct[1] += xd * s0.y; Ct[2] += xd * s0.z; Ct[3] += xd * s0.w;
        Ct[4] += xd * s1.x; Ct[5] += xd * s1.y; Ct[6] += xd * s1.z; Ct[7] += xd * s1.w;
        G[0] += xs * s0.x; G[1] += xs * s0.y; G[2] += xs * s0.z; G[3] += xs * s0.w;
        G[4] += xs * s1.x; G[5] += xs * s1.y; G[6] += xs * s1.z; G[7] += xs * s1.w;
        H[0] += xd * d0.x; H[1] += xd * d0.y; H[2] += xd * d0.z; H[3] += xd * d0.w;
        H[4] += xd * d1.x; H[5] += xd * d1.y; H[6] += xd * d1.z; H[7] += xd * d1.w;
    }
    size_t s0o = (size_t)pos0[e] << 6;
    size_t s1o = (size_t)pos1[e] << 6;
    union { float4 f; __half2 h[4]; } u;
#pragma unroll
    for (int k = 0; k < 4; ++k) u.h[k] = __floats2half2_rn(C[2*k], C[2*k+1]);
    *(float4*)(Wc + s0o + (a << 3)) = u.f;
#pragma unroll
    for (int k = 0; k < 4; ++k) u.h[k] = __floats2half2_rn(Ct[2*k], Ct[2*k+1]);
    *(float4*)(Wc + s1o + (a << 3)) = u.f;
    if (haveGH) {
#pragma unroll
        for (int k = 0; k < 4; ++k) u.h[k] = __floats2half2_rn(G[2*k], G[2*k+1]);
        *(float4*)(GHc + s0o + (a << 3)) = u.f;
#pragma unroll
        for (int k = 0; k < 4; ++k) u.h[k] = __floats2half2_rn(H[2*k], H[2*k+1]);
        *(float4*)(GHc + s1o + (a << 3)) = u.f;
    }
}

// diag (fp16) from CSR-streamed GH: wave per node.
__global__ __launch_bounds__(256) void k_diagS(const int* __restrict__ off,
                                               const __half* __restrict__ GHc,
                                               __half* __restrict__ diag) {
    int wave = (blockIdx.x * blockDim.x + threadIdx.x) >> 6;
    int lane = threadIdx.x & 63;
    int g = lane >> 3, a = lane & 7;
    int m = wave;
    if (m >= M_NODES) return;
    float D[8];
#pragma unroll
    for (int j = 0; j < 8; ++j) D[j] = 0.0f;
    int beg = off[m], end = off[m + 1];
    for (int i = beg + g; i < end; i += 8) {
        union { float4 f; __half2 h[4]; } u;
        u.f = *(const float4*)(GHc + ((size_t)i << 6) + (a << 3));
        float2 w0 = __half22float2(u.h[0]);
        float2 w1 = __half22float2(u.h[1]);
        float2 w2 = __half22float2(u.h[2]);
        float2 w3 = __half22float2(u.h[3]);
        D[0] += w0.x; D[1] += w0.y; D[2] += w1.x; D[3] += w1.y;
        D[4] += w2.x; D[5] += w2.y; D[6] += w3.x; D[7] += w3.y;
    }
#pragma unroll
    for (int j = 0; j < 8; ++j) {
        D[j] += __shfl_xor(D[j], 8, 64);
        D[j] += __shfl_xor(D[j], 16, 64);
        D[j] += __shfl_xor(D[j], 32, 64);
    }
    if (g == 0) {
        D[a] += 1.0f;
        union { float4 f; __half2 h[4]; } u;
#pragma unroll
        for (int k = 0; k < 4; ++k) u.h[k] = __floats2half2_rn(D[2*k], D[2*k+1]);
        *(float4*)(diag + ((size_t)m << 6) + (a << 3)) = u.f;
    }
}

// fallback diag straight from R (runs once)
__global__ void k_diagR(const int* __restrict__ off, const int* __restrict__ wk,
                        const float* __restrict__ Rs, const float* __restrict__ Rd,
                        __half* __restrict__ diag) {
    int gt = blockIdx.x * blockDim.x + threadIdx.x;
    int m = gt >> 3, a = gt & 7;
    if (m >= M_NODES) return;
    float D[8];
#pragma unroll
    for (int j = 0; j < 8; ++j) D[j] = 0.0f;
    int beg = off[m], end = off[m + 1];
    for (int i = beg; i < end; ++i) {
        int k = wk[i];
        int side = (k >= E_EDGES);
        int e = k - (side ? E_EDGES : 0);
        const float* R = (side ? Rd : Rs) + ((size_t)e << 6);
#pragma unroll
        for (int c = 0; c < 8; ++c) {
            float xa = R[c * 8 + a];
            float4 y0 = *(const float4*)(R + c * 8);
            float4 y1 = *(const float4*)(R + c * 8 + 4);
            D[0] += xa * y0.x; D[1] += xa * y0.y; D[2] += xa * y0.z; D[3] += xa * y0.w;
            D[4] += xa * y1.x; D[5] += xa * y1.y; D[6] += xa * y1.z; D[7] += xa * y1.w;
        }
    }
    D[a] += 1.0f;
    union { float4 f; __half2 h[4]; } u;
#pragma unroll
    for (int k = 0; k < 4; ++k) u.h[k] = __floats2half2_rn(D[2*k], D[2*k+1]);
    *(float4*)(diag + ((size_t)m << 6) + (a << 3)) = u.f;
}

// helper: write 4 floats as 4 halfs (8B) at rh + idx4*4
__device__ __forceinline__ void writeHalf4(__half* __restrict__ rh, int i4, float4 v) {
    union { float2 f2; __half2 h[2]; } u;
    u.h[0] = __floats2half2_rn(v.x, v.y);
    u.h[1] = __floats2half2_rn(v.z, v.w);
    *(float2*)(rh + (i4 << 2)) = u.f2;
}

// layout convert: orig [b][m][8] -> interleaved [m][16] fp32 + fp16 mirror
__global__ void k_cvt(const float4* __restrict__ src, float4* __restrict__ il,
                      __half* __restrict__ ilh) {
    int i = blockIdx.x * blockDim.x + threadIdx.x;
    if (i >= N4) return;
    int b = i / (PER_B / 4);
    int rem = i - b * (PER_B / 4);
    int m = rem >> 1, half = rem & 1;
    int d = (m << 2) + (b << 1) + half;
    float4 v = src[i];
    il[d] = v;
    writeHalf4(ilh, d, v);
}

// w = A r  (fp16 gather mirror rh). Wave/node grid-strided; incidence loop
// unrolled x2. Per g-group iter: 2 nb + 2x16B W + 4x16B rh loads.
// Fused dot: mu = w.r -> slots.
__global__ __launch_bounds__(256) void k_mv(const __half* __restrict__ rh,
                                            float* __restrict__ wv,
                                            const int* __restrict__ off,
                                            const int* __restrict__ nbA,
                                            const __half* __restrict__ Wc,
                                            const __half* __restrict__ diag,
                                            float* __restrict__ mu) {
    int lane = threadIdx.x & 63;
    int g = lane >> 3, a = lane & 7;
    int waveId = (blockIdx.x * blockDim.x + threadIdx.x) >> 6;
    int nWaves = (gridDim.x * blockDim.x) >> 6;
    float mu0 = 0.f, mu1 = 0.f;
    for (int m = waveId; m < M_NODES; m += nWaves) {
        int beg = off[m], end = off[m + 1];
        float acc0 = 0.f, acc1 = 0.f;
        int i = beg + g;
        for (; i + 8 < end; i += 16) {
            int nA = nbA[i];
            int nB = nbA[i + 8];
            union { float4 f; __half2 h[4]; } uA, uB, rA0, rA1, rB0, rB1;
            uA.f = *(const float4*)(Wc + ((size_t)i << 6) + (a << 3));
            uB.f = *(const float4*)(Wc + ((size_t)(i + 8) << 6) + (a << 3));
            rA0.f = *(const float4*)(rh + (nA << 4));
            rA1.f = *(const float4*)(rh + (nA << 4) + 8);
            rB0.f = *(const float4*)(rh + (nB << 4));
            rB1.f = *(const float4*)(rh + (nB << 4) + 8);
            float2 wA0 = __half22float2(uA.h[0]);
            float2 wA1 = __half22float2(uA.h[1]);
            float2 wA2 = __half22float2(uA.h[2]);
            float2 wA3 = __half22float2(uA.h[3]);
            float2 a00 = __half22float2(rA0.h[0]);
            float2 a01 = __half22float2(rA0.h[1]);
            float2 a02 = __half22float2(rA0.h[2]);
            float2 a03 = __half22float2(rA0.h[3]);
            float2 a10 = __half22float2(rA1.h[0]);
            float2 a11 = __half22float2(rA1.h[1]);
            float2 a12 = __half22float2(rA1.h[2]);
            float2 a13 = __half22float2(rA1.h[3]);
            acc0 += wA0.x*a00.x + wA0.y*a00.y + wA1.x*a01.x + wA1.y*a01.y
                  + wA2.x*a02.x + wA2.y*a02.y + wA3.x*a03.x + wA3.y*a03.y;
            acc1 += wA0.x*a10.x + wA0.y*a10.y + wA1.x*a11.x + wA1.y*a11.y
                  + wA2.x*a12.x + wA2.y*a12.y + wA3.x*a13.x + wA3.y*a13.y;
            float2 wB0 = __half22float2(uB.h[0]);
            float2 wB1 = __half22float2(uB.h[1]);
            float2 wB2 = __half22float2(uB.h[2]);
            float2 wB3 = __half22float2(uB.h[3]);
            float2 b00 = __half22float2(rB0.h[0]);
            float2 b01 = __half22float2(rB0.h[1]);
            float2 b02 = __half22float2(rB0.h[2]);
            float2 b03 = __half22float2(rB0.h[3]);
            float2 b10 = __half22float2(rB1.h[0]);
            float2 b11 = __half22float2(rB1.h[1]);
            float2 b12 = __half22float2(rB1.h[2]);
            float2 b13 = __half22float2(rB1.h[3]);
            acc0 += wB0.x*b00.x + wB0.y*b00.y + wB1.x*b01.x + wB1.y*b01.y
                  + wB2.x*b02.x + wB2.y*b02.y + wB3.x*b03.x + wB3.y*b03.y;
            acc1 += wB0.x*b10.x + wB0.y*b10.y + wB1.x*b11.x + wB1.y*b11.y
                  + wB2.x*b12.x + wB2.y*b12.y + wB3.x*b13.x + wB3.y*b13.y;
        }
        if (i < end) {
            int n = nbA[i];
            union { float4 f; __half2 h[4]; } u, r0, r1;
            u.f = *(const float4*)(Wc + ((size_t)i << 6) + (a << 3));
            r0.f = *(const float4*)(rh + (n << 4));
            r1.f = *(const float4*)(rh + (n << 4) + 8);
            float2 w0 = __half22float2(u.h[0]);
            float2 w1 = __half22float2(u.h[1]);
            float2 w2 = __half22float2(u.h[2]);
            float2 w3 = __half22float2(u.h[3]);
            float2 c00 = __half22float2(r0.h[0]);
            float2 c01 = __half22float2(r0.h[1]);
            float2 c02 = __half22float2(r0.h[2]);
            float2 c03 = __half22float2(r0.h[3]);
            float2 c10 = __half22float2(r1.h[0]);
            float2 c11 = __half22float2(r1.h[1]);
            float2 c12 = __half22float2(r1.h[2]);
            float2 c13 = __half22float2(r1.h[3]);
            acc0 += w0.x*c00.x + w0.y*c00.y + w1.x*c01.x + w1.y*c01.y
                  + w2.x*c02.x + w2.y*c02.y + w3.x*c03.x + w3.y*c03.y;
            acc1 += w0.x*c10.x + w0.y*c10.y + w1.x*c11.x + w1.y*c11.y
                  + w2.x*c12.x + w2.y*c12.y + w3.x*c13.x + w3.y*c13.y;
        }
        acc0 += __shfl_xor(acc0, 8, 64);  acc1 += __shfl_xor(acc1, 8, 64);
        acc0 += __shfl_xor(acc0, 16, 64); acc1 += __shfl_xor(acc1, 16, 64);
        acc0 += __shfl_xor(acc0, 32, 64); acc1 += __shfl_xor(acc1, 32, 64);
        if (g < 2) {
            union { float4 f; __half2 h[4]; } ur, ud;
            ur.f = *(const float4*)(rh + (m << 4) + (g << 3));
            ud.f = *(const float4*)(diag + ((size_t)m << 6) + (a << 3));
            float rm[8];
            float2 t;
            t = __half22float2(ur.h[0]); rm[0] = t.x; rm[1] = t.y;
            t = __half22float2(ur.h[1]); rm[2] = t.x; rm[3] = t.y;
            t = __half22float2(ur.h[2]); rm[4] = t.x; rm[5] = t.y;
            t = __half22float2(ur.h[3]); rm[6] = t.x; rm[7] = t.y;
            float2 g0 = __half22float2(ud.h[0]);
            float2 g1 = __half22float2(ud.h[1]);
            float2 g2 = __half22float2(ud.h[2]);
            float2 g3 = __half22float2(ud.h[3]);
            float acc = g ? acc1 : acc0;
            float w = g0.x*rm[0] + g0.y*rm[1] + g1.x*rm[2] + g1.y*rm[3]
                    + g2.x*rm[4] + g2.y*rm[5] + g3.x*rm[6] + g3.y*rm[7] - acc;
            wv[(m << 4) + (g << 3) + a] = w;
            float ra = rm[a];
            if (g == 0) mu0 += ra * w; else mu1 += ra * w;
        }
    }
    blockReduceAdd2(mu0, mu1, mu);
}

// r = b - w ; x = b ; rh mirror ; rho0 = r.r
__global__ __launch_bounds__(256) void k_init0(const float4* __restrict__ b_il,
                                               const float4* __restrict__ w,
                                               float4* __restrict__ r,
                                               __half* __restrict__ rh,
                                               float4* __restrict__ x,
                                               float* __restrict__ rho0) {
    int i = blockIdx.x * blockDim.x + threadIdx.x;
    float s0 = 0.f, s1 = 0.f;
    if (i < N4) {
        float4 bv = b_il[i], wv = w[i];
        float4 rv = make_float4(bv.x - wv.x, bv.y - wv.y, bv.z - wv.z, bv.w - wv.w);
        r[i] = rv; x[i] = bv;
        writeHalf4(rh, i, rv);
        float d = rv.x*rv.x + rv.y*rv.y + rv.z*rv.z + rv.w*rv.w;
        int batch = (i >> 1) & 1;
        if (batch == 0) s0 = d; else s1 = d;
    }
    blockReduceAdd2(s0, s1, rho0);
}

// C-G CG update, grid-stride. Scalars once/block (thread 0 -> LDS broadcast).
// p = r + beta p; q = w + beta q; x += alpha p; r -= alpha q (+rh mirror);
// rho_next = r.r. Last iter: write x de-interleaved to out only.
__global__ __launch_bounds__(256) void k_axpy(float4* __restrict__ x,
                                              float4* __restrict__ r,
                                              __half* __restrict__ rh,
                                              float4* __restrict__ p,
                                              float4* __restrict__ q,
                                              const float4* __restrict__ w,
                                              const float* __restrict__ rho_s,
                                              const float* __restrict__ mu_s,
                                              float* __restrict__ fin,
                                              float* __restrict__ rho_next,
                                              int j, int last,
                                              float4* __restrict__ out) {
    __shared__ float sc[4];
    if (threadIdx.x == 0) {
        float2 rho = sumSlots(rho_s);
        float2 mu  = sumSlots(mu_s);
        float b0, b1, al0, al1;
        if (j == 0) {
            b0 = b1 = 0.0f;
            al0 = rho.x / (mu.x + EPSF);
            al1 = rho.y / (mu.y + EPSF);
        } else {
            float ap0 = fin[4*(j-1)+0], ap1 = fin[4*(j-1)+1];
            float rp0 = fin[4*(j-1)+2], rp1 = fin[4*(j-1)+3];
            b0 = rho.x / (rp0 + EPSF);
            b1 = rho.y / (rp1 + EPSF);
            al0 = rho.x / (mu.x - b0 * rho.x / (ap0 + EPSF) + EPSF);
            al1 = rho.y / (mu.y - b1 * rho.y / (ap1 + EPSF) + EPSF);
        }
        if (!last && blockIdx.x == 0) {
            fin[4*j] = al0; fin[4*j+1] = al1; fin[4*j+2] = rho.x; fin[4*j+3] = rho.y;
        }
        sc[0] = al0; sc[1] = al1; sc[2] = b0; sc[3] = b1;
    }
    __syncthreads();
    float al0 = sc[0], al1 = sc[1], b0 = sc[2], b1 = sc[3];
    float s0 = 0.f, s1 = 0.f;
    for (int i = blockIdx.x * blockDim.x + threadIdx.x; i < N4;
         i += gridDim.x * blockDim.x) {
        int batch = (i >> 1) & 1;
        float be = batch ? b1 : b0;
        float al = batch ? al1 : al0;
        float4 rv = r[i], wv = w[i], xv = x[i];
        float4 pn, qn;
        if (j == 0) { pn = rv; qn = wv; }
        else {
            float4 pv = p[i], qv = q[i];
            pn = make_float4(rv.x + be*pv.x, rv.y + be*pv.y, rv.z + be*pv.z, rv.w + be*pv.w);
            qn = make_float4(wv.x + be*qv.x, wv.y + be*qv.y, wv.z + be*qv.z, wv.w + be*qv.w);
        }
        float4 xn = make_float4(xv.x + al*pn.x, xv.y + al*pn.y, xv.z + al*pn.z, xv.w + al*pn.w);
        if (last) {
            int m = i >> 2, slot = i & 3;
            int b = slot >> 1, h = slot & 1;
            out[b * (PER_B / 4) + (m << 1) + h] = xn;
        } else {
            float4 rn = make_float4(rv.x - al*qn.x, rv.y - al*qn.y,
                                    rv.z - al*qn.z, rv.w - al*qn.w);
            x[i] = xn; r[i] = rn; p[i] = pn; q[i] = qn;
            writeHalf4(rh, i, rn);
            float d = rn.x*rn.x + rn.y*rn.y + rn.z*rn.z + rn.w*rn.w;
            if (batch == 0) s0 += d; else s1 += d;
        }
    }
    if (!last) blockReduceAdd2(s0, s1, rho_next);
}

extern "C" void kernel_launch(void* const* d_in, const int* in_sizes, int n_in,
                              void* d_out, int out_size, void* d_ws, size_t ws_size,
                              hipStream_t stream) {
    const float* c0 = (const float*)d_in[0];
    const int* src  = (const int*)d_in[1];
    const int* dst  = (const int*)d_in[2];
    const float* Rs = (const float*)d_in[3];
    const float* Rd = (const float*)d_in[4];

    char* wsp = (char*)d_ws;
    size_t o = 0;
    auto alloc = [&](size_t bytes) { char* c = wsp + o; o = (o + bytes + 255) & ~(size_t)255; return c; };
    float* b_il   = (float*)alloc(VEC_N * 4);
    float* r      = (float*)alloc(VEC_N * 4);
    float* wv     = (float*)alloc(VEC_N * 4);
    float* p      = (float*)alloc(VEC_N * 4);
    float* q      = (float*)alloc(VEC_N * 4);
    float* x      = (float*)alloc(VEC_N * 4);
    __half* rh    = (__half*)alloc(VEC_N * 2);
    __half* bh    = (__half*)alloc(VEC_N * 2);
    float* scal   = (float*)alloc(4096 * 4);
    int*   cnt    = (int*)alloc(M_NODES * 4);
    int*   offa   = (int*)alloc((M_NODES + 1) * 4);
    int*   cursor = (int*)alloc(M_NODES * 4);
    int*   pos0   = (int*)alloc(E_EDGES * 4);
    int*   pos1   = (int*)alloc(E_EDGES * 4);
    int*   wk     = (int*)alloc(N_INC * 4);
    int*   nb     = (int*)alloc(N_INC * 4);
    __half* diag  = (__half*)alloc((size_t)M_NODES * 64 * 2);
    __half* Wc    = (__half*)alloc((size_t)N_INC * 64 * 2);
    size_t ghBytes = (size_t)N_INC * 64 * 2;
    int haveGH = (o + ghBytes) <= ws_size;
    __half* GHc = haveGH ? (__half*)alloc(ghBytes) : (__half*)Wc;

    const int BLK = 256;
    const int grid_v  = (N4 + BLK - 1) / BLK;
    const int grid_e  = (E_EDGES + BLK - 1) / BLK;
    const int grid_m  = (M_NODES + BLK - 1) / BLK;
    const int grid_e8 = (E_EDGES * 8 + BLK - 1) / BLK;
    const int grid_m8 = (M_NODES * 8 + BLK - 1) / BLK;
    const int grid_mw = (M_NODES * 64 + BLK - 1) / BLK;
    const int MVB     = 2048;
    const int AXB     = 512;

    float* RHO = scal;             // RHO(t) = scal + 64*t
    float* MU  = scal + 1024;      // MU(t)  = scal + 1024 + 64*t
    float* FIN = scal + 3968;

    // ---- precompute (rebuilt every call) ----
    k_zero<<<grid_m, BLK, 0, stream>>>(scal, cnt);
    k_hist<<<grid_e, BLK, 0, stream>>>(src, dst, cnt);
    k_scan<<<1, SCAN_T, 0, stream>>>(cnt, offa, cursor);
    k_scatter<<<grid_e, BLK, 0, stream>>>(src, dst, cursor, pos0, pos1, nb, wk);
    k_buildC<<<grid_e8, BLK, 0, stream>>>(Rs, Rd, pos0, pos1, Wc, GHc, haveGH);
    if (haveGH)
        k_diagS<<<grid_mw, BLK, 0, stream>>>(offa, GHc, diag);
    else
        k_diagR<<<grid_m8, BLK, 0, stream>>>(offa, wk, Rs, Rd, diag);

    // ---- init: b_il/bh = interleave(c0); w = A b; r = b - w; x = b; rho0 ----
    k_cvt<<<grid_v, BLK, 0, stream>>>((const float4*)c0, (float4*)b_il, bh);
    k_mv<<<MVB, BLK, 0, stream>>>(bh, wv, offa, nb, Wc, diag, MU + 64 * 13);
    k_init0<<<grid_v, BLK, 0, stream>>>((const float4*)b_il, (const float4*)wv,
                                        (float4*)r, rh, (float4*)x, RHO);

    // ---- C-G CG: 2 kernels/iter, matvec on rh ----
    for (int t = 0; t < CG_ITERS; ++t) {
        k_mv<<<MVB, BLK, 0, stream>>>(rh, wv, offa, nb, Wc, diag, MU + 64 * t);
        k_axpy<<<AXB, BLK, 0, stream>>>((float4*)x, (float4*)r, rh, (float4*)p,
                                        (float4*)q, (const float4*)wv,
                                        RHO + 64 * t, MU + 64 * t, FIN,
                                        RHO + 64 * (t + 1), t,
                                        (t == CG_ITERS - 1) ? 1 : 0,
                                        (float4*)d_out);
    }
}